// Round 10
// baseline (411.377 us; speedup 1.0000x reference)
//
#include <hip/hip_runtime.h>
#include <hip/hip_bf16.h>
#include <cstddef>
#include <cstdint>

// Problem constants (match reference)
constexpr int Bc  = 4;
constexpr int Tc  = 2048;
constexpr int Dc  = 1024;
constexpr int Hc  = 16;
constexpr int Ec  = 8;     // experts
constexpr int DEc = 256;   // expert dim
constexpr int NTOK = Bc * Tc;          // 8192 tokens
constexpr int EDE = Ec * DEc;          // 2048

typedef __attribute__((ext_vector_type(8)))  short  s8v;   // 8 bf16 (4 VGPRs)
typedef __attribute__((ext_vector_type(4)))  float  f4v;   // 16x16 MFMA C/D
typedef __attribute__((ext_vector_type(16))) float  f16v;  // 32x32 MFMA C/D
typedef __attribute__((ext_vector_type(8)))  ushort u8v;
typedef __attribute__((ext_vector_type(4)))  ushort u4v;

constexpr float LOG2E = 1.44269504088896340736f;

__device__ inline ushort f2bf(float f) {  // fp32 -> bf16 bits, RNE
  union { float f; uint32_t u; } v; v.f = f;
  uint32_t r = v.u + 0x7FFFu + ((v.u >> 16) & 1u);
  return (ushort)(r >> 16);
}
__device__ inline float exp2v(float x) {   // 2^x on the TRANS pipe
  float r; asm("v_exp_f32 %0, %1" : "=v"(r) : "v"(x)); return r;
}
__device__ inline float max3f(float a, float b, float c) {
  return fmaxf(fmaxf(a, b), c);             // clang fuses to v_max3_f32
}
// pair-reduce lane l <-> l^32 without DS ops (pure VALU)
__device__ inline float pmax32(float x) {
  float a = x, b = x;
  asm("v_permlane32_swap_b32 %0, %1" : "+v"(b), "+v"(a));
  return fmaxf(a, b);
}

// async global->LDS, 16B per lane; LDS dest = wave-uniform base + lane*16
#define GLOAD_LDS(gsrc, ldst)                                        \
  __builtin_amdgcn_global_load_lds(                                  \
      (const __attribute__((address_space(1))) void*)(gsrc),         \
      (__attribute__((address_space(3))) void*)(ldst), 16, 0, 0)

// pack 2 f32 -> 1 u32 of 2 bf16 (lo = a, hi = b), RNE
__device__ inline uint32_t cvtpk(float a, float b) {
  uint32_t r;
  asm("v_cvt_pk_bf16_f32 %0, %1, %2" : "=v"(r) : "v"(a), "v"(b));
  return r;
}

__device__ inline u8v pack8(const float4& a, const float4& b) {
  u8v o;
  o[0] = f2bf(a.x); o[1] = f2bf(a.y); o[2] = f2bf(a.z); o[3] = f2bf(a.w);
  o[4] = f2bf(b.x); o[5] = f2bf(b.y); o[6] = f2bf(b.z); o[7] = f2bf(b.w);
  return o;
}

// ---------------------------------------------------------------------------
// Single fused weight-convert kernel (block-range dispatch)
// ---------------------------------------------------------------------------
__global__ __launch_bounds__(256)
void convert_all(const float* __restrict__ in_w, const float* __restrict__ out_w,
                 const float* __restrict__ Wg, const float* __restrict__ Wu,
                 const float* __restrict__ Wd,
                 ushort* __restrict__ wb_in, ushort* __restrict__ wb_out,
                 ushort* __restrict__ wb_gu, ushort* __restrict__ wb_d) {
  const int b = blockIdx.x;
  const int tid = threadIdx.x;
  if (b < 1536) {
    const size_t i = ((size_t)b * 256 + tid) * 8;
    *(u8v*)(wb_in + i) = pack8(*(const float4*)(in_w + i),
                               *(const float4*)(in_w + i + 4));
  } else if (b < 2048) {
    const size_t i = ((size_t)(b - 1536) * 256 + tid) * 8;
    *(u8v*)(wb_out + i) = pack8(*(const float4*)(out_w + i),
                                *(const float4*)(out_w + i + 4));
  } else if (b < 4096) {
    const size_t i = ((size_t)(b - 2048) * 256 + tid) * 8;
    const int r = (int)(i >> 10), k = (int)(i & 1023);
    const int j = ((r >> 5) << 4) + (r & 15);
    const float* src = (r & 16) ? Wu : Wg;
    *(u8v*)(wb_gu + i) = pack8(*(const float4*)(src + (size_t)j * Dc + k),
                               *(const float4*)(src + (size_t)j * Dc + k + 4));
  } else {
    const size_t i = ((size_t)(b - 4096) * 256 + tid) * 8;
    const int e = (int)(i >> 18);
    const int d = (int)((i >> 8) & 1023);
    const int f = (int)(i & 255);
    *(u8v*)(wb_d + (size_t)d * EDE + e * DEc + f) =
        pack8(*(const float4*)(Wd + i), *(const float4*)(Wd + i + 4));
  }
}

// ---------------------------------------------------------------------------
// LayerNorm (+ optional fused router). One block per token row (D=1024).
// ---------------------------------------------------------------------------
template <int ROUTER>
__global__ __launch_bounds__(256)
void ln_kernel(const float* __restrict__ in, const float* __restrict__ g,
               const float* __restrict__ bt, ushort* __restrict__ out,
               const float* __restrict__ rw, const float* __restrict__ log_temp,
               float* __restrict__ wts) {
  const int row = blockIdx.x;
  const int tid = threadIdx.x;
  const float* xr = in + (size_t)row * Dc;
  float4 v = *(const float4*)(xr + tid * 4);
  float s  = v.x + v.y + v.z + v.w;
  float ss = v.x * v.x + v.y * v.y + v.z * v.z + v.w * v.w;
#pragma unroll
  for (int off = 32; off; off >>= 1) {
    s  += __shfl_xor(s, off);
    ss += __shfl_xor(ss, off);
  }
  __shared__ float red[8];
  const int w = tid >> 6;
  if ((tid & 63) == 0) { red[w] = s; red[4 + w] = ss; }
  __syncthreads();
  const float ts  = red[0] + red[1] + red[2] + red[3];
  const float tss = red[4] + red[5] + red[6] + red[7];
  const float mean = ts * (1.0f / Dc);
  const float var  = tss * (1.0f / Dc) - mean * mean;
  const float rstd = rsqrtf(var + 1e-5f);
  float4 gv = *(const float4*)(g + tid * 4);
  float4 bv = *(const float4*)(bt + tid * 4);
  const float n0 = (v.x - mean) * rstd * gv.x + bv.x;
  const float n1 = (v.y - mean) * rstd * gv.y + bv.y;
  const float n2 = (v.z - mean) * rstd * gv.z + bv.z;
  const float n3 = (v.w - mean) * rstd * gv.w + bv.w;
  u4v o;
  o[0] = f2bf(n0); o[1] = f2bf(n1); o[2] = f2bf(n2); o[3] = f2bf(n3);
  *(u4v*)(out + (size_t)row * Dc + tid * 4) = o;
  if constexpr (ROUTER) {
    float part[Ec];
#pragma unroll
    for (int e = 0; e < Ec; ++e) {
      float4 wv = *(const float4*)(rw + (size_t)e * Dc + tid * 4);
      part[e] = n0 * wv.x + n1 * wv.y + n2 * wv.z + n3 * wv.w;
    }
#pragma unroll
    for (int off = 32; off; off >>= 1) {
#pragma unroll
      for (int e = 0; e < Ec; ++e) part[e] += __shfl_xor(part[e], off);
    }
    __shared__ float red2[4][Ec];
    if ((tid & 63) == 0) {
#pragma unroll
      for (int e = 0; e < Ec; ++e) red2[w][e] = part[e];
    }
    __syncthreads();
    if (tid == 0) {
      const float lt = *log_temp;
      const float temp = log1pf(__expf(lt)) + 0.1f;
      float lg[Ec];
#pragma unroll
      for (int e = 0; e < Ec; ++e)
        lg[e] = (red2[0][e] + red2[1][e] + red2[2][e] + red2[3][e]) / temp;
      float m1 = -1e30f, m2 = -1e30f;
#pragma unroll
      for (int e = 0; e < Ec; ++e) {
        const float vv = lg[e];
        if (vv > m1) { m2 = m1; m1 = vv; }
        else if (vv > m2) { m2 = vv; }
      }
      float sl[Ec];
      float mx = -1e30f;
#pragma unroll
      for (int e = 0; e < Ec; ++e) {
        const float sup = 1.f / (1.f + __expf(-10.f * (lg[e] - m2)));
        sl[e] = lg[e] * sup;
        mx = fmaxf(mx, sl[e]);
      }
      float ssum = 0.f;
#pragma unroll
      for (int e = 0; e < Ec; ++e) {
        const float p = __expf(sl[e] - mx);
        sl[e] = p;
        ssum += p;
      }
      const float inv = 1.f / ssum;
#pragma unroll
      for (int e = 0; e < Ec; ++e) wts[(size_t)row * Ec + e] = sl[e] * inv;
    }
  }
}

// ---------------------------------------------------------------------------
// 256x256 8-phase bf16 GEMM (T3+T4): BK=64, 512 thr = 8 waves (2Mx4N),
// double-buffered 128KiB LDS, raw s_barrier + counted vmcnt.
// EPI: 0 = QKV scatter   4 = fused silu(gate)*up*wts (B row-interleaved)
// ---------------------------------------------------------------------------
template <int EPI>
__global__ __launch_bounds__(512, 2)
void gemm256(const ushort* __restrict__ A, int lda,
             const ushort* __restrict__ B,
             const float* __restrict__ bias,
             void* __restrict__ Cout, int K) {
  __shared__ __align__(16) ushort Asm[2][256 * 64];
  __shared__ __align__(16) ushort Bsm[2][256 * 64];
  const int tid = threadIdx.x;
  const int lane = tid & 63, w = tid >> 6;
  const int g = lane >> 4, c = lane & 15;
  const int wr = w >> 2, wc = w & 3;
  int bid = blockIdx.y * gridDim.x + blockIdx.x;
  const int qq = (gridDim.x * gridDim.y) >> 3;
  bid = (bid & 7) * qq + (bid >> 3);
  const int m0 = (bid / gridDim.x) * 256, n0 = (bid % gridDim.x) * 256;
  f4v acc[8][4];
#pragma unroll
  for (int i = 0; i < 8; ++i)
#pragma unroll
    for (int j = 0; j < 4; ++j) acc[i][j] = f4v{0.f, 0.f, 0.f, 0.f};

  const int srow = tid >> 3;                       // 0..63
  const int koff = 8 * ((tid & 7) ^ (srow & 7));   // pre-swizzled k slot

#define STAGE_A(buf, kt, i)                                                  \
  GLOAD_LDS(A + (size_t)(m0 + (i) * 64 + srow) * lda + (kt) * 64 + koff,     \
            &Asm[buf][((i) * 512 + tid) * 8])
#define STAGE_B(buf, kt, i)                                                  \
  GLOAD_LDS(B + (size_t)(n0 + (i) * 64 + srow) * K + (kt) * 64 + koff,       \
            &Bsm[buf][((i) * 512 + tid) * 8])

#define RD_A(buf, mi, ks)                                                    \
  (*(const s8v*)&Asm[buf][(wr * 128 + (mi) * 16 + c) * 64 +                  \
      8 * (((ks) * 4 + g) ^ ((wr * 128 + (mi) * 16 + c) & 7))])
#define RD_B(buf, ni, ks)                                                    \
  (*(const s8v*)&Bsm[buf][(wc * 64 + (ni) * 16 + c) * 64 +                   \
      8 * (((ks) * 4 + g) ^ ((wc * 64 + (ni) * 16 + c) & 7))])

  const int NT = K >> 6;
  STAGE_B(0, 0, 0); STAGE_B(0, 0, 1); STAGE_B(0, 0, 2); STAGE_B(0, 0, 3);
  STAGE_A(0, 0, 0); STAGE_A(0, 0, 2); STAGE_A(0, 0, 1); STAGE_A(0, 0, 3);
  asm volatile("s_waitcnt vmcnt(0)" ::: "memory");
  __builtin_amdgcn_s_barrier();

  for (int t = 0; t < NT; ++t) {
    const int cur = t & 1, nxt = cur ^ 1;
    const bool st = (t + 1 < NT);
    s8v bf[2][4], af[2][2];
#pragma unroll
    for (int ks = 0; ks < 2; ++ks) {
#pragma unroll
      for (int ni = 0; ni < 4; ++ni) bf[ks][ni] = RD_B(cur, ni, ks);
      af[ks][0] = RD_A(cur, 0, ks); af[ks][1] = RD_A(cur, 1, ks);
    }
    if (st) { STAGE_B(nxt, t + 1, 0); STAGE_B(nxt, t + 1, 1); }
    __builtin_amdgcn_s_barrier();
    __builtin_amdgcn_s_setprio(1);
#pragma unroll
    for (int ks = 0; ks < 2; ++ks)
#pragma unroll
      for (int q = 0; q < 2; ++q)
#pragma unroll
        for (int ni = 0; ni < 4; ++ni)
          acc[q][ni] = __builtin_amdgcn_mfma_f32_16x16x32_bf16(
              af[ks][q], bf[ks][ni], acc[q][ni], 0, 0, 0);
    __builtin_amdgcn_s_setprio(0);
    __builtin_amdgcn_s_barrier();
#pragma unroll
    for (int ks = 0; ks < 2; ++ks) {
      af[ks][0] = RD_A(cur, 2, ks); af[ks][1] = RD_A(cur, 3, ks);
    }
    if (st) { STAGE_B(nxt, t + 1, 2); STAGE_B(nxt, t + 1, 3); }
    __builtin_amdgcn_s_barrier();
    __builtin_amdgcn_s_setprio(1);
#pragma unroll
    for (int ks = 0; ks < 2; ++ks)
#pragma unroll
      for (int q = 0; q < 2; ++q)
#pragma unroll
        for (int ni = 0; ni < 4; ++ni)
          acc[2 + q][ni] = __builtin_amdgcn_mfma_f32_16x16x32_bf16(
              af[ks][q], bf[ks][ni], acc[2 + q][ni], 0, 0, 0);
    __builtin_amdgcn_s_setprio(0);
    if (st) asm volatile("s_waitcnt vmcnt(4)" ::: "memory");
    else    asm volatile("s_waitcnt vmcnt(0)" ::: "memory");
    __builtin_amdgcn_s_barrier();
#pragma unroll
    for (int ks = 0; ks < 2; ++ks) {
      af[ks][0] = RD_A(cur, 4, ks); af[ks][1] = RD_A(cur, 5, ks);
    }
    if (st) { STAGE_A(nxt, t + 1, 0); STAGE_A(nxt, t + 1, 2); }
    __builtin_amdgcn_s_barrier();
    __builtin_amdgcn_s_setprio(1);
#pragma unroll
    for (int ks = 0; ks < 2; ++ks)
#pragma unroll
      for (int q = 0; q < 2; ++q)
#pragma unroll
        for (int ni = 0; ni < 4; ++ni)
          acc[4 + q][ni] = __builtin_amdgcn_mfma_f32_16x16x32_bf16(
              af[ks][q], bf[ks][ni], acc[4 + q][ni], 0, 0, 0);
    __builtin_amdgcn_s_setprio(0);
    __builtin_amdgcn_s_barrier();
#pragma unroll
    for (int ks = 0; ks < 2; ++ks) {
      af[ks][0] = RD_A(cur, 6, ks); af[ks][1] = RD_A(cur, 7, ks);
    }
    if (st) { STAGE_A(nxt, t + 1, 1); STAGE_A(nxt, t + 1, 3); }
    __builtin_amdgcn_s_barrier();
    __builtin_amdgcn_s_setprio(1);
#pragma unroll
    for (int ks = 0; ks < 2; ++ks)
#pragma unroll
      for (int q = 0; q < 2; ++q)
#pragma unroll
        for (int ni = 0; ni < 4; ++ni)
          acc[6 + q][ni] = __builtin_amdgcn_mfma_f32_16x16x32_bf16(
              af[ks][q], bf[ks][ni], acc[6 + q][ni], 0, 0, 0);
    __builtin_amdgcn_s_setprio(0);
    if (st) asm volatile("s_waitcnt vmcnt(2)" ::: "memory");
    __builtin_amdgcn_s_barrier();
  }
#undef STAGE_A
#undef STAGE_B
#undef RD_A
#undef RD_B

#pragma unroll
  for (int mi = 0; mi < 8; ++mi) {
    if constexpr (EPI == 4) {  // fused act: ni pairs (gate, up)
#pragma unroll
      for (int nip = 0; nip < 2; ++nip) {
        const int jbase = ((n0 + wc * 64) >> 1) + nip * 16;
        const int e = jbase >> 8;
#pragma unroll
        for (int j = 0; j < 4; ++j) {
          const int row = m0 + wr * 128 + mi * 16 + g * 4 + j;
          const float wgt = bias[(size_t)row * Ec + e];  // bias = wts
          const float gv = acc[mi][2 * nip][j];
          const float uv = acc[mi][2 * nip + 1][j];
          const float av = (gv / (1.f + __expf(-gv))) * uv * wgt;
          ((ushort*)Cout)[(size_t)row * EDE + jbase + c] = f2bf(av);
        }
      }
    } else {  // EPI == 0: QKV scatter, head-major
#pragma unroll
      for (int ni = 0; ni < 4; ++ni) {
        const int col = n0 + wc * 64 + ni * 16 + c;
        const int which = col >> 10, hh = (col >> 6) & 15, d = col & 63;
        const int row0 = m0 + wr * 128 + mi * 16 + g * 4;
        const int b = row0 >> 11, t0 = row0 & 2047;
        const float bs = bias[col];
        ushort* base = (ushort*)Cout;
        if (which == 2) {  // V transposed: Vt[bh][d][t]
          u4v pk;
#pragma unroll
          for (int j = 0; j < 4; ++j) pk[j] = f2bf(acc[mi][ni][j] + bs);
          *(u4v*)&base[2 * (size_t)NTOK * Dc +
                       (((size_t)(b * Hc + hh)) * 64 + d) * Tc + t0] = pk;
        } else {
          const float qs = (which == 0) ? 0.125f * LOG2E : 1.f;
          const size_t off = (size_t)which * ((size_t)NTOK * Dc);
#pragma unroll
          for (int j = 0; j < 4; ++j)
            base[off + (((size_t)(b * Hc + hh)) * Tc + t0 + j) * 64 + d] =
                f2bf((acc[mi][ni][j] + bs) * qs);
        }
      }
    }
  }
}

// ---------------------------------------------------------------------------
// 128x128 m97-structure bf16 GEMM (kept for N=1024 shapes).
// EPI: 1 = fp32 +bias+resid   3 = fp32 accumulate
// ---------------------------------------------------------------------------
template <int EPI>
__global__ __launch_bounds__(256)
void gemm_bf16(const ushort* __restrict__ A, int lda,
               const ushort* __restrict__ B,
               const float* __restrict__ bias, const float* __restrict__ resid,
               void* __restrict__ Cout, int ldc, int K) {
  __shared__ __align__(16) ushort As[128 * 32];
  __shared__ __align__(16) ushort Bs[128 * 32];
  const int tid = threadIdx.x;
  const int lane = tid & 63, w = tid >> 6;
  const int g = lane >> 4, c = lane & 15;
  int bid = blockIdx.y * gridDim.x + blockIdx.x;
  const int qq = (gridDim.x * gridDim.y) >> 3;
  bid = (bid & 7) * qq + (bid >> 3);
  const int m0 = (bid / gridDim.x) * 128, n0 = (bid % gridDim.x) * 128;
  const int wm = (w >> 1) * 64, wn = (w & 1) * 64;
  f4v acc[4][4];
#pragma unroll
  for (int i = 0; i < 4; ++i)
#pragma unroll
    for (int j = 0; j < 4; ++j) acc[i][j] = f4v{0.f, 0.f, 0.f, 0.f};

  int srow[2], skoff[2];
#pragma unroll
  for (int seg = 0; seg < 2; ++seg) {
    const int ci = seg * 256 + tid;
    srow[seg] = ci >> 2;
    skoff[seg] = 8 * ((ci & 3) ^ ((srow[seg] >> 1) & 3));
  }

  for (int k0 = 0; k0 < K; k0 += 32) {
#pragma unroll
    for (int seg = 0; seg < 2; ++seg) {
      const int ci = seg * 256 + tid;
      GLOAD_LDS(A + (size_t)(m0 + srow[seg]) * lda + k0 + skoff[seg], &As[ci * 8]);
      GLOAD_LDS(B + (size_t)(n0 + srow[seg]) * K + k0 + skoff[seg], &Bs[ci * 8]);
    }
    __syncthreads();
    s8v af[4], bf[4];
#pragma unroll
    for (int mi = 0; mi < 4; ++mi) {
      const int R = wm + mi * 16 + c;
      af[mi] = *(const s8v*)&As[R * 32 + 8 * (g ^ ((R >> 1) & 3))];
    }
#pragma unroll
    for (int ni = 0; ni < 4; ++ni) {
      const int R = wn + ni * 16 + c;
      bf[ni] = *(const s8v*)&Bs[R * 32 + 8 * (g ^ ((R >> 1) & 3))];
    }
#pragma unroll
    for (int mi = 0; mi < 4; ++mi)
#pragma unroll
      for (int ni = 0; ni < 4; ++ni)
        acc[mi][ni] = __builtin_amdgcn_mfma_f32_16x16x32_bf16(
            af[mi], bf[ni], acc[mi][ni], 0, 0, 0);
    __syncthreads();
  }

#pragma unroll
  for (int mi = 0; mi < 4; ++mi) {
#pragma unroll
    for (int ni = 0; ni < 4; ++ni) {
#pragma unroll
      for (int j = 0; j < 4; ++j) {
        const int row = m0 + wm + mi * 16 + g * 4 + j;
        const int col = n0 + wn + ni * 16 + c;
        float v = acc[mi][ni][j];
        if constexpr (EPI == 1) {
          v += bias[col] + resid[(size_t)row * ldc + col];
          ((float*)Cout)[(size_t)row * ldc + col] = v;
        } else {
          ((float*)Cout)[(size_t)row * ldc + col] += v;
        }
      }
    }
  }
}

// ---------------------------------------------------------------------------
// MFMA flash attention: swapped 32x32, exp2-domain softmax, counted-vmcnt
// double-buffered staging. This round: (a) QK^T consumes a hoisted fzero as
// C (no per-chunk zero-init movs); (b) softmax denominator accumulated on
// the MATRIX pipe via a ones-A MFMA over the P fragments (sacc[0] = lsum),
// removing the 32-add VALU reduction chain per chunk.
// ---------------------------------------------------------------------------
__global__ __launch_bounds__(256)
void attn_mfma(const ushort* __restrict__ Qb, const ushort* __restrict__ Kb,
               const ushort* __restrict__ Vt, ushort* __restrict__ Ob) {
  __shared__ __align__(16) ushort Ksm[2][64 * 64];
  __shared__ __align__(16) ushort Vtsm[2][64 * 64];
  const int tid = threadIdx.x;
  const int lane = tid & 63, w = tid >> 6;
  const int ql = lane & 31, hi = lane >> 5;
  int bid = blockIdx.x;
  bid = (bid & 7) * 128 + (bid >> 3);
  const int qt = bid & 15, bh = bid >> 4;
  const ushort* Qh = Qb + (size_t)bh * Tc * 64;
  const ushort* Kh = Kb + (size_t)bh * Tc * 64;
  const ushort* Vth = Vt + (size_t)bh * 64 * Tc;
  const int qrow = qt * 128 + w * 32 + ql;
  s8v qf[4];
#pragma unroll
  for (int ds = 0; ds < 4; ++ds)
    qf[ds] = *(const s8v*)(Qh + (size_t)qrow * 64 + ds * 16 + hi * 8);
  f16v accO0, accO1, sacc;
#pragma unroll
  for (int i = 0; i < 16; ++i) { accO0[i] = 0.f; accO1[i] = 0.f; sacc[i] = 0.f; }
  f16v fzero;
#pragma unroll
  for (int i = 0; i < 16; ++i) fzero[i] = 0.f;
  s8v ones;   // bf16 1.0 pattern
#pragma unroll
  for (int i = 0; i < 8; ++i) ones[i] = (short)0x3F80;
  float mold = -1e30f;
  int srow[2], soff[2];
#pragma unroll
  for (int seg = 0; seg < 2; ++seg) {
    const int ci = seg * 256 + tid;
    srow[seg] = ci >> 3;
    soff[seg] = ((ci & 7) * 8) ^ ((srow[seg] & 7) << 3);
  }
  auto stage = [&](int buf, int j0) {
#pragma unroll
    for (int seg = 0; seg < 2; ++seg) {
      const int ci = seg * 256 + tid;
      GLOAD_LDS(Kh + (size_t)(j0 + srow[seg]) * 64 + soff[seg], &Ksm[buf][ci * 8]);
      GLOAD_LDS(Vth + (size_t)srow[seg] * Tc + j0 + soff[seg], &Vtsm[buf][ci * 8]);
    }
  };

  stage(0, 0);   // 4 loads in flight
  int cur = 0;
  for (int j0 = 0; j0 < Tc; j0 += 64) {
    const bool st = (j0 + 64 < Tc);
    if (st) {
      stage(cur ^ 1, j0 + 64);   // 4 more in flight (8 total)
      asm volatile("s_waitcnt vmcnt(4)" ::: "memory");  // cur tile ready
    } else {
      asm volatile("s_waitcnt vmcnt(0)" ::: "memory");
    }
    __builtin_amdgcn_s_barrier();   // all waves' cur-loads landed
    f16v s0, s1;
    __builtin_amdgcn_s_setprio(1);
#pragma unroll
    for (int ds = 0; ds < 4; ++ds) {
      const int col = (ds * 16 + hi * 8);
      const int r0 = ql;
      s8v kf0 = *(const s8v*)&Ksm[cur][r0 * 64 + (col ^ ((r0 & 7) << 3))];
      s0 = __builtin_amdgcn_mfma_f32_32x32x16_bf16(
          kf0, qf[ds], ds ? s0 : fzero, 0, 0, 0);
      const int r1 = 32 + ql;
      s8v kf1 = *(const s8v*)&Ksm[cur][r1 * 64 + (col ^ ((r1 & 7) << 3))];
      s1 = __builtin_amdgcn_mfma_f32_32x32x16_bf16(
          kf1, qf[ds], ds ? s1 : fzero, 0, 0, 0);
    }
    __builtin_amdgcn_s_setprio(0);
    float cc0 = fmaxf(s0[0], s1[0]), cc1 = fmaxf(s0[1], s1[1]);
    float cc2 = fmaxf(s0[2], s1[2]), cc3 = fmaxf(s0[3], s1[3]);
#pragma unroll
    for (int i = 4; i < 16; i += 4) {
      cc0 = max3f(cc0, s0[i + 0], s1[i + 0]);
      cc1 = max3f(cc1, s0[i + 1], s1[i + 1]);
      cc2 = max3f(cc2, s0[i + 2], s1[i + 2]);
      cc3 = max3f(cc3, s0[i + 3], s1[i + 3]);
    }
    float mx = pmax32(fmaxf(max3f(cc0, cc1, cc2), cc3));
    const bool need = mx > mold + 11.5416f;    // 8 * log2(e)
    if (__any((int)need)) {
      const float mnew = fmaxf(mold, mx);
      const float sc = exp2v(mold - mnew);
      sacc[0] *= sc;                 // only entry 0 is ever read
#pragma unroll
      for (int i = 0; i < 16; ++i) { accO0[i] *= sc; accO1[i] *= sc; }
      mold = mnew;
    }
#pragma unroll
    for (int i = 0; i < 16; ++i) {
      s0[i] = exp2v(s0[i] - mold);
      s1[i] = exp2v(s1[i] - mold);
    }
    // build P B-fragments in-register (cvt_pk + permlane32_swap)
    s8v pa[4];
#pragma unroll
    for (int s = 0; s < 4; ++s) {
      const f16v st2 = (s < 2) ? s0 : s1;
      const int mA = 2 * (s & 1);
      uint32_t a0 = cvtpk(st2[4 * mA + 0], st2[4 * mA + 1]);
      uint32_t a1 = cvtpk(st2[4 * mA + 2], st2[4 * mA + 3]);
      uint32_t b0 = cvtpk(st2[4 * mA + 4], st2[4 * mA + 5]);
      uint32_t b1 = cvtpk(st2[4 * mA + 6], st2[4 * mA + 7]);
      asm("v_permlane32_swap_b32 %0, %1" : "+v"(b0), "+v"(a0));
      asm("v_permlane32_swap_b32 %0, %1" : "+v"(b1), "+v"(a1));
      union { uint32_t u[4]; s8v v; } pk;
      pk.u[0] = a0; pk.u[1] = a1; pk.u[2] = b0; pk.u[3] = b1;
      pa[s] = pk.v;
    }
    // PV: O^T[d][q] += V^T P^T ; denominator via ones-A MFMA (row-sum of P)
    __builtin_amdgcn_s_setprio(1);
#pragma unroll
    for (int s = 0; s < 4; ++s) {
      const int col = (s * 16 + hi * 8);
      const int r0 = ql;
      s8v vf0 = *(const s8v*)&Vtsm[cur][r0 * 64 + (col ^ ((r0 & 7) << 3))];
      accO0 = __builtin_amdgcn_mfma_f32_32x32x16_bf16(vf0, pa[s], accO0, 0, 0, 0);
      const int r1 = 32 + ql;
      s8v vf1 = *(const s8v*)&Vtsm[cur][r1 * 64 + (col ^ ((r1 & 7) << 3))];
      accO1 = __builtin_amdgcn_mfma_f32_32x32x16_bf16(vf1, pa[s], accO1, 0, 0, 0);
      sacc = __builtin_amdgcn_mfma_f32_32x32x16_bf16(ones, pa[s], sacc, 0, 0, 0);
    }
    __builtin_amdgcn_s_setprio(0);
    __builtin_amdgcn_s_barrier();   // all waves done reading cur
    cur ^= 1;
  }
  const int h = bh & 15, b = bh >> 4;
  const int tok = b * Tc + qt * 128 + w * 32 + ql;
  const float inv = 1.f / sacc[0];
  ushort* orow = Ob + (size_t)tok * Dc + h * 64;
#pragma unroll
  for (int dt = 0; dt < 2; ++dt) {
    const f16v ac = dt ? accO1 : accO0;
#pragma unroll
    for (int rq = 0; rq < 4; ++rq) {
      u4v pk;
#pragma unroll
      for (int j = 0; j < 4; ++j) pk[j] = f2bf(ac[4 * rq + j] * inv);
      *(u4v*)&orow[dt * 32 + 8 * rq + 4 * hi] = pk;
    }
  }
}

// ---------------------------------------------------------------------------
extern "C" void kernel_launch(void* const* d_in, const int* in_sizes, int n_in,
                              void* d_out, int out_size, void* d_ws, size_t ws_size,
                              hipStream_t stream) {
  (void)in_sizes; (void)n_in; (void)out_size; (void)ws_size;
  const float* x        = (const float*)d_in[0];
  const float* ln1_g    = (const float*)d_in[1];
  const float* ln1_b    = (const float*)d_in[2];
  const float* in_w     = (const float*)d_in[3];
  const float* in_b     = (const float*)d_in[4];
  const float* out_w    = (const float*)d_in[5];
  const float* out_b    = (const float*)d_in[6];
  const float* ln2_g    = (const float*)d_in[7];
  const float* ln2_b    = (const float*)d_in[8];
  const float* rw       = (const float*)d_in[9];
  const float* log_temp = (const float*)d_in[10];
  const float* Wg       = (const float*)d_in[11];
  const float* Wu       = (const float*)d_in[12];
  const float* Wd       = (const float*)d_in[13];
  float* out = (float*)d_out;

  // Workspace (ushorts), total ~138 MiB:
  ushort* h_bf   = (ushort*)d_ws;                       // NTOK*1024   16 MiB
  ushort* Qb     = h_bf   + (size_t)NTOK * Dc;          // 16 MiB
  ushort* Kb     = Qb     + (size_t)NTOK * Dc;          // 16 MiB
  ushort* Vt     = Kb     + (size_t)NTOK * Dc;          // 16 MiB ([bh][d][t])
  ushort* Ob     = Vt     + (size_t)NTOK * Dc;          // 16 MiB
  ushort* act    = Ob     + (size_t)NTOK * Dc;          // NTOK*2048   32 MiB
  ushort* wb_in  = act    + (size_t)NTOK * EDE;         // 3072*1024    6 MiB
  ushort* wb_out = wb_in  + (size_t)3 * Dc * Dc;        // 1024*1024    2 MiB
  ushort* wb_gu  = wb_out + (size_t)Dc * Dc;            // 4096*1024    8 MiB
  ushort* wb_d   = wb_gu  + (size_t)2 * EDE * Dc;       // 1024*2048    4 MiB
  float*  wts    = (float*)(wb_d + (size_t)Dc * EDE);   // NTOK*8     0.25 MiB

  const dim3 blk(256);

  // 0. all weight conversions in one launch
  convert_all<<<dim3(5120), blk, 0, stream>>>(
      in_w, out_w, Wg, Wu, Wd, wb_in, wb_out, wb_gu, wb_d);

  // 1. LN1: x -> h_bf (bf16)
  ln_kernel<0><<<dim3(NTOK), blk, 0, stream>>>(x, ln1_g, ln1_b, h_bf,
                                               nullptr, nullptr, nullptr);
  // 2. QKV GEMM (256^2 8-phase) -> head-major Q(x0.125*log2e)/K + V^T
  gemm256<0><<<dim3(3 * Dc / 256, NTOK / 256), dim3(512), 0, stream>>>(
      h_bf, Dc, wb_in, in_b, Qb, Dc);
  // 3. MFMA attention -> Ob bf16
  attn_mfma<<<dim3(Bc * Hc * (Tc / 128)), blk, 0, stream>>>(Qb, Kb, Vt, Ob);
  // 4. out proj + bias + residual(x) -> out fp32 (128^2)
  gemm_bf16<1><<<dim3(Dc / 128, NTOK / 128), blk, 0, stream>>>(
      Ob, Dc, wb_out, out_b, x, out, Dc, Dc);
  // 5. LN2 + fused router: out -> h_bf (h2), wts
  ln_kernel<1><<<dim3(NTOK), blk, 0, stream>>>(out, ln2_g, ln2_b, h_bf,
                                               rw, log_temp, wts);
  // 6. fused gate+up GEMM (256^2 8-phase) + silu*up*wts -> act bf16
  gemm256<4><<<dim3(2 * EDE / 256, NTOK / 256), dim3(512), 0, stream>>>(
      h_bf, Dc, wb_gu, wts, act, Dc);
  // 7. single down GEMM (128^2, K=2048), += into out
  gemm_bf16<3><<<dim3(Dc / 128, NTOK / 128), blk, 0, stream>>>(
      act, EDE, wb_d, nullptr, nullptr, out, Dc, EDE);
}

// Round 11
// 402.925 us; speedup vs baseline: 1.0210x; 1.0210x over previous
//
#include <hip/hip_runtime.h>
#include <hip/hip_bf16.h>
#include <cstddef>
#include <cstdint>

// Problem constants (match reference)
constexpr int Bc  = 4;
constexpr int Tc  = 2048;
constexpr int Dc  = 1024;
constexpr int Hc  = 16;
constexpr int Ec  = 8;     // experts
constexpr int DEc = 256;   // expert dim
constexpr int NTOK = Bc * Tc;          // 8192 tokens
constexpr int EDE = Ec * DEc;          // 2048

typedef __attribute__((ext_vector_type(8)))  short  s8v;   // 8 bf16 (4 VGPRs)
typedef __attribute__((ext_vector_type(4)))  float  f4v;   // 16x16 MFMA C/D
typedef __attribute__((ext_vector_type(16))) float  f16v;  // 32x32 MFMA C/D
typedef __attribute__((ext_vector_type(8)))  ushort u8v;
typedef __attribute__((ext_vector_type(4)))  ushort u4v;

constexpr float LOG2E = 1.44269504088896340736f;

__device__ inline ushort f2bf(float f) {  // fp32 -> bf16 bits, RNE
  union { float f; uint32_t u; } v; v.f = f;
  uint32_t r = v.u + 0x7FFFu + ((v.u >> 16) & 1u);
  return (ushort)(r >> 16);
}
__device__ inline float exp2v(float x) {   // 2^x on the TRANS pipe
  float r; asm("v_exp_f32 %0, %1" : "=v"(r) : "v"(x)); return r;
}
__device__ inline float max3f(float a, float b, float c) {
  return fmaxf(fmaxf(a, b), c);             // clang fuses to v_max3_f32
}
// pair-reduce lane l <-> l^32 without DS ops (pure VALU)
__device__ inline float pmax32(float x) {
  float a = x, b = x;
  asm("v_permlane32_swap_b32 %0, %1" : "+v"(b), "+v"(a));
  return fmaxf(a, b);
}
__device__ inline float psum32(float x) {
  float a = x, b = x;
  asm("v_permlane32_swap_b32 %0, %1" : "+v"(b), "+v"(a));
  return a + b;
}

// async global->LDS, 16B per lane; LDS dest = wave-uniform base + lane*16
#define GLOAD_LDS(gsrc, ldst)                                        \
  __builtin_amdgcn_global_load_lds(                                  \
      (const __attribute__((address_space(1))) void*)(gsrc),         \
      (__attribute__((address_space(3))) void*)(ldst), 16, 0, 0)

// pack 2 f32 -> 1 u32 of 2 bf16 (lo = a, hi = b), RNE
__device__ inline uint32_t cvtpk(float a, float b) {
  uint32_t r;
  asm("v_cvt_pk_bf16_f32 %0, %1, %2" : "=v"(r) : "v"(a), "v"(b));
  return r;
}

__device__ inline u8v pack8(const float4& a, const float4& b) {
  u8v o;
  o[0] = f2bf(a.x); o[1] = f2bf(a.y); o[2] = f2bf(a.z); o[3] = f2bf(a.w);
  o[4] = f2bf(b.x); o[5] = f2bf(b.y); o[6] = f2bf(b.z); o[7] = f2bf(b.w);
  return o;
}

// ---------------------------------------------------------------------------
// Single fused weight-convert kernel (block-range dispatch)
// ---------------------------------------------------------------------------
__global__ __launch_bounds__(256)
void convert_all(const float* __restrict__ in_w, const float* __restrict__ out_w,
                 const float* __restrict__ Wg, const float* __restrict__ Wu,
                 const float* __restrict__ Wd,
                 ushort* __restrict__ wb_in, ushort* __restrict__ wb_out,
                 ushort* __restrict__ wb_gu, ushort* __restrict__ wb_d) {
  const int b = blockIdx.x;
  const int tid = threadIdx.x;
  if (b < 1536) {
    const size_t i = ((size_t)b * 256 + tid) * 8;
    *(u8v*)(wb_in + i) = pack8(*(const float4*)(in_w + i),
                               *(const float4*)(in_w + i + 4));
  } else if (b < 2048) {
    const size_t i = ((size_t)(b - 1536) * 256 + tid) * 8;
    *(u8v*)(wb_out + i) = pack8(*(const float4*)(out_w + i),
                                *(const float4*)(out_w + i + 4));
  } else if (b < 4096) {
    const size_t i = ((size_t)(b - 2048) * 256 + tid) * 8;
    const int r = (int)(i >> 10), k = (int)(i & 1023);
    const int j = ((r >> 5) << 4) + (r & 15);
    const float* src = (r & 16) ? Wu : Wg;
    *(u8v*)(wb_gu + i) = pack8(*(const float4*)(src + (size_t)j * Dc + k),
                               *(const float4*)(src + (size_t)j * Dc + k + 4));
  } else {
    const size_t i = ((size_t)(b - 4096) * 256 + tid) * 8;
    const int e = (int)(i >> 18);
    const int d = (int)((i >> 8) & 1023);
    const int f = (int)(i & 255);
    *(u8v*)(wb_d + (size_t)d * EDE + e * DEc + f) =
        pack8(*(const float4*)(Wd + i), *(const float4*)(Wd + i + 4));
  }
}

// ---------------------------------------------------------------------------
// LayerNorm (+ optional fused router). One block per token row (D=1024).
// ---------------------------------------------------------------------------
template <int ROUTER>
__global__ __launch_bounds__(256)
void ln_kernel(const float* __restrict__ in, const float* __restrict__ g,
               const float* __restrict__ bt, ushort* __restrict__ out,
               const float* __restrict__ rw, const float* __restrict__ log_temp,
               float* __restrict__ wts) {
  const int row = blockIdx.x;
  const int tid = threadIdx.x;
  const float* xr = in + (size_t)row * Dc;
  float4 v = *(const float4*)(xr + tid * 4);
  float s  = v.x + v.y + v.z + v.w;
  float ss = v.x * v.x + v.y * v.y + v.z * v.z + v.w * v.w;
#pragma unroll
  for (int off = 32; off; off >>= 1) {
    s  += __shfl_xor(s, off);
    ss += __shfl_xor(ss, off);
  }
  __shared__ float red[8];
  const int w = tid >> 6;
  if ((tid & 63) == 0) { red[w] = s; red[4 + w] = ss; }
  __syncthreads();
  const float ts  = red[0] + red[1] + red[2] + red[3];
  const float tss = red[4] + red[5] + red[6] + red[7];
  const float mean = ts * (1.0f / Dc);
  const float var  = tss * (1.0f / Dc) - mean * mean;
  const float rstd = rsqrtf(var + 1e-5f);
  float4 gv = *(const float4*)(g + tid * 4);
  float4 bv = *(const float4*)(bt + tid * 4);
  const float n0 = (v.x - mean) * rstd * gv.x + bv.x;
  const float n1 = (v.y - mean) * rstd * gv.y + bv.y;
  const float n2 = (v.z - mean) * rstd * gv.z + bv.z;
  const float n3 = (v.w - mean) * rstd * gv.w + bv.w;
  u4v o;
  o[0] = f2bf(n0); o[1] = f2bf(n1); o[2] = f2bf(n2); o[3] = f2bf(n3);
  *(u4v*)(out + (size_t)row * Dc + tid * 4) = o;
  if constexpr (ROUTER) {
    float part[Ec];
#pragma unroll
    for (int e = 0; e < Ec; ++e) {
      float4 wv = *(const float4*)(rw + (size_t)e * Dc + tid * 4);
      part[e] = n0 * wv.x + n1 * wv.y + n2 * wv.z + n3 * wv.w;
    }
#pragma unroll
    for (int off = 32; off; off >>= 1) {
#pragma unroll
      for (int e = 0; e < Ec; ++e) part[e] += __shfl_xor(part[e], off);
    }
    __shared__ float red2[4][Ec];
    if ((tid & 63) == 0) {
#pragma unroll
      for (int e = 0; e < Ec; ++e) red2[w][e] = part[e];
    }
    __syncthreads();
    if (tid == 0) {
      const float lt = *log_temp;
      const float temp = log1pf(__expf(lt)) + 0.1f;
      float lg[Ec];
#pragma unroll
      for (int e = 0; e < Ec; ++e)
        lg[e] = (red2[0][e] + red2[1][e] + red2[2][e] + red2[3][e]) / temp;
      float m1 = -1e30f, m2 = -1e30f;
#pragma unroll
      for (int e = 0; e < Ec; ++e) {
        const float vv = lg[e];
        if (vv > m1) { m2 = m1; m1 = vv; }
        else if (vv > m2) { m2 = vv; }
      }
      float sl[Ec];
      float mx = -1e30f;
#pragma unroll
      for (int e = 0; e < Ec; ++e) {
        const float sup = 1.f / (1.f + __expf(-10.f * (lg[e] - m2)));
        sl[e] = lg[e] * sup;
        mx = fmaxf(mx, sl[e]);
      }
      float ssum = 0.f;
#pragma unroll
      for (int e = 0; e < Ec; ++e) {
        const float p = __expf(sl[e] - mx);
        sl[e] = p;
        ssum += p;
      }
      const float inv = 1.f / ssum;
#pragma unroll
      for (int e = 0; e < Ec; ++e) wts[(size_t)row * Ec + e] = sl[e] * inv;
    }
  }
}

// ---------------------------------------------------------------------------
// 256x256 8-phase bf16 GEMM (T3+T4): BK=64, 512 thr = 8 waves (2Mx4N),
// double-buffered 128KiB LDS, raw s_barrier + counted vmcnt.
// EPI: 0 = QKV scatter   4 = fused silu(gate)*up*wts (B row-interleaved)
// ---------------------------------------------------------------------------
template <int EPI>
__global__ __launch_bounds__(512, 2)
void gemm256(const ushort* __restrict__ A, int lda,
             const ushort* __restrict__ B,
             const float* __restrict__ bias,
             void* __restrict__ Cout, int K) {
  __shared__ __align__(16) ushort Asm[2][256 * 64];
  __shared__ __align__(16) ushort Bsm[2][256 * 64];
  const int tid = threadIdx.x;
  const int lane = tid & 63, w = tid >> 6;
  const int g = lane >> 4, c = lane & 15;
  const int wr = w >> 2, wc = w & 3;
  int bid = blockIdx.y * gridDim.x + blockIdx.x;
  const int qq = (gridDim.x * gridDim.y) >> 3;
  bid = (bid & 7) * qq + (bid >> 3);
  const int m0 = (bid / gridDim.x) * 256, n0 = (bid % gridDim.x) * 256;
  f4v acc[8][4];
#pragma unroll
  for (int i = 0; i < 8; ++i)
#pragma unroll
    for (int j = 0; j < 4; ++j) acc[i][j] = f4v{0.f, 0.f, 0.f, 0.f};

  const int srow = tid >> 3;                       // 0..63
  const int koff = 8 * ((tid & 7) ^ (srow & 7));   // pre-swizzled k slot

#define STAGE_A(buf, kt, i)                                                  \
  GLOAD_LDS(A + (size_t)(m0 + (i) * 64 + srow) * lda + (kt) * 64 + koff,     \
            &Asm[buf][((i) * 512 + tid) * 8])
#define STAGE_B(buf, kt, i)                                                  \
  GLOAD_LDS(B + (size_t)(n0 + (i) * 64 + srow) * K + (kt) * 64 + koff,       \
            &Bsm[buf][((i) * 512 + tid) * 8])

#define RD_A(buf, mi, ks)                                                    \
  (*(const s8v*)&Asm[buf][(wr * 128 + (mi) * 16 + c) * 64 +                  \
      8 * (((ks) * 4 + g) ^ ((wr * 128 + (mi) * 16 + c) & 7))])
#define RD_B(buf, ni, ks)                                                    \
  (*(const s8v*)&Bsm[buf][(wc * 64 + (ni) * 16 + c) * 64 +                   \
      8 * (((ks) * 4 + g) ^ ((wc * 64 + (ni) * 16 + c) & 7))])

  const int NT = K >> 6;
  STAGE_B(0, 0, 0); STAGE_B(0, 0, 1); STAGE_B(0, 0, 2); STAGE_B(0, 0, 3);
  STAGE_A(0, 0, 0); STAGE_A(0, 0, 2); STAGE_A(0, 0, 1); STAGE_A(0, 0, 3);
  asm volatile("s_waitcnt vmcnt(0)" ::: "memory");
  __builtin_amdgcn_s_barrier();

  for (int t = 0; t < NT; ++t) {
    const int cur = t & 1, nxt = cur ^ 1;
    const bool st = (t + 1 < NT);
    s8v bf[2][4], af[2][2];
#pragma unroll
    for (int ks = 0; ks < 2; ++ks) {
#pragma unroll
      for (int ni = 0; ni < 4; ++ni) bf[ks][ni] = RD_B(cur, ni, ks);
      af[ks][0] = RD_A(cur, 0, ks); af[ks][1] = RD_A(cur, 1, ks);
    }
    if (st) { STAGE_B(nxt, t + 1, 0); STAGE_B(nxt, t + 1, 1); }
    __builtin_amdgcn_s_barrier();
    __builtin_amdgcn_s_setprio(1);
#pragma unroll
    for (int ks = 0; ks < 2; ++ks)
#pragma unroll
      for (int q = 0; q < 2; ++q)
#pragma unroll
        for (int ni = 0; ni < 4; ++ni)
          acc[q][ni] = __builtin_amdgcn_mfma_f32_16x16x32_bf16(
              af[ks][q], bf[ks][ni], acc[q][ni], 0, 0, 0);
    __builtin_amdgcn_s_setprio(0);
    __builtin_amdgcn_s_barrier();
#pragma unroll
    for (int ks = 0; ks < 2; ++ks) {
      af[ks][0] = RD_A(cur, 2, ks); af[ks][1] = RD_A(cur, 3, ks);
    }
    if (st) { STAGE_B(nxt, t + 1, 2); STAGE_B(nxt, t + 1, 3); }
    __builtin_amdgcn_s_barrier();
    __builtin_amdgcn_s_setprio(1);
#pragma unroll
    for (int ks = 0; ks < 2; ++ks)
#pragma unroll
      for (int q = 0; q < 2; ++q)
#pragma unroll
        for (int ni = 0; ni < 4; ++ni)
          acc[2 + q][ni] = __builtin_amdgcn_mfma_f32_16x16x32_bf16(
              af[ks][q], bf[ks][ni], acc[2 + q][ni], 0, 0, 0);
    __builtin_amdgcn_s_setprio(0);
    if (st) asm volatile("s_waitcnt vmcnt(4)" ::: "memory");
    else    asm volatile("s_waitcnt vmcnt(0)" ::: "memory");
    __builtin_amdgcn_s_barrier();
#pragma unroll
    for (int ks = 0; ks < 2; ++ks) {
      af[ks][0] = RD_A(cur, 4, ks); af[ks][1] = RD_A(cur, 5, ks);
    }
    if (st) { STAGE_A(nxt, t + 1, 0); STAGE_A(nxt, t + 1, 2); }
    __builtin_amdgcn_s_barrier();
    __builtin_amdgcn_s_setprio(1);
#pragma unroll
    for (int ks = 0; ks < 2; ++ks)
#pragma unroll
      for (int q = 0; q < 2; ++q)
#pragma unroll
        for (int ni = 0; ni < 4; ++ni)
          acc[4 + q][ni] = __builtin_amdgcn_mfma_f32_16x16x32_bf16(
              af[ks][q], bf[ks][ni], acc[4 + q][ni], 0, 0, 0);
    __builtin_amdgcn_s_setprio(0);
    __builtin_amdgcn_s_barrier();
#pragma unroll
    for (int ks = 0; ks < 2; ++ks) {
      af[ks][0] = RD_A(cur, 6, ks); af[ks][1] = RD_A(cur, 7, ks);
    }
    if (st) { STAGE_A(nxt, t + 1, 1); STAGE_A(nxt, t + 1, 3); }
    __builtin_amdgcn_s_barrier();
    __builtin_amdgcn_s_setprio(1);
#pragma unroll
    for (int ks = 0; ks < 2; ++ks)
#pragma unroll
      for (int q = 0; q < 2; ++q)
#pragma unroll
        for (int ni = 0; ni < 4; ++ni)
          acc[6 + q][ni] = __builtin_amdgcn_mfma_f32_16x16x32_bf16(
              af[ks][q], bf[ks][ni], acc[6 + q][ni], 0, 0, 0);
    __builtin_amdgcn_s_setprio(0);
    if (st) asm volatile("s_waitcnt vmcnt(2)" ::: "memory");
    __builtin_amdgcn_s_barrier();
  }
#undef STAGE_A
#undef STAGE_B
#undef RD_A
#undef RD_B

#pragma unroll
  for (int mi = 0; mi < 8; ++mi) {
    if constexpr (EPI == 4) {  // fused act: ni pairs (gate, up)
#pragma unroll
      for (int nip = 0; nip < 2; ++nip) {
        const int jbase = ((n0 + wc * 64) >> 1) + nip * 16;
        const int e = jbase >> 8;
#pragma unroll
        for (int j = 0; j < 4; ++j) {
          const int row = m0 + wr * 128 + mi * 16 + g * 4 + j;
          const float wgt = bias[(size_t)row * Ec + e];  // bias = wts
          const float gv = acc[mi][2 * nip][j];
          const float uv = acc[mi][2 * nip + 1][j];
          const float av = (gv / (1.f + __expf(-gv))) * uv * wgt;
          ((ushort*)Cout)[(size_t)row * EDE + jbase + c] = f2bf(av);
        }
      }
    } else {  // EPI == 0: QKV scatter, head-major
#pragma unroll
      for (int ni = 0; ni < 4; ++ni) {
        const int col = n0 + wc * 64 + ni * 16 + c;
        const int which = col >> 10, hh = (col >> 6) & 15, d = col & 63;
        const int row0 = m0 + wr * 128 + mi * 16 + g * 4;
        const int b = row0 >> 11, t0 = row0 & 2047;
        const float bs = bias[col];
        ushort* base = (ushort*)Cout;
        if (which == 2) {  // V transposed: Vt[bh][d][t]
          u4v pk;
#pragma unroll
          for (int j = 0; j < 4; ++j) pk[j] = f2bf(acc[mi][ni][j] + bs);
          *(u4v*)&base[2 * (size_t)NTOK * Dc +
                       (((size_t)(b * Hc + hh)) * 64 + d) * Tc + t0] = pk;
        } else {
          const float qs = (which == 0) ? 0.125f * LOG2E : 1.f;
          const size_t off = (size_t)which * ((size_t)NTOK * Dc);
#pragma unroll
          for (int j = 0; j < 4; ++j)
            base[off + (((size_t)(b * Hc + hh)) * Tc + t0 + j) * 64 + d] =
                f2bf((acc[mi][ni][j] + bs) * qs);
        }
      }
    }
  }
}

// ---------------------------------------------------------------------------
// 128x128 bf16 GEMM, now 2-phase double-buffered (T3-minimum): stage next
// K-step before computing the current one; raw s_barrier + counted vmcnt(4)
// (the attn-validated pattern) instead of the __syncthreads vmcnt(0) drain.
// EPI: 1 = fp32 +bias+resid   3 = fp32 accumulate
// ---------------------------------------------------------------------------
template <int EPI>
__global__ __launch_bounds__(256)
void gemm_bf16(const ushort* __restrict__ A, int lda,
               const ushort* __restrict__ B,
               const float* __restrict__ bias, const float* __restrict__ resid,
               void* __restrict__ Cout, int ldc, int K) {
  __shared__ __align__(16) ushort As[2][128 * 32];
  __shared__ __align__(16) ushort Bs[2][128 * 32];
  const int tid = threadIdx.x;
  const int lane = tid & 63, w = tid >> 6;
  const int g = lane >> 4, c = lane & 15;
  int bid = blockIdx.y * gridDim.x + blockIdx.x;
  const int qq = (gridDim.x * gridDim.y) >> 3;
  bid = (bid & 7) * qq + (bid >> 3);
  const int m0 = (bid / gridDim.x) * 128, n0 = (bid % gridDim.x) * 128;
  const int wm = (w >> 1) * 64, wn = (w & 1) * 64;
  f4v acc[4][4];
#pragma unroll
  for (int i = 0; i < 4; ++i)
#pragma unroll
    for (int j = 0; j < 4; ++j) acc[i][j] = f4v{0.f, 0.f, 0.f, 0.f};

  int srow[2], skoff[2];
#pragma unroll
  for (int seg = 0; seg < 2; ++seg) {
    const int ci = seg * 256 + tid;
    srow[seg] = ci >> 2;
    skoff[seg] = 8 * ((ci & 3) ^ ((srow[seg] >> 1) & 3));
  }
  auto stage = [&](int buf, int k0) {
#pragma unroll
    for (int seg = 0; seg < 2; ++seg) {
      const int ci = seg * 256 + tid;
      GLOAD_LDS(A + (size_t)(m0 + srow[seg]) * lda + k0 + skoff[seg],
                &As[buf][ci * 8]);
      GLOAD_LDS(B + (size_t)(n0 + srow[seg]) * K + k0 + skoff[seg],
                &Bs[buf][ci * 8]);
    }
  };

  stage(0, 0);   // 4 loads in flight
  int curb = 0;
  for (int k0 = 0; k0 < K; k0 += 32) {
    const bool st = (k0 + 32 < K);
    if (st) {
      stage(curb ^ 1, k0 + 32);   // 8 in flight
      asm volatile("s_waitcnt vmcnt(4)" ::: "memory");  // cur tile landed
    } else {
      asm volatile("s_waitcnt vmcnt(0)" ::: "memory");
    }
    __builtin_amdgcn_s_barrier();
    s8v af[4], bf[4];
#pragma unroll
    for (int mi = 0; mi < 4; ++mi) {
      const int R = wm + mi * 16 + c;
      af[mi] = *(const s8v*)&As[curb][R * 32 + 8 * (g ^ ((R >> 1) & 3))];
    }
#pragma unroll
    for (int ni = 0; ni < 4; ++ni) {
      const int R = wn + ni * 16 + c;
      bf[ni] = *(const s8v*)&Bs[curb][R * 32 + 8 * (g ^ ((R >> 1) & 3))];
    }
    __builtin_amdgcn_s_setprio(1);
#pragma unroll
    for (int mi = 0; mi < 4; ++mi)
#pragma unroll
      for (int ni = 0; ni < 4; ++ni)
        acc[mi][ni] = __builtin_amdgcn_mfma_f32_16x16x32_bf16(
            af[mi], bf[ni], acc[mi][ni], 0, 0, 0);
    __builtin_amdgcn_s_setprio(0);
    __builtin_amdgcn_s_barrier();   // all waves done reading curb
    curb ^= 1;
  }

#pragma unroll
  for (int mi = 0; mi < 4; ++mi) {
#pragma unroll
    for (int ni = 0; ni < 4; ++ni) {
#pragma unroll
      for (int j = 0; j < 4; ++j) {
        const int row = m0 + wm + mi * 16 + g * 4 + j;
        const int col = n0 + wn + ni * 16 + c;
        float v = acc[mi][ni][j];
        if constexpr (EPI == 1) {
          v += bias[col] + resid[(size_t)row * ldc + col];
          ((float*)Cout)[(size_t)row * ldc + col] = v;
        } else {
          ((float*)Cout)[(size_t)row * ldc + col] += v;
        }
      }
    }
  }
}

// ---------------------------------------------------------------------------
// MFMA flash attention (round-8 version, measured 124 us): swapped 32x32,
// exp2-domain softmax, counted-vmcnt double-buffered staging. The ones-MFMA
// denominator experiment (round 10) regressed (+16 VGPR, +4.5 us) — reverted.
// ---------------------------------------------------------------------------
__global__ __launch_bounds__(256)
void attn_mfma(const ushort* __restrict__ Qb, const ushort* __restrict__ Kb,
               const ushort* __restrict__ Vt, ushort* __restrict__ Ob) {
  __shared__ __align__(16) ushort Ksm[2][64 * 64];
  __shared__ __align__(16) ushort Vtsm[2][64 * 64];
  const int tid = threadIdx.x;
  const int lane = tid & 63, w = tid >> 6;
  const int ql = lane & 31, hi = lane >> 5;
  int bid = blockIdx.x;
  bid = (bid & 7) * 128 + (bid >> 3);
  const int qt = bid & 15, bh = bid >> 4;
  const ushort* Qh = Qb + (size_t)bh * Tc * 64;
  const ushort* Kh = Kb + (size_t)bh * Tc * 64;
  const ushort* Vth = Vt + (size_t)bh * 64 * Tc;
  const int qrow = qt * 128 + w * 32 + ql;
  s8v qf[4];
#pragma unroll
  for (int ds = 0; ds < 4; ++ds)
    qf[ds] = *(const s8v*)(Qh + (size_t)qrow * 64 + ds * 16 + hi * 8);
  f16v accO0, accO1;
#pragma unroll
  for (int i = 0; i < 16; ++i) { accO0[i] = 0.f; accO1[i] = 0.f; }
  float mold = -1e30f, lsum = 0.f;
  int srow[2], soff[2];
#pragma unroll
  for (int seg = 0; seg < 2; ++seg) {
    const int ci = seg * 256 + tid;
    srow[seg] = ci >> 3;
    soff[seg] = ((ci & 7) * 8) ^ ((srow[seg] & 7) << 3);
  }
  auto stage = [&](int buf, int j0) {
#pragma unroll
    for (int seg = 0; seg < 2; ++seg) {
      const int ci = seg * 256 + tid;
      GLOAD_LDS(Kh + (size_t)(j0 + srow[seg]) * 64 + soff[seg], &Ksm[buf][ci * 8]);
      GLOAD_LDS(Vth + (size_t)srow[seg] * Tc + j0 + soff[seg], &Vtsm[buf][ci * 8]);
    }
  };

  stage(0, 0);   // 4 loads in flight
  int cur = 0;
  for (int j0 = 0; j0 < Tc; j0 += 64) {
    const bool st = (j0 + 64 < Tc);
    if (st) {
      stage(cur ^ 1, j0 + 64);   // 4 more in flight (8 total)
      asm volatile("s_waitcnt vmcnt(4)" ::: "memory");  // cur tile ready
    } else {
      asm volatile("s_waitcnt vmcnt(0)" ::: "memory");
    }
    __builtin_amdgcn_s_barrier();   // all waves' cur-loads landed
    f16v s0, s1;
#pragma unroll
    for (int i = 0; i < 16; ++i) { s0[i] = 0.f; s1[i] = 0.f; }
    __builtin_amdgcn_s_setprio(1);
#pragma unroll
    for (int ds = 0; ds < 4; ++ds) {
      const int col = (ds * 16 + hi * 8);
      const int r0 = ql;
      s8v kf0 = *(const s8v*)&Ksm[cur][r0 * 64 + (col ^ ((r0 & 7) << 3))];
      s0 = __builtin_amdgcn_mfma_f32_32x32x16_bf16(kf0, qf[ds], s0, 0, 0, 0);
      const int r1 = 32 + ql;
      s8v kf1 = *(const s8v*)&Ksm[cur][r1 * 64 + (col ^ ((r1 & 7) << 3))];
      s1 = __builtin_amdgcn_mfma_f32_32x32x16_bf16(kf1, qf[ds], s1, 0, 0, 0);
    }
    __builtin_amdgcn_s_setprio(0);
    float cc0 = fmaxf(s0[0], s1[0]), cc1 = fmaxf(s0[1], s1[1]);
    float cc2 = fmaxf(s0[2], s1[2]), cc3 = fmaxf(s0[3], s1[3]);
#pragma unroll
    for (int i = 4; i < 16; i += 4) {
      cc0 = max3f(cc0, s0[i + 0], s1[i + 0]);
      cc1 = max3f(cc1, s0[i + 1], s1[i + 1]);
      cc2 = max3f(cc2, s0[i + 2], s1[i + 2]);
      cc3 = max3f(cc3, s0[i + 3], s1[i + 3]);
    }
    float mx = pmax32(fmaxf(max3f(cc0, cc1, cc2), cc3));
    const bool need = mx > mold + 11.5416f;    // 8 * log2(e)
    if (__any((int)need)) {
      const float mnew = fmaxf(mold, mx);
      const float sc = exp2v(mold - mnew);
      lsum *= sc;
#pragma unroll
      for (int i = 0; i < 16; ++i) { accO0[i] *= sc; accO1[i] *= sc; }
      mold = mnew;
    }
    float r0s = 0.f, r1s = 0.f, r2s = 0.f, r3s = 0.f;
#pragma unroll
    for (int i = 0; i < 16; i += 4) {
      s0[i+0] = exp2v(s0[i+0] - mold); r0s += s0[i+0];
      s0[i+1] = exp2v(s0[i+1] - mold); r1s += s0[i+1];
      s0[i+2] = exp2v(s0[i+2] - mold); r2s += s0[i+2];
      s0[i+3] = exp2v(s0[i+3] - mold); r3s += s0[i+3];
      s1[i+0] = exp2v(s1[i+0] - mold); r0s += s1[i+0];
      s1[i+1] = exp2v(s1[i+1] - mold); r1s += s1[i+1];
      s1[i+2] = exp2v(s1[i+2] - mold); r2s += s1[i+2];
      s1[i+3] = exp2v(s1[i+3] - mold); r3s += s1[i+3];
    }
    lsum += psum32((r0s + r1s) + (r2s + r3s));
    s8v pa[4];
#pragma unroll
    for (int s = 0; s < 4; ++s) {
      const f16v st2 = (s < 2) ? s0 : s1;
      const int mA = 2 * (s & 1);
      uint32_t a0 = cvtpk(st2[4 * mA + 0], st2[4 * mA + 1]);
      uint32_t a1 = cvtpk(st2[4 * mA + 2], st2[4 * mA + 3]);
      uint32_t b0 = cvtpk(st2[4 * mA + 4], st2[4 * mA + 5]);
      uint32_t b1 = cvtpk(st2[4 * mA + 6], st2[4 * mA + 7]);
      asm("v_permlane32_swap_b32 %0, %1" : "+v"(b0), "+v"(a0));
      asm("v_permlane32_swap_b32 %0, %1" : "+v"(b1), "+v"(a1));
      union { uint32_t u[4]; s8v v; } pk;
      pk.u[0] = a0; pk.u[1] = a1; pk.u[2] = b0; pk.u[3] = b1;
      pa[s] = pk.v;
    }
    __builtin_amdgcn_s_setprio(1);
#pragma unroll
    for (int s = 0; s < 4; ++s) {
      const int col = (s * 16 + hi * 8);
      const int r0 = ql;
      s8v vf0 = *(const s8v*)&Vtsm[cur][r0 * 64 + (col ^ ((r0 & 7) << 3))];
      accO0 = __builtin_amdgcn_mfma_f32_32x32x16_bf16(vf0, pa[s], accO0, 0, 0, 0);
      const int r1 = 32 + ql;
      s8v vf1 = *(const s8v*)&Vtsm[cur][r1 * 64 + (col ^ ((r1 & 7) << 3))];
      accO1 = __builtin_amdgcn_mfma_f32_32x32x16_bf16(vf1, pa[s], accO1, 0, 0, 0);
    }
    __builtin_amdgcn_s_setprio(0);
    __builtin_amdgcn_s_barrier();   // all waves done reading cur
    cur ^= 1;
  }
  const int h = bh & 15, b = bh >> 4;
  const int tok = b * Tc + qt * 128 + w * 32 + ql;
  const float inv = 1.f / lsum;
  ushort* orow = Ob + (size_t)tok * Dc + h * 64;
#pragma unroll
  for (int dt = 0; dt < 2; ++dt) {
    const f16v ac = dt ? accO1 : accO0;
#pragma unroll
    for (int rq = 0; rq < 4; ++rq) {
      u4v pk;
#pragma unroll
      for (int j = 0; j < 4; ++j) pk[j] = f2bf(ac[4 * rq + j] * inv);
      *(u4v*)&orow[dt * 32 + 8 * rq + 4 * hi] = pk;
    }
  }
}

// ---------------------------------------------------------------------------
extern "C" void kernel_launch(void* const* d_in, const int* in_sizes, int n_in,
                              void* d_out, int out_size, void* d_ws, size_t ws_size,
                              hipStream_t stream) {
  (void)in_sizes; (void)n_in; (void)out_size; (void)ws_size;
  const float* x        = (const float*)d_in[0];
  const float* ln1_g    = (const float*)d_in[1];
  const float* ln1_b    = (const float*)d_in[2];
  const float* in_w     = (const float*)d_in[3];
  const float* in_b     = (const float*)d_in[4];
  const float* out_w    = (const float*)d_in[5];
  const float* out_b    = (const float*)d_in[6];
  const float* ln2_g    = (const float*)d_in[7];
  const float* ln2_b    = (const float*)d_in[8];
  const float* rw       = (const float*)d_in[9];
  const float* log_temp = (const float*)d_in[10];
  const float* Wg       = (const float*)d_in[11];
  const float* Wu       = (const float*)d_in[12];
  const float* Wd       = (const float*)d_in[13];
  float* out = (float*)d_out;

  // Workspace (ushorts), total ~138 MiB:
  ushort* h_bf   = (ushort*)d_ws;                       // NTOK*1024   16 MiB
  ushort* Qb     = h_bf   + (size_t)NTOK * Dc;          // 16 MiB
  ushort* Kb     = Qb     + (size_t)NTOK * Dc;          // 16 MiB
  ushort* Vt     = Kb     + (size_t)NTOK * Dc;          // 16 MiB ([bh][d][t])
  ushort* Ob     = Vt     + (size_t)NTOK * Dc;          // 16 MiB
  ushort* act    = Ob     + (size_t)NTOK * Dc;          // NTOK*2048   32 MiB
  ushort* wb_in  = act    + (size_t)NTOK * EDE;         // 3072*1024    6 MiB
  ushort* wb_out = wb_in  + (size_t)3 * Dc * Dc;        // 1024*1024    2 MiB
  ushort* wb_gu  = wb_out + (size_t)Dc * Dc;            // 4096*1024    8 MiB
  ushort* wb_d   = wb_gu  + (size_t)2 * EDE * Dc;       // 1024*2048    4 MiB
  float*  wts    = (float*)(wb_d + (size_t)Dc * EDE);   // NTOK*8     0.25 MiB

  const dim3 blk(256);

  // 0. all weight conversions in one launch
  convert_all<<<dim3(5120), blk, 0, stream>>>(
      in_w, out_w, Wg, Wu, Wd, wb_in, wb_out, wb_gu, wb_d);

  // 1. LN1: x -> h_bf (bf16)
  ln_kernel<0><<<dim3(NTOK), blk, 0, stream>>>(x, ln1_g, ln1_b, h_bf,
                                               nullptr, nullptr, nullptr);
  // 2. QKV GEMM (256^2 8-phase) -> head-major Q(x0.125*log2e)/K + V^T
  gemm256<0><<<dim3(3 * Dc / 256, NTOK / 256), dim3(512), 0, stream>>>(
      h_bf, Dc, wb_in, in_b, Qb, Dc);
  // 3. MFMA attention -> Ob bf16
  attn_mfma<<<dim3(Bc * Hc * (Tc / 128)), blk, 0, stream>>>(Qb, Kb, Vt, Ob);
  // 4. out proj + bias + residual(x) -> out fp32 (128^2 2-phase)
  gemm_bf16<1><<<dim3(Dc / 128, NTOK / 128), blk, 0, stream>>>(
      Ob, Dc, wb_out, out_b, x, out, Dc, Dc);
  // 5. LN2 + fused router: out -> h_bf (h2), wts
  ln_kernel<1><<<dim3(NTOK), blk, 0, stream>>>(out, ln2_g, ln2_b, h_bf,
                                               rw, log_temp, wts);
  // 6. fused gate+up GEMM (256^2 8-phase) + silu*up*wts -> act bf16
  gemm256<4><<<dim3(2 * EDE / 256, NTOK / 256), dim3(512), 0, stream>>>(
      h_bf, Dc, wb_gu, wts, act, Dc);
  // 7. single down GEMM (128^2 2-phase, K=2048), += into out
  gemm_bf16<3><<<dim3(Dc / 128, NTOK / 128), blk, 0, stream>>>(
      act, EDE, wb_d, nullptr, nullptr, out, Dc, EDE);
}

// Round 12
// 399.436 us; speedup vs baseline: 1.0299x; 1.0087x over previous
//
#include <hip/hip_runtime.h>
#include <hip/hip_bf16.h>
#include <cstddef>
#include <cstdint>

// Problem constants (match reference)
constexpr int Bc  = 4;
constexpr int Tc  = 2048;
constexpr int Dc  = 1024;
constexpr int Hc  = 16;
constexpr int Ec  = 8;     // experts
constexpr int DEc = 256;   // expert dim
constexpr int NTOK = Bc * Tc;          // 8192 tokens
constexpr int EDE = Ec * DEc;          // 2048

typedef __attribute__((ext_vector_type(8)))  short  s8v;   // 8 bf16 (4 VGPRs)
typedef __attribute__((ext_vector_type(4)))  float  f4v;   // 16x16 MFMA C/D
typedef __attribute__((ext_vector_type(16))) float  f16v;  // 32x32 MFMA C/D
typedef __attribute__((ext_vector_type(8)))  ushort u8v;
typedef __attribute__((ext_vector_type(4)))  ushort u4v;

constexpr float LOG2E = 1.44269504088896340736f;

__device__ inline ushort f2bf(float f) {  // fp32 -> bf16 bits, RNE
  union { float f; uint32_t u; } v; v.f = f;
  uint32_t r = v.u + 0x7FFFu + ((v.u >> 16) & 1u);
  return (ushort)(r >> 16);
}
__device__ inline float exp2v(float x) {   // 2^x on the TRANS pipe
  float r; asm("v_exp_f32 %0, %1" : "=v"(r) : "v"(x)); return r;
}
__device__ inline float max3f(float a, float b, float c) {
  return fmaxf(fmaxf(a, b), c);             // clang fuses to v_max3_f32
}
// pair-reduce lane l <-> l^32 without DS ops (pure VALU)
__device__ inline float pmax32(float x) {
  float a = x, b = x;
  asm("v_permlane32_swap_b32 %0, %1" : "+v"(b), "+v"(a));
  return fmaxf(a, b);
}
__device__ inline float psum32(float x) {
  float a = x, b = x;
  asm("v_permlane32_swap_b32 %0, %1" : "+v"(b), "+v"(a));
  return a + b;
}

// async global->LDS, 16B per lane; LDS dest = wave-uniform base + lane*16
#define GLOAD_LDS(gsrc, ldst)                                        \
  __builtin_amdgcn_global_load_lds(                                  \
      (const __attribute__((address_space(1))) void*)(gsrc),         \
      (__attribute__((address_space(3))) void*)(ldst), 16, 0, 0)

// pack 2 f32 -> 1 u32 of 2 bf16 (lo = a, hi = b), RNE
__device__ inline uint32_t cvtpk(float a, float b) {
  uint32_t r;
  asm("v_cvt_pk_bf16_f32 %0, %1, %2" : "=v"(r) : "v"(a), "v"(b));
  return r;
}

__device__ inline u8v pack8(const float4& a, const float4& b) {
  u8v o;
  o[0] = f2bf(a.x); o[1] = f2bf(a.y); o[2] = f2bf(a.z); o[3] = f2bf(a.w);
  o[4] = f2bf(b.x); o[5] = f2bf(b.y); o[6] = f2bf(b.z); o[7] = f2bf(b.w);
  return o;
}

// ---------------------------------------------------------------------------
// Single fused weight-convert kernel (block-range dispatch)
// ---------------------------------------------------------------------------
__global__ __launch_bounds__(256)
void convert_all(const float* __restrict__ in_w, const float* __restrict__ out_w,
                 const float* __restrict__ Wg, const float* __restrict__ Wu,
                 const float* __restrict__ Wd,
                 ushort* __restrict__ wb_in, ushort* __restrict__ wb_out,
                 ushort* __restrict__ wb_gu, ushort* __restrict__ wb_d) {
  const int b = blockIdx.x;
  const int tid = threadIdx.x;
  if (b < 1536) {
    const size_t i = ((size_t)b * 256 + tid) * 8;
    *(u8v*)(wb_in + i) = pack8(*(const float4*)(in_w + i),
                               *(const float4*)(in_w + i + 4));
  } else if (b < 2048) {
    const size_t i = ((size_t)(b - 1536) * 256 + tid) * 8;
    *(u8v*)(wb_out + i) = pack8(*(const float4*)(out_w + i),
                                *(const float4*)(out_w + i + 4));
  } else if (b < 4096) {
    const size_t i = ((size_t)(b - 2048) * 256 + tid) * 8;
    const int r = (int)(i >> 10), k = (int)(i & 1023);
    const int j = ((r >> 5) << 4) + (r & 15);
    const float* src = (r & 16) ? Wu : Wg;
    *(u8v*)(wb_gu + i) = pack8(*(const float4*)(src + (size_t)j * Dc + k),
                               *(const float4*)(src + (size_t)j * Dc + k + 4));
  } else {
    const size_t i = ((size_t)(b - 4096) * 256 + tid) * 8;
    const int e = (int)(i >> 18);
    const int d = (int)((i >> 8) & 1023);
    const int f = (int)(i & 255);
    *(u8v*)(wb_d + (size_t)d * EDE + e * DEc + f) =
        pack8(*(const float4*)(Wd + i), *(const float4*)(Wd + i + 4));
  }
}

// ---------------------------------------------------------------------------
// LayerNorm (+ optional fused router). One block per token row (D=1024).
// ---------------------------------------------------------------------------
template <int ROUTER>
__global__ __launch_bounds__(256)
void ln_kernel(const float* __restrict__ in, const float* __restrict__ g,
               const float* __restrict__ bt, ushort* __restrict__ out,
               const float* __restrict__ rw, const float* __restrict__ log_temp,
               float* __restrict__ wts) {
  const int row = blockIdx.x;
  const int tid = threadIdx.x;
  const float* xr = in + (size_t)row * Dc;
  float4 v = *(const float4*)(xr + tid * 4);
  float s  = v.x + v.y + v.z + v.w;
  float ss = v.x * v.x + v.y * v.y + v.z * v.z + v.w * v.w;
#pragma unroll
  for (int off = 32; off; off >>= 1) {
    s  += __shfl_xor(s, off);
    ss += __shfl_xor(ss, off);
  }
  __shared__ float red[8];
  const int w = tid >> 6;
  if ((tid & 63) == 0) { red[w] = s; red[4 + w] = ss; }
  __syncthreads();
  const float ts  = red[0] + red[1] + red[2] + red[3];
  const float tss = red[4] + red[5] + red[6] + red[7];
  const float mean = ts * (1.0f / Dc);
  const float var  = tss * (1.0f / Dc) - mean * mean;
  const float rstd = rsqrtf(var + 1e-5f);
  float4 gv = *(const float4*)(g + tid * 4);
  float4 bv = *(const float4*)(bt + tid * 4);
  const float n0 = (v.x - mean) * rstd * gv.x + bv.x;
  const float n1 = (v.y - mean) * rstd * gv.y + bv.y;
  const float n2 = (v.z - mean) * rstd * gv.z + bv.z;
  const float n3 = (v.w - mean) * rstd * gv.w + bv.w;
  u4v o;
  o[0] = f2bf(n0); o[1] = f2bf(n1); o[2] = f2bf(n2); o[3] = f2bf(n3);
  *(u4v*)(out + (size_t)row * Dc + tid * 4) = o;
  if constexpr (ROUTER) {
    float part[Ec];
#pragma unroll
    for (int e = 0; e < Ec; ++e) {
      float4 wv = *(const float4*)(rw + (size_t)e * Dc + tid * 4);
      part[e] = n0 * wv.x + n1 * wv.y + n2 * wv.z + n3 * wv.w;
    }
#pragma unroll
    for (int off = 32; off; off >>= 1) {
#pragma unroll
      for (int e = 0; e < Ec; ++e) part[e] += __shfl_xor(part[e], off);
    }
    __shared__ float red2[4][Ec];
    if ((tid & 63) == 0) {
#pragma unroll
      for (int e = 0; e < Ec; ++e) red2[w][e] = part[e];
    }
    __syncthreads();
    if (tid == 0) {
      const float lt = *log_temp;
      const float temp = log1pf(__expf(lt)) + 0.1f;
      float lg[Ec];
#pragma unroll
      for (int e = 0; e < Ec; ++e)
        lg[e] = (red2[0][e] + red2[1][e] + red2[2][e] + red2[3][e]) / temp;
      float m1 = -1e30f, m2 = -1e30f;
#pragma unroll
      for (int e = 0; e < Ec; ++e) {
        const float vv = lg[e];
        if (vv > m1) { m2 = m1; m1 = vv; }
        else if (vv > m2) { m2 = vv; }
      }
      float sl[Ec];
      float mx = -1e30f;
#pragma unroll
      for (int e = 0; e < Ec; ++e) {
        const float sup = 1.f / (1.f + __expf(-10.f * (lg[e] - m2)));
        sl[e] = lg[e] * sup;
        mx = fmaxf(mx, sl[e]);
      }
      float ssum = 0.f;
#pragma unroll
      for (int e = 0; e < Ec; ++e) {
        const float p = __expf(sl[e] - mx);
        sl[e] = p;
        ssum += p;
      }
      const float inv = 1.f / ssum;
#pragma unroll
      for (int e = 0; e < Ec; ++e) wts[(size_t)row * Ec + e] = sl[e] * inv;
    }
  }
}

// ---------------------------------------------------------------------------
// 256x256 8-phase bf16 GEMM (T3+T4): BK=64, 512 thr = 8 waves (2Mx4N),
// double-buffered 128KiB LDS, raw s_barrier + counted vmcnt.
// EPI: 0 = QKV scatter   4 = fused silu(gate)*up*wts (B row-interleaved)
// ---------------------------------------------------------------------------
template <int EPI>
__global__ __launch_bounds__(512, 2)
void gemm256(const ushort* __restrict__ A, int lda,
             const ushort* __restrict__ B,
             const float* __restrict__ bias,
             void* __restrict__ Cout, int K) {
  __shared__ __align__(16) ushort Asm[2][256 * 64];
  __shared__ __align__(16) ushort Bsm[2][256 * 64];
  const int tid = threadIdx.x;
  const int lane = tid & 63, w = tid >> 6;
  const int g = lane >> 4, c = lane & 15;
  const int wr = w >> 2, wc = w & 3;
  int bid = blockIdx.y * gridDim.x + blockIdx.x;
  const int qq = (gridDim.x * gridDim.y) >> 3;
  bid = (bid & 7) * qq + (bid >> 3);
  const int m0 = (bid / gridDim.x) * 256, n0 = (bid % gridDim.x) * 256;
  f4v acc[8][4];
#pragma unroll
  for (int i = 0; i < 8; ++i)
#pragma unroll
    for (int j = 0; j < 4; ++j) acc[i][j] = f4v{0.f, 0.f, 0.f, 0.f};

  const int srow = tid >> 3;                       // 0..63
  const int koff = 8 * ((tid & 7) ^ (srow & 7));   // pre-swizzled k slot

#define STAGE_A(buf, kt, i)                                                  \
  GLOAD_LDS(A + (size_t)(m0 + (i) * 64 + srow) * lda + (kt) * 64 + koff,     \
            &Asm[buf][((i) * 512 + tid) * 8])
#define STAGE_B(buf, kt, i)                                                  \
  GLOAD_LDS(B + (size_t)(n0 + (i) * 64 + srow) * K + (kt) * 64 + koff,       \
            &Bsm[buf][((i) * 512 + tid) * 8])

#define RD_A(buf, mi, ks)                                                    \
  (*(const s8v*)&Asm[buf][(wr * 128 + (mi) * 16 + c) * 64 +                  \
      8 * (((ks) * 4 + g) ^ ((wr * 128 + (mi) * 16 + c) & 7))])
#define RD_B(buf, ni, ks)                                                    \
  (*(const s8v*)&Bsm[buf][(wc * 64 + (ni) * 16 + c) * 64 +                   \
      8 * (((ks) * 4 + g) ^ ((wc * 64 + (ni) * 16 + c) & 7))])

  const int NT = K >> 6;
  STAGE_B(0, 0, 0); STAGE_B(0, 0, 1); STAGE_B(0, 0, 2); STAGE_B(0, 0, 3);
  STAGE_A(0, 0, 0); STAGE_A(0, 0, 2); STAGE_A(0, 0, 1); STAGE_A(0, 0, 3);
  asm volatile("s_waitcnt vmcnt(0)" ::: "memory");
  __builtin_amdgcn_s_barrier();

  for (int t = 0; t < NT; ++t) {
    const int cur = t & 1, nxt = cur ^ 1;
    const bool st = (t + 1 < NT);
    s8v bf[2][4], af[2][2];
#pragma unroll
    for (int ks = 0; ks < 2; ++ks) {
#pragma unroll
      for (int ni = 0; ni < 4; ++ni) bf[ks][ni] = RD_B(cur, ni, ks);
      af[ks][0] = RD_A(cur, 0, ks); af[ks][1] = RD_A(cur, 1, ks);
    }
    if (st) { STAGE_B(nxt, t + 1, 0); STAGE_B(nxt, t + 1, 1); }
    __builtin_amdgcn_s_barrier();
    __builtin_amdgcn_s_setprio(1);
#pragma unroll
    for (int ks = 0; ks < 2; ++ks)
#pragma unroll
      for (int q = 0; q < 2; ++q)
#pragma unroll
        for (int ni = 0; ni < 4; ++ni)
          acc[q][ni] = __builtin_amdgcn_mfma_f32_16x16x32_bf16(
              af[ks][q], bf[ks][ni], acc[q][ni], 0, 0, 0);
    __builtin_amdgcn_s_setprio(0);
    __builtin_amdgcn_s_barrier();
#pragma unroll
    for (int ks = 0; ks < 2; ++ks) {
      af[ks][0] = RD_A(cur, 2, ks); af[ks][1] = RD_A(cur, 3, ks);
    }
    if (st) { STAGE_B(nxt, t + 1, 2); STAGE_B(nxt, t + 1, 3); }
    __builtin_amdgcn_s_barrier();
    __builtin_amdgcn_s_setprio(1);
#pragma unroll
    for (int ks = 0; ks < 2; ++ks)
#pragma unroll
      for (int q = 0; q < 2; ++q)
#pragma unroll
        for (int ni = 0; ni < 4; ++ni)
          acc[2 + q][ni] = __builtin_amdgcn_mfma_f32_16x16x32_bf16(
              af[ks][q], bf[ks][ni], acc[2 + q][ni], 0, 0, 0);
    __builtin_amdgcn_s_setprio(0);
    if (st) asm volatile("s_waitcnt vmcnt(4)" ::: "memory");
    else    asm volatile("s_waitcnt vmcnt(0)" ::: "memory");
    __builtin_amdgcn_s_barrier();
#pragma unroll
    for (int ks = 0; ks < 2; ++ks) {
      af[ks][0] = RD_A(cur, 4, ks); af[ks][1] = RD_A(cur, 5, ks);
    }
    if (st) { STAGE_A(nxt, t + 1, 0); STAGE_A(nxt, t + 1, 2); }
    __builtin_amdgcn_s_barrier();
    __builtin_amdgcn_s_setprio(1);
#pragma unroll
    for (int ks = 0; ks < 2; ++ks)
#pragma unroll
      for (int q = 0; q < 2; ++q)
#pragma unroll
        for (int ni = 0; ni < 4; ++ni)
          acc[4 + q][ni] = __builtin_amdgcn_mfma_f32_16x16x32_bf16(
              af[ks][q], bf[ks][ni], acc[4 + q][ni], 0, 0, 0);
    __builtin_amdgcn_s_setprio(0);
    __builtin_amdgcn_s_barrier();
#pragma unroll
    for (int ks = 0; ks < 2; ++ks) {
      af[ks][0] = RD_A(cur, 6, ks); af[ks][1] = RD_A(cur, 7, ks);
    }
    if (st) { STAGE_A(nxt, t + 1, 1); STAGE_A(nxt, t + 1, 3); }
    __builtin_amdgcn_s_barrier();
    __builtin_amdgcn_s_setprio(1);
#pragma unroll
    for (int ks = 0; ks < 2; ++ks)
#pragma unroll
      for (int q = 0; q < 2; ++q)
#pragma unroll
        for (int ni = 0; ni < 4; ++ni)
          acc[6 + q][ni] = __builtin_amdgcn_mfma_f32_16x16x32_bf16(
              af[ks][q], bf[ks][ni], acc[6 + q][ni], 0, 0, 0);
    __builtin_amdgcn_s_setprio(0);
    if (st) asm volatile("s_waitcnt vmcnt(2)" ::: "memory");
    __builtin_amdgcn_s_barrier();
  }
#undef STAGE_A
#undef STAGE_B
#undef RD_A
#undef RD_B

#pragma unroll
  for (int mi = 0; mi < 8; ++mi) {
    if constexpr (EPI == 4) {  // fused act: ni pairs (gate, up)
#pragma unroll
      for (int nip = 0; nip < 2; ++nip) {
        const int jbase = ((n0 + wc * 64) >> 1) + nip * 16;
        const int e = jbase >> 8;
#pragma unroll
        for (int j = 0; j < 4; ++j) {
          const int row = m0 + wr * 128 + mi * 16 + g * 4 + j;
          const float wgt = bias[(size_t)row * Ec + e];  // bias = wts
          const float gv = acc[mi][2 * nip][j];
          const float uv = acc[mi][2 * nip + 1][j];
          const float av = (gv / (1.f + __expf(-gv))) * uv * wgt;
          ((ushort*)Cout)[(size_t)row * EDE + jbase + c] = f2bf(av);
        }
      }
    } else {  // EPI == 0: QKV scatter, head-major
#pragma unroll
      for (int ni = 0; ni < 4; ++ni) {
        const int col = n0 + wc * 64 + ni * 16 + c;
        const int which = col >> 10, hh = (col >> 6) & 15, d = col & 63;
        const int row0 = m0 + wr * 128 + mi * 16 + g * 4;
        const int b = row0 >> 11, t0 = row0 & 2047;
        const float bs = bias[col];
        ushort* base = (ushort*)Cout;
        if (which == 2) {  // V transposed: Vt[bh][d][t]
          u4v pk;
#pragma unroll
          for (int j = 0; j < 4; ++j) pk[j] = f2bf(acc[mi][ni][j] + bs);
          *(u4v*)&base[2 * (size_t)NTOK * Dc +
                       (((size_t)(b * Hc + hh)) * 64 + d) * Tc + t0] = pk;
        } else {
          const float qs = (which == 0) ? 0.125f * LOG2E : 1.f;
          const size_t off = (size_t)which * ((size_t)NTOK * Dc);
#pragma unroll
          for (int j = 0; j < 4; ++j)
            base[off + (((size_t)(b * Hc + hh)) * Tc + t0 + j) * 64 + d] =
                f2bf((acc[mi][ni][j] + bs) * qs);
        }
      }
    }
  }
}

// ---------------------------------------------------------------------------
// 128x128 bf16 GEMM, 2-phase double-buffered (validated round 11).
// EPI: 1 = fp32 +bias+resid   3 = fp32 accumulate
// ---------------------------------------------------------------------------
template <int EPI>
__global__ __launch_bounds__(256)
void gemm_bf16(const ushort* __restrict__ A, int lda,
               const ushort* __restrict__ B,
               const float* __restrict__ bias, const float* __restrict__ resid,
               void* __restrict__ Cout, int ldc, int K) {
  __shared__ __align__(16) ushort As[2][128 * 32];
  __shared__ __align__(16) ushort Bs[2][128 * 32];
  const int tid = threadIdx.x;
  const int lane = tid & 63, w = tid >> 6;
  const int g = lane >> 4, c = lane & 15;
  int bid = blockIdx.y * gridDim.x + blockIdx.x;
  const int qq = (gridDim.x * gridDim.y) >> 3;
  bid = (bid & 7) * qq + (bid >> 3);
  const int m0 = (bid / gridDim.x) * 128, n0 = (bid % gridDim.x) * 128;
  const int wm = (w >> 1) * 64, wn = (w & 1) * 64;
  f4v acc[4][4];
#pragma unroll
  for (int i = 0; i < 4; ++i)
#pragma unroll
    for (int j = 0; j < 4; ++j) acc[i][j] = f4v{0.f, 0.f, 0.f, 0.f};

  int srow[2], skoff[2];
#pragma unroll
  for (int seg = 0; seg < 2; ++seg) {
    const int ci = seg * 256 + tid;
    srow[seg] = ci >> 2;
    skoff[seg] = 8 * ((ci & 3) ^ ((srow[seg] >> 1) & 3));
  }
  auto stage = [&](int buf, int k0) {
#pragma unroll
    for (int seg = 0; seg < 2; ++seg) {
      const int ci = seg * 256 + tid;
      GLOAD_LDS(A + (size_t)(m0 + srow[seg]) * lda + k0 + skoff[seg],
                &As[buf][ci * 8]);
      GLOAD_LDS(B + (size_t)(n0 + srow[seg]) * K + k0 + skoff[seg],
                &Bs[buf][ci * 8]);
    }
  };

  stage(0, 0);   // 4 loads in flight
  int curb = 0;
  for (int k0 = 0; k0 < K; k0 += 32) {
    const bool st = (k0 + 32 < K);
    if (st) {
      stage(curb ^ 1, k0 + 32);   // 8 in flight
      asm volatile("s_waitcnt vmcnt(4)" ::: "memory");  // cur tile landed
    } else {
      asm volatile("s_waitcnt vmcnt(0)" ::: "memory");
    }
    __builtin_amdgcn_s_barrier();
    s8v af[4], bf[4];
#pragma unroll
    for (int mi = 0; mi < 4; ++mi) {
      const int R = wm + mi * 16 + c;
      af[mi] = *(const s8v*)&As[curb][R * 32 + 8 * (g ^ ((R >> 1) & 3))];
    }
#pragma unroll
    for (int ni = 0; ni < 4; ++ni) {
      const int R = wn + ni * 16 + c;
      bf[ni] = *(const s8v*)&Bs[curb][R * 32 + 8 * (g ^ ((R >> 1) & 3))];
    }
    __builtin_amdgcn_s_setprio(1);
#pragma unroll
    for (int mi = 0; mi < 4; ++mi)
#pragma unroll
      for (int ni = 0; ni < 4; ++ni)
        acc[mi][ni] = __builtin_amdgcn_mfma_f32_16x16x32_bf16(
            af[mi], bf[ni], acc[mi][ni], 0, 0, 0);
    __builtin_amdgcn_s_setprio(0);
    __builtin_amdgcn_s_barrier();   // all waves done reading curb
    curb ^= 1;
  }

#pragma unroll
  for (int mi = 0; mi < 4; ++mi) {
#pragma unroll
    for (int ni = 0; ni < 4; ++ni) {
#pragma unroll
      for (int j = 0; j < 4; ++j) {
        const int row = m0 + wm + mi * 16 + g * 4 + j;
        const int col = n0 + wn + ni * 16 + c;
        float v = acc[mi][ni][j];
        if constexpr (EPI == 1) {
          v += bias[col] + resid[(size_t)row * ldc + col];
          ((float*)Cout)[(size_t)row * ldc + col] = v;
        } else {
          ((float*)Cout)[(size_t)row * ldc + col] += v;
        }
      }
    }
  }
}

// ---------------------------------------------------------------------------
// MFMA flash attention with cross-chunk software pipeline (att[2] style):
// QK^T for chunk j+1 is issued BEFORE softmax+PV of chunk j, so the softmax
// never stalls on fresh MFMA results and QK^T overlaps the previous chunk's
// VALU/TRANS work. 3-buffer LDS rotation (chunk j lives in buf j%3; staging
// j+2 never collides with PV(j) or QKT(j+1) reads). Counted vmcnt as before.
// Static sA/sB score registers via 2-unrolled loop (no runtime indexing).
// ---------------------------------------------------------------------------
__global__ __launch_bounds__(256)
void attn_mfma(const ushort* __restrict__ Qb, const ushort* __restrict__ Kb,
               const ushort* __restrict__ Vt, ushort* __restrict__ Ob) {
  __shared__ __align__(16) ushort Ksm[3][64 * 64];
  __shared__ __align__(16) ushort Vtsm[3][64 * 64];
  const int tid = threadIdx.x;
  const int lane = tid & 63, w = tid >> 6;
  const int ql = lane & 31, hi = lane >> 5;
  int bid = blockIdx.x;
  bid = (bid & 7) * 128 + (bid >> 3);
  const int qt = bid & 15, bh = bid >> 4;
  const ushort* Qh = Qb + (size_t)bh * Tc * 64;
  const ushort* Kh = Kb + (size_t)bh * Tc * 64;
  const ushort* Vth = Vt + (size_t)bh * 64 * Tc;
  const int qrow = qt * 128 + w * 32 + ql;
  s8v qf[4];
#pragma unroll
  for (int ds = 0; ds < 4; ++ds)
    qf[ds] = *(const s8v*)(Qh + (size_t)qrow * 64 + ds * 16 + hi * 8);
  f16v accO0, accO1;
#pragma unroll
  for (int i = 0; i < 16; ++i) { accO0[i] = 0.f; accO1[i] = 0.f; }
  float mold = -1e30f, lsum = 0.f;
  int srow[2], soff[2];
#pragma unroll
  for (int seg = 0; seg < 2; ++seg) {
    const int ci = seg * 256 + tid;
    srow[seg] = ci >> 3;
    soff[seg] = ((ci & 7) * 8) ^ ((srow[seg] & 7) << 3);
  }
  auto stage = [&](int buf, int j0) {
#pragma unroll
    for (int seg = 0; seg < 2; ++seg) {
      const int ci = seg * 256 + tid;
      GLOAD_LDS(Kh + (size_t)(j0 + srow[seg]) * 64 + soff[seg], &Ksm[buf][ci * 8]);
      GLOAD_LDS(Vth + (size_t)srow[seg] * Tc + j0 + soff[seg], &Vtsm[buf][ci * 8]);
    }
  };
  // QK^T of one chunk from Ksm[buf] into (s0,s1)
  auto qkt = [&](int buf, f16v& s0, f16v& s1) {
#pragma unroll
    for (int i = 0; i < 16; ++i) { s0[i] = 0.f; s1[i] = 0.f; }
    __builtin_amdgcn_s_setprio(1);
#pragma unroll
    for (int ds = 0; ds < 4; ++ds) {
      const int col = (ds * 16 + hi * 8);
      const int r0 = ql;
      s8v kf0 = *(const s8v*)&Ksm[buf][r0 * 64 + (col ^ ((r0 & 7) << 3))];
      s0 = __builtin_amdgcn_mfma_f32_32x32x16_bf16(kf0, qf[ds], s0, 0, 0, 0);
      const int r1 = 32 + ql;
      s8v kf1 = *(const s8v*)&Ksm[buf][r1 * 64 + (col ^ ((r1 & 7) << 3))];
      s1 = __builtin_amdgcn_mfma_f32_32x32x16_bf16(kf1, qf[ds], s1, 0, 0, 0);
    }
    __builtin_amdgcn_s_setprio(0);
  };
  // softmax + P-build + PV of one chunk (scores in s0/s1, V in Vtsm[buf])
  auto smpv = [&](int buf, f16v& s0, f16v& s1) {
    float cc0 = fmaxf(s0[0], s1[0]), cc1 = fmaxf(s0[1], s1[1]);
    float cc2 = fmaxf(s0[2], s1[2]), cc3 = fmaxf(s0[3], s1[3]);
#pragma unroll
    for (int i = 4; i < 16; i += 4) {
      cc0 = max3f(cc0, s0[i + 0], s1[i + 0]);
      cc1 = max3f(cc1, s0[i + 1], s1[i + 1]);
      cc2 = max3f(cc2, s0[i + 2], s1[i + 2]);
      cc3 = max3f(cc3, s0[i + 3], s1[i + 3]);
    }
    float mx = pmax32(fmaxf(max3f(cc0, cc1, cc2), cc3));
    const bool need = mx > mold + 11.5416f;    // 8 * log2(e)
    if (__any((int)need)) {
      const float mnew = fmaxf(mold, mx);
      const float sc = exp2v(mold - mnew);
      lsum *= sc;
#pragma unroll
      for (int i = 0; i < 16; ++i) { accO0[i] *= sc; accO1[i] *= sc; }
      mold = mnew;
    }
    float r0s = 0.f, r1s = 0.f, r2s = 0.f, r3s = 0.f;
#pragma unroll
    for (int i = 0; i < 16; i += 4) {
      s0[i+0] = exp2v(s0[i+0] - mold); r0s += s0[i+0];
      s0[i+1] = exp2v(s0[i+1] - mold); r1s += s0[i+1];
      s0[i+2] = exp2v(s0[i+2] - mold); r2s += s0[i+2];
      s0[i+3] = exp2v(s0[i+3] - mold); r3s += s0[i+3];
      s1[i+0] = exp2v(s1[i+0] - mold); r0s += s1[i+0];
      s1[i+1] = exp2v(s1[i+1] - mold); r1s += s1[i+1];
      s1[i+2] = exp2v(s1[i+2] - mold); r2s += s1[i+2];
      s1[i+3] = exp2v(s1[i+3] - mold); r3s += s1[i+3];
    }
    lsum += psum32((r0s + r1s) + (r2s + r3s));
    s8v pa[4];
#pragma unroll
    for (int s = 0; s < 4; ++s) {
      const f16v st2 = (s < 2) ? s0 : s1;
      const int mA = 2 * (s & 1);
      uint32_t a0 = cvtpk(st2[4 * mA + 0], st2[4 * mA + 1]);
      uint32_t a1 = cvtpk(st2[4 * mA + 2], st2[4 * mA + 3]);
      uint32_t b0 = cvtpk(st2[4 * mA + 4], st2[4 * mA + 5]);
      uint32_t b1 = cvtpk(st2[4 * mA + 6], st2[4 * mA + 7]);
      asm("v_permlane32_swap_b32 %0, %1" : "+v"(b0), "+v"(a0));
      asm("v_permlane32_swap_b32 %0, %1" : "+v"(b1), "+v"(a1));
      union { uint32_t u[4]; s8v v; } pk;
      pk.u[0] = a0; pk.u[1] = a1; pk.u[2] = b0; pk.u[3] = b1;
      pa[s] = pk.v;
    }
    __builtin_amdgcn_s_setprio(1);
#pragma unroll
    for (int s = 0; s < 4; ++s) {
      const int col = (s * 16 + hi * 8);
      const int r0 = ql;
      s8v vf0 = *(const s8v*)&Vtsm[buf][r0 * 64 + (col ^ ((r0 & 7) << 3))];
      accO0 = __builtin_amdgcn_mfma_f32_32x32x16_bf16(vf0, pa[s], accO0, 0, 0, 0);
      const int r1 = 32 + ql;
      s8v vf1 = *(const s8v*)&Vtsm[buf][r1 * 64 + (col ^ ((r1 & 7) << 3))];
      accO1 = __builtin_amdgcn_mfma_f32_32x32x16_bf16(vf1, pa[s], accO1, 0, 0, 0);
    }
    __builtin_amdgcn_s_setprio(0);
  };

  constexpr int NCH = Tc / 64;   // 32 chunks
  // prologue: stage chunks 0,1 (8 loads); chunk0 ready after vmcnt(4)
  stage(0, 0);
  stage(1, 64);
  asm volatile("s_waitcnt vmcnt(4)" ::: "memory");
  __builtin_amdgcn_s_barrier();
  f16v s0A, s1A, s0B, s1B;
  qkt(0, s0A, s1A);

  // Vmcnt ledger (steady state): entering phase cj, 4 loads outstanding
  // (chunk cj+1, issued previous phase). Stage cj+2 -> 8; wait vmcnt(4)
  // -> chunk cj+1 landed, chunk cj+2 stays in flight. Tail: no stage ->
  // wait vmcnt(0). Buffer safety: staging (cj+2)%3 only reuses chunk
  // (cj-1)'s buffer, whose last readers finished before the end-of-phase
  // barrier of phase cj-1.
  for (int j = 0; j < NCH; j += 2) {
    {  // phase: consume A (chunk j), produce B (chunk j+1)
      const int cj = j;
      const bool stg = (cj + 2 < NCH);
      if (stg) {
        stage((cj + 2) % 3, (cj + 2) * 64);
        asm volatile("s_waitcnt vmcnt(4)" ::: "memory");
      } else {
        asm volatile("s_waitcnt vmcnt(0)" ::: "memory");
      }
      __builtin_amdgcn_s_barrier();
      if (cj + 1 < NCH) qkt((cj + 1) % 3, s0B, s1B);
      smpv(cj % 3, s0A, s1A);
      __builtin_amdgcn_s_barrier();
    }
    {  // phase: consume B (chunk j+1), produce A (chunk j+2)
      const int cj = j + 1;
      const bool stg = (cj + 2 < NCH);
      if (stg) {
        stage((cj + 2) % 3, (cj + 2) * 64);
        asm volatile("s_waitcnt vmcnt(4)" ::: "memory");
      } else {
        asm volatile("s_waitcnt vmcnt(0)" ::: "memory");
      }
      __builtin_amdgcn_s_barrier();
      if (cj + 1 < NCH) qkt((cj + 1) % 3, s0A, s1A);
      smpv(cj % 3, s0B, s1B);
      __builtin_amdgcn_s_barrier();
    }
  }
  const int h = bh & 15, b = bh >> 4;
  const int tok = b * Tc + qt * 128 + w * 32 + ql;
  const float inv = 1.f / lsum;
  ushort* orow = Ob + (size_t)tok * Dc + h * 64;
#pragma unroll
  for (int dt = 0; dt < 2; ++dt) {
    const f16v ac = dt ? accO1 : accO0;
#pragma unroll
    for (int rq = 0; rq < 4; ++rq) {
      u4v pk;
#pragma unroll
      for (int j = 0; j < 4; ++j) pk[j] = f2bf(ac[4 * rq + j] * inv);
      *(u4v*)&orow[dt * 32 + 8 * rq + 4 * hi] = pk;
    }
  }
}

// ---------------------------------------------------------------------------
extern "C" void kernel_launch(void* const* d_in, const int* in_sizes, int n_in,
                              void* d_out, int out_size, void* d_ws, size_t ws_size,
                              hipStream_t stream) {
  (void)in_sizes; (void)n_in; (void)out_size; (void)ws_size;
  const float* x        = (const float*)d_in[0];
  const float* ln1_g    = (const float*)d_in[1];
  const float* ln1_b    = (const float*)d_in[2];
  const float* in_w     = (const float*)d_in[3];
  const float* in_b     = (const float*)d_in[4];
  const float* out_w    = (const float*)d_in[5];
  const float* out_b    = (const float*)d_in[6];
  const float* ln2_g    = (const float*)d_in[7];
  const float* ln2_b    = (const float*)d_in[8];
  const float* rw       = (const float*)d_in[9];
  const float* log_temp = (const float*)d_in[10];
  const float* Wg       = (const float*)d_in[11];
  const float* Wu       = (const float*)d_in[12];
  const float* Wd       = (const float*)d_in[13];
  float* out = (float*)d_out;

  // Workspace (ushorts), total ~138 MiB:
  ushort* h_bf   = (ushort*)d_ws;                       // NTOK*1024   16 MiB
  ushort* Qb     = h_bf   + (size_t)NTOK * Dc;          // 16 MiB
  ushort* Kb     = Qb     + (size_t)NTOK * Dc;          // 16 MiB
  ushort* Vt     = Kb     + (size_t)NTOK * Dc;          // 16 MiB ([bh][d][t])
  ushort* Ob     = Vt     + (size_t)NTOK * Dc;          // 16 MiB
  ushort* act    = Ob     + (size_t)NTOK * Dc;          // NTOK*2048   32 MiB
  ushort* wb_in  = act    + (size_t)NTOK * EDE;         // 3072*1024    6 MiB
  ushort* wb_out = wb_in  + (size_t)3 * Dc * Dc;        // 1024*1024    2 MiB
  ushort* wb_gu  = wb_out + (size_t)Dc * Dc;            // 4096*1024    8 MiB
  ushort* wb_d   = wb_gu  + (size_t)2 * EDE * Dc;       // 1024*2048    4 MiB
  float*  wts    = (float*)(wb_d + (size_t)Dc * EDE);   // NTOK*8     0.25 MiB

  const dim3 blk(256);

  // 0. all weight conversions in one launch
  convert_all<<<dim3(5120), blk, 0, stream>>>(
      in_w, out_w, Wg, Wu, Wd, wb_in, wb_out, wb_gu, wb_d);

  // 1. LN1: x -> h_bf (bf16)
  ln_kernel<0><<<dim3(NTOK), blk, 0, stream>>>(x, ln1_g, ln1_b, h_bf,
                                               nullptr, nullptr, nullptr);
  // 2. QKV GEMM (256^2 8-phase) -> head-major Q(x0.125*log2e)/K + V^T
  gemm256<0><<<dim3(3 * Dc / 256, NTOK / 256), dim3(512), 0, stream>>>(
      h_bf, Dc, wb_in, in_b, Qb, Dc);
  // 3. MFMA attention (cross-chunk pipelined) -> Ob bf16
  attn_mfma<<<dim3(Bc * Hc * (Tc / 128)), blk, 0, stream>>>(Qb, Kb, Vt, Ob);
  // 4. out proj + bias + residual(x) -> out fp32 (128^2 2-phase)
  gemm_bf16<1><<<dim3(Dc / 128, NTOK / 128), blk, 0, stream>>>(
      Ob, Dc, wb_out, out_b, x, out, Dc, Dc);
  // 5. LN2 + fused router: out -> h_bf (h2), wts
  ln_kernel<1><<<dim3(NTOK), blk, 0, stream>>>(out, ln2_g, ln2_b, h_bf,
                                               rw, log_temp, wts);
  // 6. fused gate+up GEMM (256^2 8-phase) + silu*up*wts -> act bf16
  gemm256<4><<<dim3(2 * EDE / 256, NTOK / 256), dim3(512), 0, stream>>>(
      h_bf, Dc, wb_gu, wts, act, Dc);
  // 7. single down GEMM (128^2 2-phase, K=2048), += into out
  gemm_bf16<3><<<dim3(Dc / 128, NTOK / 128), blk, 0, stream>>>(
      act, EDE, wb_d, nullptr, nullptr, out, Dc, EDE);
}

// Round 13
// 380.509 us; speedup vs baseline: 1.0811x; 1.0497x over previous
//
#include <hip/hip_runtime.h>
#include <hip/hip_bf16.h>
#include <cstddef>
#include <cstdint>

// Problem constants (match reference)
constexpr int Bc  = 4;
constexpr int Tc  = 2048;
constexpr int Dc  = 1024;
constexpr int Hc  = 16;
constexpr int Ec  = 8;     // experts
constexpr int DEc = 256;   // expert dim
constexpr int NTOK = Bc * Tc;          // 8192 tokens
constexpr int EDE = Ec * DEc;          // 2048

typedef __attribute__((ext_vector_type(8)))  short  s8v;   // 8 bf16 (4 VGPRs)
typedef __attribute__((ext_vector_type(4)))  float  f4v;   // 16x16 MFMA C/D
typedef __attribute__((ext_vector_type(16))) float  f16v;  // 32x32 MFMA C/D
typedef __attribute__((ext_vector_type(8)))  ushort u8v;
typedef __attribute__((ext_vector_type(4)))  ushort u4v;

constexpr float LOG2E = 1.44269504088896340736f;

__device__ inline ushort f2bf(float f) {  // fp32 -> bf16 bits, RNE
  union { float f; uint32_t u; } v; v.f = f;
  uint32_t r = v.u + 0x7FFFu + ((v.u >> 16) & 1u);
  return (ushort)(r >> 16);
}
__device__ inline float exp2v(float x) {   // 2^x on the TRANS pipe
  float r; asm("v_exp_f32 %0, %1" : "=v"(r) : "v"(x)); return r;
}
__device__ inline float max3f(float a, float b, float c) {
  return fmaxf(fmaxf(a, b), c);             // clang fuses to v_max3_f32
}
// pair-reduce lane l <-> l^32 without DS ops (pure VALU)
__device__ inline float pmax32(float x) {
  float a = x, b = x;
  asm("v_permlane32_swap_b32 %0, %1" : "+v"(b), "+v"(a));
  return fmaxf(a, b);
}
__device__ inline float psum32(float x) {
  float a = x, b = x;
  asm("v_permlane32_swap_b32 %0, %1" : "+v"(b), "+v"(a));
  return a + b;
}

// async global->LDS, 16B per lane; LDS dest = wave-uniform base + lane*16
#define GLOAD_LDS(gsrc, ldst)                                        \
  __builtin_amdgcn_global_load_lds(                                  \
      (const __attribute__((address_space(1))) void*)(gsrc),         \
      (__attribute__((address_space(3))) void*)(ldst), 16, 0, 0)

// pack 2 f32 -> 1 u32 of 2 bf16 (lo = a, hi = b), RNE
__device__ inline uint32_t cvtpk(float a, float b) {
  uint32_t r;
  asm("v_cvt_pk_bf16_f32 %0, %1, %2" : "=v"(r) : "v"(a), "v"(b));
  return r;
}

__device__ inline u8v pack8(const float4& a, const float4& b) {
  u8v o;
  o[0] = f2bf(a.x); o[1] = f2bf(a.y); o[2] = f2bf(a.z); o[3] = f2bf(a.w);
  o[4] = f2bf(b.x); o[5] = f2bf(b.y); o[6] = f2bf(b.z); o[7] = f2bf(b.w);
  return o;
}

// ---------------------------------------------------------------------------
// Single fused weight-convert kernel (block-range dispatch)
// ---------------------------------------------------------------------------
__global__ __launch_bounds__(256)
void convert_all(const float* __restrict__ in_w, const float* __restrict__ out_w,
                 const float* __restrict__ Wg, const float* __restrict__ Wu,
                 const float* __restrict__ Wd,
                 ushort* __restrict__ wb_in, ushort* __restrict__ wb_out,
                 ushort* __restrict__ wb_gu, ushort* __restrict__ wb_d) {
  const int b = blockIdx.x;
  const int tid = threadIdx.x;
  if (b < 1536) {
    const size_t i = ((size_t)b * 256 + tid) * 8;
    *(u8v*)(wb_in + i) = pack8(*(const float4*)(in_w + i),
                               *(const float4*)(in_w + i + 4));
  } else if (b < 2048) {
    const size_t i = ((size_t)(b - 1536) * 256 + tid) * 8;
    *(u8v*)(wb_out + i) = pack8(*(const float4*)(out_w + i),
                                *(const float4*)(out_w + i + 4));
  } else if (b < 4096) {
    const size_t i = ((size_t)(b - 2048) * 256 + tid) * 8;
    const int r = (int)(i >> 10), k = (int)(i & 1023);
    const int j = ((r >> 5) << 4) + (r & 15);
    const float* src = (r & 16) ? Wu : Wg;
    *(u8v*)(wb_gu + i) = pack8(*(const float4*)(src + (size_t)j * Dc + k),
                               *(const float4*)(src + (size_t)j * Dc + k + 4));
  } else {
    const size_t i = ((size_t)(b - 4096) * 256 + tid) * 8;
    const int e = (int)(i >> 18);
    const int d = (int)((i >> 8) & 1023);
    const int f = (int)(i & 255);
    *(u8v*)(wb_d + (size_t)d * EDE + e * DEc + f) =
        pack8(*(const float4*)(Wd + i), *(const float4*)(Wd + i + 4));
  }
}

// ---------------------------------------------------------------------------
// LayerNorm (+ optional fused router). One block per token row (D=1024).
// ---------------------------------------------------------------------------
template <int ROUTER>
__global__ __launch_bounds__(256)
void ln_kernel(const float* __restrict__ in, const float* __restrict__ g,
               const float* __restrict__ bt, ushort* __restrict__ out,
               const float* __restrict__ rw, const float* __restrict__ log_temp,
               float* __restrict__ wts) {
  const int row = blockIdx.x;
  const int tid = threadIdx.x;
  const float* xr = in + (size_t)row * Dc;
  float4 v = *(const float4*)(xr + tid * 4);
  float s  = v.x + v.y + v.z + v.w;
  float ss = v.x * v.x + v.y * v.y + v.z * v.z + v.w * v.w;
#pragma unroll
  for (int off = 32; off; off >>= 1) {
    s  += __shfl_xor(s, off);
    ss += __shfl_xor(ss, off);
  }
  __shared__ float red[8];
  const int w = tid >> 6;
  if ((tid & 63) == 0) { red[w] = s; red[4 + w] = ss; }
  __syncthreads();
  const float ts  = red[0] + red[1] + red[2] + red[3];
  const float tss = red[4] + red[5] + red[6] + red[7];
  const float mean = ts * (1.0f / Dc);
  const float var  = tss * (1.0f / Dc) - mean * mean;
  const float rstd = rsqrtf(var + 1e-5f);
  float4 gv = *(const float4*)(g + tid * 4);
  float4 bv = *(const float4*)(bt + tid * 4);
  const float n0 = (v.x - mean) * rstd * gv.x + bv.x;
  const float n1 = (v.y - mean) * rstd * gv.y + bv.y;
  const float n2 = (v.z - mean) * rstd * gv.z + bv.z;
  const float n3 = (v.w - mean) * rstd * gv.w + bv.w;
  u4v o;
  o[0] = f2bf(n0); o[1] = f2bf(n1); o[2] = f2bf(n2); o[3] = f2bf(n3);
  *(u4v*)(out + (size_t)row * Dc + tid * 4) = o;
  if constexpr (ROUTER) {
    float part[Ec];
#pragma unroll
    for (int e = 0; e < Ec; ++e) {
      float4 wv = *(const float4*)(rw + (size_t)e * Dc + tid * 4);
      part[e] = n0 * wv.x + n1 * wv.y + n2 * wv.z + n3 * wv.w;
    }
#pragma unroll
    for (int off = 32; off; off >>= 1) {
#pragma unroll
      for (int e = 0; e < Ec; ++e) part[e] += __shfl_xor(part[e], off);
    }
    __shared__ float red2[4][Ec];
    if ((tid & 63) == 0) {
#pragma unroll
      for (int e = 0; e < Ec; ++e) red2[w][e] = part[e];
    }
    __syncthreads();
    if (tid == 0) {
      const float lt = *log_temp;
      const float temp = log1pf(__expf(lt)) + 0.1f;
      float lg[Ec];
#pragma unroll
      for (int e = 0; e < Ec; ++e)
        lg[e] = (red2[0][e] + red2[1][e] + red2[2][e] + red2[3][e]) / temp;
      float m1 = -1e30f, m2 = -1e30f;
#pragma unroll
      for (int e = 0; e < Ec; ++e) {
        const float vv = lg[e];
        if (vv > m1) { m2 = m1; m1 = vv; }
        else if (vv > m2) { m2 = vv; }
      }
      float sl[Ec];
      float mx = -1e30f;
#pragma unroll
      for (int e = 0; e < Ec; ++e) {
        const float sup = 1.f / (1.f + __expf(-10.f * (lg[e] - m2)));
        sl[e] = lg[e] * sup;
        mx = fmaxf(mx, sl[e]);
      }
      float ssum = 0.f;
#pragma unroll
      for (int e = 0; e < Ec; ++e) {
        const float p = __expf(sl[e] - mx);
        sl[e] = p;
        ssum += p;
      }
      const float inv = 1.f / ssum;
#pragma unroll
      for (int e = 0; e < Ec; ++e) wts[(size_t)row * Ec + e] = sl[e] * inv;
    }
  }
}

// ---------------------------------------------------------------------------
// 256x256 8-phase bf16 GEMM (T3+T4): BK=64, 512 thr = 8 waves (2Mx4N),
// double-buffered 128KiB LDS, raw s_barrier + counted vmcnt.
// EPI: 0 = QKV scatter   4 = fused silu(gate)*up*wts (B row-interleaved)
// ---------------------------------------------------------------------------
template <int EPI>
__global__ __launch_bounds__(512, 2)
void gemm256(const ushort* __restrict__ A, int lda,
             const ushort* __restrict__ B,
             const float* __restrict__ bias,
             void* __restrict__ Cout, int K) {
  __shared__ __align__(16) ushort Asm[2][256 * 64];
  __shared__ __align__(16) ushort Bsm[2][256 * 64];
  const int tid = threadIdx.x;
  const int lane = tid & 63, w = tid >> 6;
  const int g = lane >> 4, c = lane & 15;
  const int wr = w >> 2, wc = w & 3;
  int bid = blockIdx.y * gridDim.x + blockIdx.x;
  const int qq = (gridDim.x * gridDim.y) >> 3;
  bid = (bid & 7) * qq + (bid >> 3);
  const int m0 = (bid / gridDim.x) * 256, n0 = (bid % gridDim.x) * 256;
  f4v acc[8][4];
#pragma unroll
  for (int i = 0; i < 8; ++i)
#pragma unroll
    for (int j = 0; j < 4; ++j) acc[i][j] = f4v{0.f, 0.f, 0.f, 0.f};

  const int srow = tid >> 3;                       // 0..63
  const int koff = 8 * ((tid & 7) ^ (srow & 7));   // pre-swizzled k slot

#define STAGE_A(buf, kt, i)                                                  \
  GLOAD_LDS(A + (size_t)(m0 + (i) * 64 + srow) * lda + (kt) * 64 + koff,     \
            &Asm[buf][((i) * 512 + tid) * 8])
#define STAGE_B(buf, kt, i)                                                  \
  GLOAD_LDS(B + (size_t)(n0 + (i) * 64 + srow) * K + (kt) * 64 + koff,       \
            &Bsm[buf][((i) * 512 + tid) * 8])

#define RD_A(buf, mi, ks)                                                    \
  (*(const s8v*)&Asm[buf][(wr * 128 + (mi) * 16 + c) * 64 +                  \
      8 * (((ks) * 4 + g) ^ ((wr * 128 + (mi) * 16 + c) & 7))])
#define RD_B(buf, ni, ks)                                                    \
  (*(const s8v*)&Bsm[buf][(wc * 64 + (ni) * 16 + c) * 64 +                   \
      8 * (((ks) * 4 + g) ^ ((wc * 64 + (ni) * 16 + c) & 7))])

  const int NT = K >> 6;
  STAGE_B(0, 0, 0); STAGE_B(0, 0, 1); STAGE_B(0, 0, 2); STAGE_B(0, 0, 3);
  STAGE_A(0, 0, 0); STAGE_A(0, 0, 2); STAGE_A(0, 0, 1); STAGE_A(0, 0, 3);
  asm volatile("s_waitcnt vmcnt(0)" ::: "memory");
  __builtin_amdgcn_s_barrier();

  for (int t = 0; t < NT; ++t) {
    const int cur = t & 1, nxt = cur ^ 1;
    const bool st = (t + 1 < NT);
    s8v bf[2][4], af[2][2];
#pragma unroll
    for (int ks = 0; ks < 2; ++ks) {
#pragma unroll
      for (int ni = 0; ni < 4; ++ni) bf[ks][ni] = RD_B(cur, ni, ks);
      af[ks][0] = RD_A(cur, 0, ks); af[ks][1] = RD_A(cur, 1, ks);
    }
    if (st) { STAGE_B(nxt, t + 1, 0); STAGE_B(nxt, t + 1, 1); }
    __builtin_amdgcn_s_barrier();
    __builtin_amdgcn_s_setprio(1);
#pragma unroll
    for (int ks = 0; ks < 2; ++ks)
#pragma unroll
      for (int q = 0; q < 2; ++q)
#pragma unroll
        for (int ni = 0; ni < 4; ++ni)
          acc[q][ni] = __builtin_amdgcn_mfma_f32_16x16x32_bf16(
              af[ks][q], bf[ks][ni], acc[q][ni], 0, 0, 0);
    __builtin_amdgcn_s_setprio(0);
    __builtin_amdgcn_s_barrier();
#pragma unroll
    for (int ks = 0; ks < 2; ++ks) {
      af[ks][0] = RD_A(cur, 2, ks); af[ks][1] = RD_A(cur, 3, ks);
    }
    if (st) { STAGE_B(nxt, t + 1, 2); STAGE_B(nxt, t + 1, 3); }
    __builtin_amdgcn_s_barrier();
    __builtin_amdgcn_s_setprio(1);
#pragma unroll
    for (int ks = 0; ks < 2; ++ks)
#pragma unroll
      for (int q = 0; q < 2; ++q)
#pragma unroll
        for (int ni = 0; ni < 4; ++ni)
          acc[2 + q][ni] = __builtin_amdgcn_mfma_f32_16x16x32_bf16(
              af[ks][q], bf[ks][ni], acc[2 + q][ni], 0, 0, 0);
    __builtin_amdgcn_s_setprio(0);
    if (st) asm volatile("s_waitcnt vmcnt(4)" ::: "memory");
    else    asm volatile("s_waitcnt vmcnt(0)" ::: "memory");
    __builtin_amdgcn_s_barrier();
#pragma unroll
    for (int ks = 0; ks < 2; ++ks) {
      af[ks][0] = RD_A(cur, 4, ks); af[ks][1] = RD_A(cur, 5, ks);
    }
    if (st) { STAGE_A(nxt, t + 1, 0); STAGE_A(nxt, t + 1, 2); }
    __builtin_amdgcn_s_barrier();
    __builtin_amdgcn_s_setprio(1);
#pragma unroll
    for (int ks = 0; ks < 2; ++ks)
#pragma unroll
      for (int q = 0; q < 2; ++q)
#pragma unroll
        for (int ni = 0; ni < 4; ++ni)
          acc[4 + q][ni] = __builtin_amdgcn_mfma_f32_16x16x32_bf16(
              af[ks][q], bf[ks][ni], acc[4 + q][ni], 0, 0, 0);
    __builtin_amdgcn_s_setprio(0);
    __builtin_amdgcn_s_barrier();
#pragma unroll
    for (int ks = 0; ks < 2; ++ks) {
      af[ks][0] = RD_A(cur, 6, ks); af[ks][1] = RD_A(cur, 7, ks);
    }
    if (st) { STAGE_A(nxt, t + 1, 1); STAGE_A(nxt, t + 1, 3); }
    __builtin_amdgcn_s_barrier();
    __builtin_amdgcn_s_setprio(1);
#pragma unroll
    for (int ks = 0; ks < 2; ++ks)
#pragma unroll
      for (int q = 0; q < 2; ++q)
#pragma unroll
        for (int ni = 0; ni < 4; ++ni)
          acc[6 + q][ni] = __builtin_amdgcn_mfma_f32_16x16x32_bf16(
              af[ks][q], bf[ks][ni], acc[6 + q][ni], 0, 0, 0);
    __builtin_amdgcn_s_setprio(0);
    if (st) asm volatile("s_waitcnt vmcnt(2)" ::: "memory");
    __builtin_amdgcn_s_barrier();
  }
#undef STAGE_A
#undef STAGE_B
#undef RD_A
#undef RD_B

#pragma unroll
  for (int mi = 0; mi < 8; ++mi) {
    if constexpr (EPI == 4) {  // fused act: ni pairs (gate, up)
#pragma unroll
      for (int nip = 0; nip < 2; ++nip) {
        const int jbase = ((n0 + wc * 64) >> 1) + nip * 16;
        const int e = jbase >> 8;
#pragma unroll
        for (int j = 0; j < 4; ++j) {
          const int row = m0 + wr * 128 + mi * 16 + g * 4 + j;
          const float wgt = bias[(size_t)row * Ec + e];  // bias = wts
          const float gv = acc[mi][2 * nip][j];
          const float uv = acc[mi][2 * nip + 1][j];
          const float av = (gv / (1.f + __expf(-gv))) * uv * wgt;
          ((ushort*)Cout)[(size_t)row * EDE + jbase + c] = f2bf(av);
        }
      }
    } else {  // EPI == 0: QKV scatter, head-major
#pragma unroll
      for (int ni = 0; ni < 4; ++ni) {
        const int col = n0 + wc * 64 + ni * 16 + c;
        const int which = col >> 10, hh = (col >> 6) & 15, d = col & 63;
        const int row0 = m0 + wr * 128 + mi * 16 + g * 4;
        const int b = row0 >> 11, t0 = row0 & 2047;
        const float bs = bias[col];
        ushort* base = (ushort*)Cout;
        if (which == 2) {  // V transposed: Vt[bh][d][t]
          u4v pk;
#pragma unroll
          for (int j = 0; j < 4; ++j) pk[j] = f2bf(acc[mi][ni][j] + bs);
          *(u4v*)&base[2 * (size_t)NTOK * Dc +
                       (((size_t)(b * Hc + hh)) * 64 + d) * Tc + t0] = pk;
        } else {
          const float qs = (which == 0) ? 0.125f * LOG2E : 1.f;
          const size_t off = (size_t)which * ((size_t)NTOK * Dc);
#pragma unroll
          for (int j = 0; j < 4; ++j)
            base[off + (((size_t)(b * Hc + hh)) * Tc + t0 + j) * 64 + d] =
                f2bf((acc[mi][ni][j] + bs) * qs);
        }
      }
    }
  }
}

// ---------------------------------------------------------------------------
// 128x128 bf16 GEMM, 2-phase double-buffered (validated round 11).
// EPI: 1 = fp32 +bias+resid   3 = fp32 accumulate
// ---------------------------------------------------------------------------
template <int EPI>
__global__ __launch_bounds__(256)
void gemm_bf16(const ushort* __restrict__ A, int lda,
               const ushort* __restrict__ B,
               const float* __restrict__ bias, const float* __restrict__ resid,
               void* __restrict__ Cout, int ldc, int K) {
  __shared__ __align__(16) ushort As[2][128 * 32];
  __shared__ __align__(16) ushort Bs[2][128 * 32];
  const int tid = threadIdx.x;
  const int lane = tid & 63, w = tid >> 6;
  const int g = lane >> 4, c = lane & 15;
  int bid = blockIdx.y * gridDim.x + blockIdx.x;
  const int qq = (gridDim.x * gridDim.y) >> 3;
  bid = (bid & 7) * qq + (bid >> 3);
  const int m0 = (bid / gridDim.x) * 128, n0 = (bid % gridDim.x) * 128;
  const int wm = (w >> 1) * 64, wn = (w & 1) * 64;
  f4v acc[4][4];
#pragma unroll
  for (int i = 0; i < 4; ++i)
#pragma unroll
    for (int j = 0; j < 4; ++j) acc[i][j] = f4v{0.f, 0.f, 0.f, 0.f};

  int srow[2], skoff[2];
#pragma unroll
  for (int seg = 0; seg < 2; ++seg) {
    const int ci = seg * 256 + tid;
    srow[seg] = ci >> 2;
    skoff[seg] = 8 * ((ci & 3) ^ ((srow[seg] >> 1) & 3));
  }
  auto stage = [&](int buf, int k0) {
#pragma unroll
    for (int seg = 0; seg < 2; ++seg) {
      const int ci = seg * 256 + tid;
      GLOAD_LDS(A + (size_t)(m0 + srow[seg]) * lda + k0 + skoff[seg],
                &As[buf][ci * 8]);
      GLOAD_LDS(B + (size_t)(n0 + srow[seg]) * K + k0 + skoff[seg],
                &Bs[buf][ci * 8]);
    }
  };

  stage(0, 0);   // 4 loads in flight
  int curb = 0;
  for (int k0 = 0; k0 < K; k0 += 32) {
    const bool st = (k0 + 32 < K);
    if (st) {
      stage(curb ^ 1, k0 + 32);   // 8 in flight
      asm volatile("s_waitcnt vmcnt(4)" ::: "memory");  // cur tile landed
    } else {
      asm volatile("s_waitcnt vmcnt(0)" ::: "memory");
    }
    __builtin_amdgcn_s_barrier();
    s8v af[4], bf[4];
#pragma unroll
    for (int mi = 0; mi < 4; ++mi) {
      const int R = wm + mi * 16 + c;
      af[mi] = *(const s8v*)&As[curb][R * 32 + 8 * (g ^ ((R >> 1) & 3))];
    }
#pragma unroll
    for (int ni = 0; ni < 4; ++ni) {
      const int R = wn + ni * 16 + c;
      bf[ni] = *(const s8v*)&Bs[curb][R * 32 + 8 * (g ^ ((R >> 1) & 3))];
    }
    __builtin_amdgcn_s_setprio(1);
#pragma unroll
    for (int mi = 0; mi < 4; ++mi)
#pragma unroll
      for (int ni = 0; ni < 4; ++ni)
        acc[mi][ni] = __builtin_amdgcn_mfma_f32_16x16x32_bf16(
            af[mi], bf[ni], acc[mi][ni], 0, 0, 0);
    __builtin_amdgcn_s_setprio(0);
    __builtin_amdgcn_s_barrier();   // all waves done reading curb
    curb ^= 1;
  }

#pragma unroll
  for (int mi = 0; mi < 4; ++mi) {
#pragma unroll
    for (int ni = 0; ni < 4; ++ni) {
#pragma unroll
      for (int j = 0; j < 4; ++j) {
        const int row = m0 + wm + mi * 16 + g * 4 + j;
        const int col = n0 + wn + ni * 16 + c;
        float v = acc[mi][ni][j];
        if constexpr (EPI == 1) {
          v += bias[col] + resid[(size_t)row * ldc + col];
          ((float*)Cout)[(size_t)row * ldc + col] = v;
        } else {
          ((float*)Cout)[(size_t)row * ldc + col] += v;
        }
      }
    }
  }
}

// ---------------------------------------------------------------------------
// MFMA flash attention, 8-wave blocks (512 thr, 256 q-rows, grid 512): all
// 8 waves share each staged K/V chunk (halves staging instructions + L2
// re-fetch per wave). Round-8 proven body otherwise: swapped 32x32, exp2
// softmax, 2-buffer LDS, counted vmcnt (stage = 2 loads -> steady vmcnt(2)).
// Cross-chunk pipeline (round 12) was null and is dropped (VGPR back to ~88).
// ---------------------------------------------------------------------------
__global__ __launch_bounds__(512)
void attn_mfma(const ushort* __restrict__ Qb, const ushort* __restrict__ Kb,
               const ushort* __restrict__ Vt, ushort* __restrict__ Ob) {
  __shared__ __align__(16) ushort Ksm[2][64 * 64];
  __shared__ __align__(16) ushort Vtsm[2][64 * 64];
  const int tid = threadIdx.x;
  const int lane = tid & 63, w = tid >> 6;       // w in [0,8)
  const int ql = lane & 31, hi = lane >> 5;
  int bid = blockIdx.x;                           // grid = 512
  bid = (bid & 7) * 64 + (bid >> 3);              // bijective XCD swizzle
  const int qt = bid & 7, bh = bid >> 3;          // 8 q-tiles of 256 per bh
  const ushort* Qh = Qb + (size_t)bh * Tc * 64;
  const ushort* Kh = Kb + (size_t)bh * Tc * 64;
  const ushort* Vth = Vt + (size_t)bh * 64 * Tc;
  const int qrow = qt * 256 + w * 32 + ql;
  s8v qf[4];
#pragma unroll
  for (int ds = 0; ds < 4; ++ds)
    qf[ds] = *(const s8v*)(Qh + (size_t)qrow * 64 + ds * 16 + hi * 8);
  f16v accO0, accO1;
#pragma unroll
  for (int i = 0; i < 16; ++i) { accO0[i] = 0.f; accO1[i] = 0.f; }
  float mold = -1e30f, lsum = 0.f;
  // staging: 512 thr x 16B = one 64x64 bf16 chunk per issue
  const int srow = tid >> 3;                          // 0..63
  const int soff = ((tid & 7) * 8) ^ ((srow & 7) << 3);
  auto stage = [&](int buf, int j0) {
    GLOAD_LDS(Kh + (size_t)(j0 + srow) * 64 + soff, &Ksm[buf][tid * 8]);
    GLOAD_LDS(Vth + (size_t)srow * Tc + j0 + soff, &Vtsm[buf][tid * 8]);
  };

  stage(0, 0);   // 2 loads in flight
  int cur = 0;
  for (int j0 = 0; j0 < Tc; j0 += 64) {
    const bool st = (j0 + 64 < Tc);
    if (st) {
      stage(cur ^ 1, j0 + 64);   // 2 more (4 total)
      asm volatile("s_waitcnt vmcnt(2)" ::: "memory");  // cur tile ready
    } else {
      asm volatile("s_waitcnt vmcnt(0)" ::: "memory");
    }
    __builtin_amdgcn_s_barrier();   // all waves' cur-loads landed
    f16v s0, s1;
#pragma unroll
    for (int i = 0; i < 16; ++i) { s0[i] = 0.f; s1[i] = 0.f; }
    __builtin_amdgcn_s_setprio(1);
#pragma unroll
    for (int ds = 0; ds < 4; ++ds) {
      const int col = (ds * 16 + hi * 8);
      const int r0 = ql;
      s8v kf0 = *(const s8v*)&Ksm[cur][r0 * 64 + (col ^ ((r0 & 7) << 3))];
      s0 = __builtin_amdgcn_mfma_f32_32x32x16_bf16(kf0, qf[ds], s0, 0, 0, 0);
      const int r1 = 32 + ql;
      s8v kf1 = *(const s8v*)&Ksm[cur][r1 * 64 + (col ^ ((r1 & 7) << 3))];
      s1 = __builtin_amdgcn_mfma_f32_32x32x16_bf16(kf1, qf[ds], s1, 0, 0, 0);
    }
    __builtin_amdgcn_s_setprio(0);
    float cc0 = fmaxf(s0[0], s1[0]), cc1 = fmaxf(s0[1], s1[1]);
    float cc2 = fmaxf(s0[2], s1[2]), cc3 = fmaxf(s0[3], s1[3]);
#pragma unroll
    for (int i = 4; i < 16; i += 4) {
      cc0 = max3f(cc0, s0[i + 0], s1[i + 0]);
      cc1 = max3f(cc1, s0[i + 1], s1[i + 1]);
      cc2 = max3f(cc2, s0[i + 2], s1[i + 2]);
      cc3 = max3f(cc3, s0[i + 3], s1[i + 3]);
    }
    float mx = pmax32(fmaxf(max3f(cc0, cc1, cc2), cc3));
    const bool need = mx > mold + 11.5416f;    // 8 * log2(e)
    if (__any((int)need)) {
      const float mnew = fmaxf(mold, mx);
      const float sc = exp2v(mold - mnew);
      lsum *= sc;
#pragma unroll
      for (int i = 0; i < 16; ++i) { accO0[i] *= sc; accO1[i] *= sc; }
      mold = mnew;
    }
    float r0s = 0.f, r1s = 0.f, r2s = 0.f, r3s = 0.f;
#pragma unroll
    for (int i = 0; i < 16; i += 4) {
      s0[i+0] = exp2v(s0[i+0] - mold); r0s += s0[i+0];
      s0[i+1] = exp2v(s0[i+1] - mold); r1s += s0[i+1];
      s0[i+2] = exp2v(s0[i+2] - mold); r2s += s0[i+2];
      s0[i+3] = exp2v(s0[i+3] - mold); r3s += s0[i+3];
      s1[i+0] = exp2v(s1[i+0] - mold); r0s += s1[i+0];
      s1[i+1] = exp2v(s1[i+1] - mold); r1s += s1[i+1];
      s1[i+2] = exp2v(s1[i+2] - mold); r2s += s1[i+2];
      s1[i+3] = exp2v(s1[i+3] - mold); r3s += s1[i+3];
    }
    lsum += psum32((r0s + r1s) + (r2s + r3s));
    s8v pa[4];
#pragma unroll
    for (int s = 0; s < 4; ++s) {
      const f16v st2 = (s < 2) ? s0 : s1;
      const int mA = 2 * (s & 1);
      uint32_t a0 = cvtpk(st2[4 * mA + 0], st2[4 * mA + 1]);
      uint32_t a1 = cvtpk(st2[4 * mA + 2], st2[4 * mA + 3]);
      uint32_t b0 = cvtpk(st2[4 * mA + 4], st2[4 * mA + 5]);
      uint32_t b1 = cvtpk(st2[4 * mA + 6], st2[4 * mA + 7]);
      asm("v_permlane32_swap_b32 %0, %1" : "+v"(b0), "+v"(a0));
      asm("v_permlane32_swap_b32 %0, %1" : "+v"(b1), "+v"(a1));
      union { uint32_t u[4]; s8v v; } pk;
      pk.u[0] = a0; pk.u[1] = a1; pk.u[2] = b0; pk.u[3] = b1;
      pa[s] = pk.v;
    }
    __builtin_amdgcn_s_setprio(1);
#pragma unroll
    for (int s = 0; s < 4; ++s) {
      const int col = (s * 16 + hi * 8);
      const int r0 = ql;
      s8v vf0 = *(const s8v*)&Vtsm[cur][r0 * 64 + (col ^ ((r0 & 7) << 3))];
      accO0 = __builtin_amdgcn_mfma_f32_32x32x16_bf16(vf0, pa[s], accO0, 0, 0, 0);
      const int r1 = 32 + ql;
      s8v vf1 = *(const s8v*)&Vtsm[cur][r1 * 64 + (col ^ ((r1 & 7) << 3))];
      accO1 = __builtin_amdgcn_mfma_f32_32x32x16_bf16(vf1, pa[s], accO1, 0, 0, 0);
    }
    __builtin_amdgcn_s_setprio(0);
    __builtin_amdgcn_s_barrier();   // all waves done reading cur
    cur ^= 1;
  }
  const int h = bh & 15, b = bh >> 4;
  const int tok = b * Tc + qt * 256 + w * 32 + ql;
  const float inv = 1.f / lsum;
  ushort* orow = Ob + (size_t)tok * Dc + h * 64;
#pragma unroll
  for (int dt = 0; dt < 2; ++dt) {
    const f16v ac = dt ? accO1 : accO0;
#pragma unroll
    for (int rq = 0; rq < 4; ++rq) {
      u4v pk;
#pragma unroll
      for (int j = 0; j < 4; ++j) pk[j] = f2bf(ac[4 * rq + j] * inv);
      *(u4v*)&orow[dt * 32 + 8 * rq + 4 * hi] = pk;
    }
  }
}

// ---------------------------------------------------------------------------
extern "C" void kernel_launch(void* const* d_in, const int* in_sizes, int n_in,
                              void* d_out, int out_size, void* d_ws, size_t ws_size,
                              hipStream_t stream) {
  (void)in_sizes; (void)n_in; (void)out_size; (void)ws_size;
  const float* x        = (const float*)d_in[0];
  const float* ln1_g    = (const float*)d_in[1];
  const float* ln1_b    = (const float*)d_in[2];
  const float* in_w     = (const float*)d_in[3];
  const float* in_b     = (const float*)d_in[4];
  const float* out_w    = (const float*)d_in[5];
  const float* out_b    = (const float*)d_in[6];
  const float* ln2_g    = (const float*)d_in[7];
  const float* ln2_b    = (const float*)d_in[8];
  const float* rw       = (const float*)d_in[9];
  const float* log_temp = (const float*)d_in[10];
  const float* Wg       = (const float*)d_in[11];
  const float* Wu       = (const float*)d_in[12];
  const float* Wd       = (const float*)d_in[13];
  float* out = (float*)d_out;

  // Workspace (ushorts), total ~138 MiB:
  ushort* h_bf   = (ushort*)d_ws;                       // NTOK*1024   16 MiB
  ushort* Qb     = h_bf   + (size_t)NTOK * Dc;          // 16 MiB
  ushort* Kb     = Qb     + (size_t)NTOK * Dc;          // 16 MiB
  ushort* Vt     = Kb     + (size_t)NTOK * Dc;          // 16 MiB ([bh][d][t])
  ushort* Ob     = Vt     + (size_t)NTOK * Dc;          // 16 MiB
  ushort* act    = Ob     + (size_t)NTOK * Dc;          // NTOK*2048   32 MiB
  ushort* wb_in  = act    + (size_t)NTOK * EDE;         // 3072*1024    6 MiB
  ushort* wb_out = wb_in  + (size_t)3 * Dc * Dc;        // 1024*1024    2 MiB
  ushort* wb_gu  = wb_out + (size_t)Dc * Dc;            // 4096*1024    8 MiB
  ushort* wb_d   = wb_gu  + (size_t)2 * EDE * Dc;       // 1024*2048    4 MiB
  float*  wts    = (float*)(wb_d + (size_t)Dc * EDE);   // NTOK*8     0.25 MiB

  const dim3 blk(256);

  // 0. all weight conversions in one launch
  convert_all<<<dim3(5120), blk, 0, stream>>>(
      in_w, out_w, Wg, Wu, Wd, wb_in, wb_out, wb_gu, wb_d);

  // 1. LN1: x -> h_bf (bf16)
  ln_kernel<0><<<dim3(NTOK), blk, 0, stream>>>(x, ln1_g, ln1_b, h_bf,
                                               nullptr, nullptr, nullptr);
  // 2. QKV GEMM (256^2 8-phase) -> head-major Q(x0.125*log2e)/K + V^T
  gemm256<0><<<dim3(3 * Dc / 256, NTOK / 256), dim3(512), 0, stream>>>(
      h_bf, Dc, wb_in, in_b, Qb, Dc);
  // 3. MFMA attention (8-wave blocks) -> Ob bf16
  attn_mfma<<<dim3(Bc * Hc * (Tc / 256)), dim3(512), 0, stream>>>(
      Qb, Kb, Vt, Ob);
  // 4. out proj + bias + residual(x) -> out fp32 (128^2 2-phase)
  gemm_bf16<1><<<dim3(Dc / 128, NTOK / 128), blk, 0, stream>>>(
      Ob, Dc, wb_out, out_b, x, out, Dc, Dc);
  // 5. LN2 + fused router: out -> h_bf (h2), wts
  ln_kernel<1><<<dim3(NTOK), blk, 0, stream>>>(out, ln2_g, ln2_b, h_bf,
                                               rw, log_temp, wts);
  // 6. fused gate+up GEMM (256^2 8-phase) + silu*up*wts -> act bf16
  gemm256<4><<<dim3(2 * EDE / 256, NTOK / 256), dim3(512), 0, stream>>>(
      h_bf, Dc, wb_gu, wts, act, Dc);
  // 7. single down GEMM (128^2 2-phase, K=2048), += into out
  gemm_bf16<3><<<dim3(Dc / 128, NTOK / 128), blk, 0, stream>>>(
      act, EDE, wb_d, nullptr, nullptr, out, Dc, EDE);
}

// Round 14
// 366.311 us; speedup vs baseline: 1.1230x; 1.0388x over previous
//
#include <hip/hip_runtime.h>
#include <hip/hip_bf16.h>
#include <cstddef>
#include <cstdint>

// Problem constants (match reference)
constexpr int Bc  = 4;
constexpr int Tc  = 2048;
constexpr int Dc  = 1024;
constexpr int Hc  = 16;
constexpr int Ec  = 8;     // experts
constexpr int DEc = 256;   // expert dim
constexpr int NTOK = Bc * Tc;          // 8192 tokens
constexpr int EDE = Ec * DEc;          // 2048

typedef __attribute__((ext_vector_type(8)))  short  s8v;   // 8 bf16 (4 VGPRs)
typedef __attribute__((ext_vector_type(4)))  float  f4v;   // 16x16 MFMA C/D
typedef __attribute__((ext_vector_type(16))) float  f16v;  // 32x32 MFMA C/D
typedef __attribute__((ext_vector_type(8)))  ushort u8v;
typedef __attribute__((ext_vector_type(4)))  ushort u4v;

constexpr float LOG2E = 1.44269504088896340736f;

__device__ inline ushort f2bf(float f) {  // fp32 -> bf16 bits, RNE
  union { float f; uint32_t u; } v; v.f = f;
  uint32_t r = v.u + 0x7FFFu + ((v.u >> 16) & 1u);
  return (ushort)(r >> 16);
}
__device__ inline float exp2v(float x) {   // 2^x on the TRANS pipe
  float r; asm("v_exp_f32 %0, %1" : "=v"(r) : "v"(x)); return r;
}
__device__ inline float max3f(float a, float b, float c) {
  return fmaxf(fmaxf(a, b), c);             // clang fuses to v_max3_f32
}
// pair-reduce lane l <-> l^32 without DS ops (pure VALU)
__device__ inline float pmax32(float x) {
  float a = x, b = x;
  asm("v_permlane32_swap_b32 %0, %1" : "+v"(b), "+v"(a));
  return fmaxf(a, b);
}
__device__ inline float psum32(float x) {
  float a = x, b = x;
  asm("v_permlane32_swap_b32 %0, %1" : "+v"(b), "+v"(a));
  return a + b;
}

// async global->LDS, 16B per lane; LDS dest = wave-uniform base + lane*16
#define GLOAD_LDS(gsrc, ldst)                                        \
  __builtin_amdgcn_global_load_lds(                                  \
      (const __attribute__((address_space(1))) void*)(gsrc),         \
      (__attribute__((address_space(3))) void*)(ldst), 16, 0, 0)

// pack 2 f32 -> 1 u32 of 2 bf16 (lo = a, hi = b), RNE
__device__ inline uint32_t cvtpk(float a, float b) {
  uint32_t r;
  asm("v_cvt_pk_bf16_f32 %0, %1, %2" : "=v"(r) : "v"(a), "v"(b));
  return r;
}

__device__ inline u8v pack8(const float4& a, const float4& b) {
  u8v o;
  o[0] = f2bf(a.x); o[1] = f2bf(a.y); o[2] = f2bf(a.z); o[3] = f2bf(a.w);
  o[4] = f2bf(b.x); o[5] = f2bf(b.y); o[6] = f2bf(b.z); o[7] = f2bf(b.w);
  return o;
}

// ---------------------------------------------------------------------------
// Single fused weight-convert kernel (block-range dispatch)
// ---------------------------------------------------------------------------
__global__ __launch_bounds__(256)
void convert_all(const float* __restrict__ in_w, const float* __restrict__ out_w,
                 const float* __restrict__ Wg, const float* __restrict__ Wu,
                 const float* __restrict__ Wd,
                 ushort* __restrict__ wb_in, ushort* __restrict__ wb_out,
                 ushort* __restrict__ wb_gu, ushort* __restrict__ wb_d) {
  const int b = blockIdx.x;
  const int tid = threadIdx.x;
  if (b < 1536) {
    const size_t i = ((size_t)b * 256 + tid) * 8;
    *(u8v*)(wb_in + i) = pack8(*(const float4*)(in_w + i),
                               *(const float4*)(in_w + i + 4));
  } else if (b < 2048) {
    const size_t i = ((size_t)(b - 1536) * 256 + tid) * 8;
    *(u8v*)(wb_out + i) = pack8(*(const float4*)(out_w + i),
                                *(const float4*)(out_w + i + 4));
  } else if (b < 4096) {
    const size_t i = ((size_t)(b - 2048) * 256 + tid) * 8;
    const int r = (int)(i >> 10), k = (int)(i & 1023);
    const int j = ((r >> 5) << 4) + (r & 15);
    const float* src = (r & 16) ? Wu : Wg;
    *(u8v*)(wb_gu + i) = pack8(*(const float4*)(src + (size_t)j * Dc + k),
                               *(const float4*)(src + (size_t)j * Dc + k + 4));
  } else {
    const size_t i = ((size_t)(b - 4096) * 256 + tid) * 8;
    const int e = (int)(i >> 18);
    const int d = (int)((i >> 8) & 1023);
    const int f = (int)(i & 255);
    *(u8v*)(wb_d + (size_t)d * EDE + e * DEc + f) =
        pack8(*(const float4*)(Wd + i), *(const float4*)(Wd + i + 4));
  }
}

// ---------------------------------------------------------------------------
// LayerNorm (+ optional fused router). One block per token row (D=1024).
// ---------------------------------------------------------------------------
template <int ROUTER>
__global__ __launch_bounds__(256)
void ln_kernel(const float* __restrict__ in, const float* __restrict__ g,
               const float* __restrict__ bt, ushort* __restrict__ out,
               const float* __restrict__ rw, const float* __restrict__ log_temp,
               float* __restrict__ wts) {
  const int row = blockIdx.x;
  const int tid = threadIdx.x;
  const float* xr = in + (size_t)row * Dc;
  float4 v = *(const float4*)(xr + tid * 4);
  float s  = v.x + v.y + v.z + v.w;
  float ss = v.x * v.x + v.y * v.y + v.z * v.z + v.w * v.w;
#pragma unroll
  for (int off = 32; off; off >>= 1) {
    s  += __shfl_xor(s, off);
    ss += __shfl_xor(ss, off);
  }
  __shared__ float red[8];
  const int w = tid >> 6;
  if ((tid & 63) == 0) { red[w] = s; red[4 + w] = ss; }
  __syncthreads();
  const float ts  = red[0] + red[1] + red[2] + red[3];
  const float tss = red[4] + red[5] + red[6] + red[7];
  const float mean = ts * (1.0f / Dc);
  const float var  = tss * (1.0f / Dc) - mean * mean;
  const float rstd = rsqrtf(var + 1e-5f);
  float4 gv = *(const float4*)(g + tid * 4);
  float4 bv = *(const float4*)(bt + tid * 4);
  const float n0 = (v.x - mean) * rstd * gv.x + bv.x;
  const float n1 = (v.y - mean) * rstd * gv.y + bv.y;
  const float n2 = (v.z - mean) * rstd * gv.z + bv.z;
  const float n3 = (v.w - mean) * rstd * gv.w + bv.w;
  u4v o;
  o[0] = f2bf(n0); o[1] = f2bf(n1); o[2] = f2bf(n2); o[3] = f2bf(n3);
  *(u4v*)(out + (size_t)row * Dc + tid * 4) = o;
  if constexpr (ROUTER) {
    float part[Ec];
#pragma unroll
    for (int e = 0; e < Ec; ++e) {
      float4 wv = *(const float4*)(rw + (size_t)e * Dc + tid * 4);
      part[e] = n0 * wv.x + n1 * wv.y + n2 * wv.z + n3 * wv.w;
    }
#pragma unroll
    for (int off = 32; off; off >>= 1) {
#pragma unroll
      for (int e = 0; e < Ec; ++e) part[e] += __shfl_xor(part[e], off);
    }
    __shared__ float red2[4][Ec];
    if ((tid & 63) == 0) {
#pragma unroll
      for (int e = 0; e < Ec; ++e) red2[w][e] = part[e];
    }
    __syncthreads();
    if (tid == 0) {
      const float lt = *log_temp;
      const float temp = log1pf(__expf(lt)) + 0.1f;
      float lg[Ec];
#pragma unroll
      for (int e = 0; e < Ec; ++e)
        lg[e] = (red2[0][e] + red2[1][e] + red2[2][e] + red2[3][e]) / temp;
      float m1 = -1e30f, m2 = -1e30f;
#pragma unroll
      for (int e = 0; e < Ec; ++e) {
        const float vv = lg[e];
        if (vv > m1) { m2 = m1; m1 = vv; }
        else if (vv > m2) { m2 = vv; }
      }
      float sl[Ec];
      float mx = -1e30f;
#pragma unroll
      for (int e = 0; e < Ec; ++e) {
        const float sup = 1.f / (1.f + __expf(-10.f * (lg[e] - m2)));
        sl[e] = lg[e] * sup;
        mx = fmaxf(mx, sl[e]);
      }
      float ssum = 0.f;
#pragma unroll
      for (int e = 0; e < Ec; ++e) {
        const float p = __expf(sl[e] - mx);
        sl[e] = p;
        ssum += p;
      }
      const float inv = 1.f / ssum;
#pragma unroll
      for (int e = 0; e < Ec; ++e) wts[(size_t)row * Ec + e] = sl[e] * inv;
    }
  }
}

// ---------------------------------------------------------------------------
// 256x256 8-phase bf16 GEMM (T3+T4): BK=64, 512 thr = 8 waves (2Mx4N),
// double-buffered 128KiB LDS, raw s_barrier + counted vmcnt.
// EPI: 0 = QKV scatter   4 = fused silu(gate)*up*wts (B row-interleaved)
// ---------------------------------------------------------------------------
template <int EPI>
__global__ __launch_bounds__(512, 2)
void gemm256(const ushort* __restrict__ A, int lda,
             const ushort* __restrict__ B,
             const float* __restrict__ bias,
             void* __restrict__ Cout, int K) {
  __shared__ __align__(16) ushort Asm[2][256 * 64];
  __shared__ __align__(16) ushort Bsm[2][256 * 64];
  const int tid = threadIdx.x;
  const int lane = tid & 63, w = tid >> 6;
  const int g = lane >> 4, c = lane & 15;
  const int wr = w >> 2, wc = w & 3;
  int bid = blockIdx.y * gridDim.x + blockIdx.x;
  const int qq = (gridDim.x * gridDim.y) >> 3;
  bid = (bid & 7) * qq + (bid >> 3);
  const int m0 = (bid / gridDim.x) * 256, n0 = (bid % gridDim.x) * 256;
  f4v acc[8][4];
#pragma unroll
  for (int i = 0; i < 8; ++i)
#pragma unroll
    for (int j = 0; j < 4; ++j) acc[i][j] = f4v{0.f, 0.f, 0.f, 0.f};

  const int srow = tid >> 3;                       // 0..63
  const int koff = 8 * ((tid & 7) ^ (srow & 7));   // pre-swizzled k slot

#define STAGE_A(buf, kt, i)                                                  \
  GLOAD_LDS(A + (size_t)(m0 + (i) * 64 + srow) * lda + (kt) * 64 + koff,     \
            &Asm[buf][((i) * 512 + tid) * 8])
#define STAGE_B(buf, kt, i)                                                  \
  GLOAD_LDS(B + (size_t)(n0 + (i) * 64 + srow) * K + (kt) * 64 + koff,       \
            &Bsm[buf][((i) * 512 + tid) * 8])

#define RD_A(buf, mi, ks)                                                    \
  (*(const s8v*)&Asm[buf][(wr * 128 + (mi) * 16 + c) * 64 +                  \
      8 * (((ks) * 4 + g) ^ ((wr * 128 + (mi) * 16 + c) & 7))])
#define RD_B(buf, ni, ks)                                                    \
  (*(const s8v*)&Bsm[buf][(wc * 64 + (ni) * 16 + c) * 64 +                   \
      8 * (((ks) * 4 + g) ^ ((wc * 64 + (ni) * 16 + c) & 7))])

  const int NT = K >> 6;
  STAGE_B(0, 0, 0); STAGE_B(0, 0, 1); STAGE_B(0, 0, 2); STAGE_B(0, 0, 3);
  STAGE_A(0, 0, 0); STAGE_A(0, 0, 2); STAGE_A(0, 0, 1); STAGE_A(0, 0, 3);
  asm volatile("s_waitcnt vmcnt(0)" ::: "memory");
  __builtin_amdgcn_s_barrier();

  for (int t = 0; t < NT; ++t) {
    const int cur = t & 1, nxt = cur ^ 1;
    const bool st = (t + 1 < NT);
    s8v bf[2][4], af[2][2];
#pragma unroll
    for (int ks = 0; ks < 2; ++ks) {
#pragma unroll
      for (int ni = 0; ni < 4; ++ni) bf[ks][ni] = RD_B(cur, ni, ks);
      af[ks][0] = RD_A(cur, 0, ks); af[ks][1] = RD_A(cur, 1, ks);
    }
    if (st) { STAGE_B(nxt, t + 1, 0); STAGE_B(nxt, t + 1, 1); }
    __builtin_amdgcn_s_barrier();
    __builtin_amdgcn_s_setprio(1);
#pragma unroll
    for (int ks = 0; ks < 2; ++ks)
#pragma unroll
      for (int q = 0; q < 2; ++q)
#pragma unroll
        for (int ni = 0; ni < 4; ++ni)
          acc[q][ni] = __builtin_amdgcn_mfma_f32_16x16x32_bf16(
              af[ks][q], bf[ks][ni], acc[q][ni], 0, 0, 0);
    __builtin_amdgcn_s_setprio(0);
    __builtin_amdgcn_s_barrier();
#pragma unroll
    for (int ks = 0; ks < 2; ++ks) {
      af[ks][0] = RD_A(cur, 2, ks); af[ks][1] = RD_A(cur, 3, ks);
    }
    if (st) { STAGE_B(nxt, t + 1, 2); STAGE_B(nxt, t + 1, 3); }
    __builtin_amdgcn_s_barrier();
    __builtin_amdgcn_s_setprio(1);
#pragma unroll
    for (int ks = 0; ks < 2; ++ks)
#pragma unroll
      for (int q = 0; q < 2; ++q)
#pragma unroll
        for (int ni = 0; ni < 4; ++ni)
          acc[2 + q][ni] = __builtin_amdgcn_mfma_f32_16x16x32_bf16(
              af[ks][q], bf[ks][ni], acc[2 + q][ni], 0, 0, 0);
    __builtin_amdgcn_s_setprio(0);
    if (st) asm volatile("s_waitcnt vmcnt(4)" ::: "memory");
    else    asm volatile("s_waitcnt vmcnt(0)" ::: "memory");
    __builtin_amdgcn_s_barrier();
#pragma unroll
    for (int ks = 0; ks < 2; ++ks) {
      af[ks][0] = RD_A(cur, 4, ks); af[ks][1] = RD_A(cur, 5, ks);
    }
    if (st) { STAGE_A(nxt, t + 1, 0); STAGE_A(nxt, t + 1, 2); }
    __builtin_amdgcn_s_barrier();
    __builtin_amdgcn_s_setprio(1);
#pragma unroll
    for (int ks = 0; ks < 2; ++ks)
#pragma unroll
      for (int q = 0; q < 2; ++q)
#pragma unroll
        for (int ni = 0; ni < 4; ++ni)
          acc[4 + q][ni] = __builtin_amdgcn_mfma_f32_16x16x32_bf16(
              af[ks][q], bf[ks][ni], acc[4 + q][ni], 0, 0, 0);
    __builtin_amdgcn_s_setprio(0);
    __builtin_amdgcn_s_barrier();
#pragma unroll
    for (int ks = 0; ks < 2; ++ks) {
      af[ks][0] = RD_A(cur, 6, ks); af[ks][1] = RD_A(cur, 7, ks);
    }
    if (st) { STAGE_A(nxt, t + 1, 1); STAGE_A(nxt, t + 1, 3); }
    __builtin_amdgcn_s_barrier();
    __builtin_amdgcn_s_setprio(1);
#pragma unroll
    for (int ks = 0; ks < 2; ++ks)
#pragma unroll
      for (int q = 0; q < 2; ++q)
#pragma unroll
        for (int ni = 0; ni < 4; ++ni)
          acc[6 + q][ni] = __builtin_amdgcn_mfma_f32_16x16x32_bf16(
              af[ks][q], bf[ks][ni], acc[6 + q][ni], 0, 0, 0);
    __builtin_amdgcn_s_setprio(0);
    if (st) asm volatile("s_waitcnt vmcnt(2)" ::: "memory");
    __builtin_amdgcn_s_barrier();
  }
#undef STAGE_A
#undef STAGE_B
#undef RD_A
#undef RD_B

#pragma unroll
  for (int mi = 0; mi < 8; ++mi) {
    if constexpr (EPI == 4) {  // fused act: ni pairs (gate, up)
#pragma unroll
      for (int nip = 0; nip < 2; ++nip) {
        const int jbase = ((n0 + wc * 64) >> 1) + nip * 16;
        const int e = jbase >> 8;
#pragma unroll
        for (int j = 0; j < 4; ++j) {
          const int row = m0 + wr * 128 + mi * 16 + g * 4 + j;
          const float wgt = bias[(size_t)row * Ec + e];  // bias = wts
          const float gv = acc[mi][2 * nip][j];
          const float uv = acc[mi][2 * nip + 1][j];
          const float av = (gv / (1.f + __expf(-gv))) * uv * wgt;
          ((ushort*)Cout)[(size_t)row * EDE + jbase + c] = f2bf(av);
        }
      }
    } else {  // EPI == 0: QKV scatter, head-major
#pragma unroll
      for (int ni = 0; ni < 4; ++ni) {
        const int col = n0 + wc * 64 + ni * 16 + c;
        const int which = col >> 10, hh = (col >> 6) & 15, d = col & 63;
        const int row0 = m0 + wr * 128 + mi * 16 + g * 4;
        const int b = row0 >> 11, t0 = row0 & 2047;
        const float bs = bias[col];
        ushort* base = (ushort*)Cout;
        if (which == 2) {  // V transposed: Vt[bh][d][t]
          u4v pk;
#pragma unroll
          for (int j = 0; j < 4; ++j) pk[j] = f2bf(acc[mi][ni][j] + bs);
          *(u4v*)&base[2 * (size_t)NTOK * Dc +
                       (((size_t)(b * Hc + hh)) * 64 + d) * Tc + t0] = pk;
        } else {
          const float qs = (which == 0) ? 0.125f * LOG2E : 1.f;
          const size_t off = (size_t)which * ((size_t)NTOK * Dc);
#pragma unroll
          for (int j = 0; j < 4; ++j)
            base[off + (((size_t)(b * Hc + hh)) * Tc + t0 + j) * 64 + d] =
                f2bf((acc[mi][ni][j] + bs) * qs);
        }
      }
    }
  }
}

// ---------------------------------------------------------------------------
// 128x128 bf16 GEMM, BK=64 2-phase double-buffered: halves iteration count
// (barriers + vmcnt waits) vs BK=32; 64KB LDS -> 2 blocks/CU, matching the
// grid's 2 blocks/CU exactly (no occupancy loss). Counted vmcnt(8).
// EPI: 1 = fp32 +bias+resid   3 = fp32 accumulate
// ---------------------------------------------------------------------------
template <int EPI>
__global__ __launch_bounds__(256)
void gemm_bf16(const ushort* __restrict__ A, int lda,
               const ushort* __restrict__ B,
               const float* __restrict__ bias, const float* __restrict__ resid,
               void* __restrict__ Cout, int ldc, int K) {
  __shared__ __align__(16) ushort As[2][128 * 64];   // 32KB
  __shared__ __align__(16) ushort Bs[2][128 * 64];   // 32KB
  const int tid = threadIdx.x;
  const int lane = tid & 63, w = tid >> 6;
  const int g = lane >> 4, c = lane & 15;
  int bid = blockIdx.y * gridDim.x + blockIdx.x;
  const int qq = (gridDim.x * gridDim.y) >> 3;
  bid = (bid & 7) * qq + (bid >> 3);
  const int m0 = (bid / gridDim.x) * 128, n0 = (bid % gridDim.x) * 128;
  const int wm = (w >> 1) * 64, wn = (w & 1) * 64;
  f4v acc[4][4];
#pragma unroll
  for (int i = 0; i < 4; ++i)
#pragma unroll
    for (int j = 0; j < 4; ++j) acc[i][j] = f4v{0.f, 0.f, 0.f, 0.f};

  // staging: 4 issues per matrix per K-step; issue covers rows seg*32..+31
  const int srow = tid >> 3;                           // 0..31
  const int koff = ((tid & 7) * 8) ^ ((srow & 7) << 3);  // involutive swizzle
  auto stage = [&](int buf, int k0) {
#pragma unroll
    for (int seg = 0; seg < 4; ++seg) {
      const int r = seg * 32 + srow;
      GLOAD_LDS(A + (size_t)(m0 + r) * lda + k0 + koff,
                &As[buf][(seg * 256 + tid) * 8]);
      GLOAD_LDS(B + (size_t)(n0 + r) * K + k0 + koff,
                &Bs[buf][(seg * 256 + tid) * 8]);
    }
  };

  stage(0, 0);   // 8 loads in flight
  int curb = 0;
  for (int k0 = 0; k0 < K; k0 += 64) {
    const bool st = (k0 + 64 < K);
    if (st) {
      stage(curb ^ 1, k0 + 64);   // 16 in flight
      asm volatile("s_waitcnt vmcnt(8)" ::: "memory");  // cur tile landed
    } else {
      asm volatile("s_waitcnt vmcnt(0)" ::: "memory");
    }
    __builtin_amdgcn_s_barrier();
    s8v af[2][4], bf[2][4];
#pragma unroll
    for (int ks = 0; ks < 2; ++ks) {
#pragma unroll
      for (int mi = 0; mi < 4; ++mi) {
        const int R = wm + mi * 16 + c;
        af[ks][mi] = *(const s8v*)&As[curb][R * 64 + 8 * ((ks * 4 + g) ^ (R & 7))];
      }
#pragma unroll
      for (int ni = 0; ni < 4; ++ni) {
        const int R = wn + ni * 16 + c;
        bf[ks][ni] = *(const s8v*)&Bs[curb][R * 64 + 8 * ((ks * 4 + g) ^ (R & 7))];
      }
    }
    __builtin_amdgcn_s_setprio(1);
#pragma unroll
    for (int ks = 0; ks < 2; ++ks)
#pragma unroll
      for (int mi = 0; mi < 4; ++mi)
#pragma unroll
        for (int ni = 0; ni < 4; ++ni)
          acc[mi][ni] = __builtin_amdgcn_mfma_f32_16x16x32_bf16(
              af[ks][mi], bf[ks][ni], acc[mi][ni], 0, 0, 0);
    __builtin_amdgcn_s_setprio(0);
    __builtin_amdgcn_s_barrier();   // all waves done reading curb
    curb ^= 1;
  }

#pragma unroll
  for (int mi = 0; mi < 4; ++mi) {
#pragma unroll
    for (int ni = 0; ni < 4; ++ni) {
#pragma unroll
      for (int j = 0; j < 4; ++j) {
        const int row = m0 + wm + mi * 16 + g * 4 + j;
        const int col = n0 + wn + ni * 16 + c;
        float v = acc[mi][ni][j];
        if constexpr (EPI == 1) {
          v += bias[col] + resid[(size_t)row * ldc + col];
          ((float*)Cout)[(size_t)row * ldc + col] = v;
        } else {
          ((float*)Cout)[(size_t)row * ldc + col] += v;
        }
      }
    }
  }
}

// ---------------------------------------------------------------------------
// MFMA flash attention, 8-wave blocks (512 thr, 256 q-rows, grid 512):
// validated round 13 at 97 us. Frozen this round.
// ---------------------------------------------------------------------------
__global__ __launch_bounds__(512)
void attn_mfma(const ushort* __restrict__ Qb, const ushort* __restrict__ Kb,
               const ushort* __restrict__ Vt, ushort* __restrict__ Ob) {
  __shared__ __align__(16) ushort Ksm[2][64 * 64];
  __shared__ __align__(16) ushort Vtsm[2][64 * 64];
  const int tid = threadIdx.x;
  const int lane = tid & 63, w = tid >> 6;       // w in [0,8)
  const int ql = lane & 31, hi = lane >> 5;
  int bid = blockIdx.x;                           // grid = 512
  bid = (bid & 7) * 64 + (bid >> 3);              // bijective XCD swizzle
  const int qt = bid & 7, bh = bid >> 3;          // 8 q-tiles of 256 per bh
  const ushort* Qh = Qb + (size_t)bh * Tc * 64;
  const ushort* Kh = Kb + (size_t)bh * Tc * 64;
  const ushort* Vth = Vt + (size_t)bh * 64 * Tc;
  const int qrow = qt * 256 + w * 32 + ql;
  s8v qf[4];
#pragma unroll
  for (int ds = 0; ds < 4; ++ds)
    qf[ds] = *(const s8v*)(Qh + (size_t)qrow * 64 + ds * 16 + hi * 8);
  f16v accO0, accO1;
#pragma unroll
  for (int i = 0; i < 16; ++i) { accO0[i] = 0.f; accO1[i] = 0.f; }
  float mold = -1e30f, lsum = 0.f;
  const int srow = tid >> 3;                          // 0..63
  const int soff = ((tid & 7) * 8) ^ ((srow & 7) << 3);
  auto stage = [&](int buf, int j0) {
    GLOAD_LDS(Kh + (size_t)(j0 + srow) * 64 + soff, &Ksm[buf][tid * 8]);
    GLOAD_LDS(Vth + (size_t)srow * Tc + j0 + soff, &Vtsm[buf][tid * 8]);
  };

  stage(0, 0);   // 2 loads in flight
  int cur = 0;
  for (int j0 = 0; j0 < Tc; j0 += 64) {
    const bool st = (j0 + 64 < Tc);
    if (st) {
      stage(cur ^ 1, j0 + 64);   // 2 more (4 total)
      asm volatile("s_waitcnt vmcnt(2)" ::: "memory");  // cur tile ready
    } else {
      asm volatile("s_waitcnt vmcnt(0)" ::: "memory");
    }
    __builtin_amdgcn_s_barrier();   // all waves' cur-loads landed
    f16v s0, s1;
#pragma unroll
    for (int i = 0; i < 16; ++i) { s0[i] = 0.f; s1[i] = 0.f; }
    __builtin_amdgcn_s_setprio(1);
#pragma unroll
    for (int ds = 0; ds < 4; ++ds) {
      const int col = (ds * 16 + hi * 8);
      const int r0 = ql;
      s8v kf0 = *(const s8v*)&Ksm[cur][r0 * 64 + (col ^ ((r0 & 7) << 3))];
      s0 = __builtin_amdgcn_mfma_f32_32x32x16_bf16(kf0, qf[ds], s0, 0, 0, 0);
      const int r1 = 32 + ql;
      s8v kf1 = *(const s8v*)&Ksm[cur][r1 * 64 + (col ^ ((r1 & 7) << 3))];
      s1 = __builtin_amdgcn_mfma_f32_32x32x16_bf16(kf1, qf[ds], s1, 0, 0, 0);
    }
    __builtin_amdgcn_s_setprio(0);
    float cc0 = fmaxf(s0[0], s1[0]), cc1 = fmaxf(s0[1], s1[1]);
    float cc2 = fmaxf(s0[2], s1[2]), cc3 = fmaxf(s0[3], s1[3]);
#pragma unroll
    for (int i = 4; i < 16; i += 4) {
      cc0 = max3f(cc0, s0[i + 0], s1[i + 0]);
      cc1 = max3f(cc1, s0[i + 1], s1[i + 1]);
      cc2 = max3f(cc2, s0[i + 2], s1[i + 2]);
      cc3 = max3f(cc3, s0[i + 3], s1[i + 3]);
    }
    float mx = pmax32(fmaxf(max3f(cc0, cc1, cc2), cc3));
    const bool need = mx > mold + 11.5416f;    // 8 * log2(e)
    if (__any((int)need)) {
      const float mnew = fmaxf(mold, mx);
      const float sc = exp2v(mold - mnew);
      lsum *= sc;
#pragma unroll
      for (int i = 0; i < 16; ++i) { accO0[i] *= sc; accO1[i] *= sc; }
      mold = mnew;
    }
    float r0s = 0.f, r1s = 0.f, r2s = 0.f, r3s = 0.f;
#pragma unroll
    for (int i = 0; i < 16; i += 4) {
      s0[i+0] = exp2v(s0[i+0] - mold); r0s += s0[i+0];
      s0[i+1] = exp2v(s0[i+1] - mold); r1s += s0[i+1];
      s0[i+2] = exp2v(s0[i+2] - mold); r2s += s0[i+2];
      s0[i+3] = exp2v(s0[i+3] - mold); r3s += s0[i+3];
      s1[i+0] = exp2v(s1[i+0] - mold); r0s += s1[i+0];
      s1[i+1] = exp2v(s1[i+1] - mold); r1s += s1[i+1];
      s1[i+2] = exp2v(s1[i+2] - mold); r2s += s1[i+2];
      s1[i+3] = exp2v(s1[i+3] - mold); r3s += s1[i+3];
    }
    lsum += psum32((r0s + r1s) + (r2s + r3s));
    s8v pa[4];
#pragma unroll
    for (int s = 0; s < 4; ++s) {
      const f16v st2 = (s < 2) ? s0 : s1;
      const int mA = 2 * (s & 1);
      uint32_t a0 = cvtpk(st2[4 * mA + 0], st2[4 * mA + 1]);
      uint32_t a1 = cvtpk(st2[4 * mA + 2], st2[4 * mA + 3]);
      uint32_t b0 = cvtpk(st2[4 * mA + 4], st2[4 * mA + 5]);
      uint32_t b1 = cvtpk(st2[4 * mA + 6], st2[4 * mA + 7]);
      asm("v_permlane32_swap_b32 %0, %1" : "+v"(b0), "+v"(a0));
      asm("v_permlane32_swap_b32 %0, %1" : "+v"(b1), "+v"(a1));
      union { uint32_t u[4]; s8v v; } pk;
      pk.u[0] = a0; pk.u[1] = a1; pk.u[2] = b0; pk.u[3] = b1;
      pa[s] = pk.v;
    }
    __builtin_amdgcn_s_setprio(1);
#pragma unroll
    for (int s = 0; s < 4; ++s) {
      const int col = (s * 16 + hi * 8);
      const int r0 = ql;
      s8v vf0 = *(const s8v*)&Vtsm[cur][r0 * 64 + (col ^ ((r0 & 7) << 3))];
      accO0 = __builtin_amdgcn_mfma_f32_32x32x16_bf16(vf0, pa[s], accO0, 0, 0, 0);
      const int r1 = 32 + ql;
      s8v vf1 = *(const s8v*)&Vtsm[cur][r1 * 64 + (col ^ ((r1 & 7) << 3))];
      accO1 = __builtin_amdgcn_mfma_f32_32x32x16_bf16(vf1, pa[s], accO1, 0, 0, 0);
    }
    __builtin_amdgcn_s_setprio(0);
    __builtin_amdgcn_s_barrier();   // all waves done reading cur
    cur ^= 1;
  }
  const int h = bh & 15, b = bh >> 4;
  const int tok = b * Tc + qt * 256 + w * 32 + ql;
  const float inv = 1.f / lsum;
  ushort* orow = Ob + (size_t)tok * Dc + h * 64;
#pragma unroll
  for (int dt = 0; dt < 2; ++dt) {
    const f16v ac = dt ? accO1 : accO0;
#pragma unroll
    for (int rq = 0; rq < 4; ++rq) {
      u4v pk;
#pragma unroll
      for (int j = 0; j < 4; ++j) pk[j] = f2bf(ac[4 * rq + j] * inv);
      *(u4v*)&orow[dt * 32 + 8 * rq + 4 * hi] = pk;
    }
  }
}

// ---------------------------------------------------------------------------
extern "C" void kernel_launch(void* const* d_in, const int* in_sizes, int n_in,
                              void* d_out, int out_size, void* d_ws, size_t ws_size,
                              hipStream_t stream) {
  (void)in_sizes; (void)n_in; (void)out_size; (void)ws_size;
  const float* x        = (const float*)d_in[0];
  const float* ln1_g    = (const float*)d_in[1];
  const float* ln1_b    = (const float*)d_in[2];
  const float* in_w     = (const float*)d_in[3];
  const float* in_b     = (const float*)d_in[4];
  const float* out_w    = (const float*)d_in[5];
  const float* out_b    = (const float*)d_in[6];
  const float* ln2_g    = (const float*)d_in[7];
  const float* ln2_b    = (const float*)d_in[8];
  const float* rw       = (const float*)d_in[9];
  const float* log_temp = (const float*)d_in[10];
  const float* Wg       = (const float*)d_in[11];
  const float* Wu       = (const float*)d_in[12];
  const float* Wd       = (const float*)d_in[13];
  float* out = (float*)d_out;

  // Workspace (ushorts), total ~138 MiB:
  ushort* h_bf   = (ushort*)d_ws;                       // NTOK*1024   16 MiB
  ushort* Qb     = h_bf   + (size_t)NTOK * Dc;          // 16 MiB
  ushort* Kb     = Qb     + (size_t)NTOK * Dc;          // 16 MiB
  ushort* Vt     = Kb     + (size_t)NTOK * Dc;          // 16 MiB ([bh][d][t])
  ushort* Ob     = Vt     + (size_t)NTOK * Dc;          // 16 MiB
  ushort* act    = Ob     + (size_t)NTOK * Dc;          // NTOK*2048   32 MiB
  ushort* wb_in  = act    + (size_t)NTOK * EDE;         // 3072*1024    6 MiB
  ushort* wb_out = wb_in  + (size_t)3 * Dc * Dc;        // 1024*1024    2 MiB
  ushort* wb_gu  = wb_out + (size_t)Dc * Dc;            // 4096*1024    8 MiB
  ushort* wb_d   = wb_gu  + (size_t)2 * EDE * Dc;       // 1024*2048    4 MiB
  float*  wts    = (float*)(wb_d + (size_t)Dc * EDE);   // NTOK*8     0.25 MiB

  const dim3 blk(256);

  // 0. all weight conversions in one launch
  convert_all<<<dim3(5120), blk, 0, stream>>>(
      in_w, out_w, Wg, Wu, Wd, wb_in, wb_out, wb_gu, wb_d);

  // 1. LN1: x -> h_bf (bf16)
  ln_kernel<0><<<dim3(NTOK), blk, 0, stream>>>(x, ln1_g, ln1_b, h_bf,
                                               nullptr, nullptr, nullptr);
  // 2. QKV GEMM (256^2 8-phase) -> head-major Q(x0.125*log2e)/K + V^T
  gemm256<0><<<dim3(3 * Dc / 256, NTOK / 256), dim3(512), 0, stream>>>(
      h_bf, Dc, wb_in, in_b, Qb, Dc);
  // 3. MFMA attention (8-wave blocks) -> Ob bf16
  attn_mfma<<<dim3(Bc * Hc * (Tc / 256)), dim3(512), 0, stream>>>(
      Qb, Kb, Vt, Ob);
  // 4. out proj + bias + residual(x) -> out fp32 (128^2 BK=64 2-phase)
  gemm_bf16<1><<<dim3(Dc / 128, NTOK / 128), blk, 0, stream>>>(
      Ob, Dc, wb_out, out_b, x, out, Dc, Dc);
  // 5. LN2 + fused router: out -> h_bf (h2), wts
  ln_kernel<1><<<dim3(NTOK), blk, 0, stream>>>(out, ln2_g, ln2_b, h_bf,
                                               rw, log_temp, wts);
  // 6. fused gate+up GEMM (256^2 8-phase) + silu*up*wts -> act bf16
  gemm256<4><<<dim3(2 * EDE / 256, NTOK / 256), dim3(512), 0, stream>>>(
      h_bf, Dc, wb_gu, wts, act, Dc);
  // 7. single down GEMM (128^2 BK=64 2-phase, K=2048), += into out
  gemm_bf16<3><<<dim3(Dc / 128, NTOK / 128), blk, 0, stream>>>(
      act, EDE, wb_d, nullptr, nullptr, out, Dc, EDE);
}

// Round 15
// 363.738 us; speedup vs baseline: 1.1310x; 1.0071x over previous
//
#include <hip/hip_runtime.h>
#include <hip/hip_bf16.h>
#include <cstddef>
#include <cstdint>

// Problem constants (match reference)
constexpr int Bc  = 4;
constexpr int Tc  = 2048;
constexpr int Dc  = 1024;
constexpr int Hc  = 16;
constexpr int Ec  = 8;     // experts
constexpr int DEc = 256;   // expert dim
constexpr int NTOK = Bc * Tc;          // 8192 tokens
constexpr int EDE = Ec * DEc;          // 2048

typedef __attribute__((ext_vector_type(8)))  short  s8v;   // 8 bf16 (4 VGPRs)
typedef __attribute__((ext_vector_type(4)))  float  f4v;   // 16x16 MFMA C/D
typedef __attribute__((ext_vector_type(16))) float  f16v;  // 32x32 MFMA C/D
typedef __attribute__((ext_vector_type(8)))  ushort u8v;
typedef __attribute__((ext_vector_type(4)))  ushort u4v;

constexpr float LOG2E = 1.44269504088896340736f;

__device__ inline ushort f2bf(float f) {  // fp32 -> bf16 bits, RNE
  union { float f; uint32_t u; } v; v.f = f;
  uint32_t r = v.u + 0x7FFFu + ((v.u >> 16) & 1u);
  return (ushort)(r >> 16);
}
__device__ inline float exp2v(float x) {   // 2^x on the TRANS pipe
  float r; asm("v_exp_f32 %0, %1" : "=v"(r) : "v"(x)); return r;
}
__device__ inline float max3f(float a, float b, float c) {
  return fmaxf(fmaxf(a, b), c);             // clang fuses to v_max3_f32
}
// pair-reduce lane l <-> l^32 without DS ops (pure VALU)
__device__ inline float pmax32(float x) {
  float a = x, b = x;
  asm("v_permlane32_swap_b32 %0, %1" : "+v"(b), "+v"(a));
  return fmaxf(a, b);
}
__device__ inline float psum32(float x) {
  float a = x, b = x;
  asm("v_permlane32_swap_b32 %0, %1" : "+v"(b), "+v"(a));
  return a + b;
}

// async global->LDS, 16B per lane; LDS dest = wave-uniform base + lane*16
#define GLOAD_LDS(gsrc, ldst)                                        \
  __builtin_amdgcn_global_load_lds(                                  \
      (const __attribute__((address_space(1))) void*)(gsrc),         \
      (__attribute__((address_space(3))) void*)(ldst), 16, 0, 0)

// pack 2 f32 -> 1 u32 of 2 bf16 (lo = a, hi = b), RNE
__device__ inline uint32_t cvtpk(float a, float b) {
  uint32_t r;
  asm("v_cvt_pk_bf16_f32 %0, %1, %2" : "=v"(r) : "v"(a), "v"(b));
  return r;
}

__device__ inline u8v pack8(const float4& a, const float4& b) {
  u8v o;
  o[0] = f2bf(a.x); o[1] = f2bf(a.y); o[2] = f2bf(a.z); o[3] = f2bf(a.w);
  o[4] = f2bf(b.x); o[5] = f2bf(b.y); o[6] = f2bf(b.z); o[7] = f2bf(b.w);
  return o;
}

// ---------------------------------------------------------------------------
// Fused weight-convert + LN1 kernel (block-range dispatch):
//   [0,1536)      in_w  flat -> wb_in
//   [1536,2048)   out_w flat -> wb_out
//   [2048,4096)   Wg/Wu interleaved 16-row blocks -> wb_gu [4096,1024]
//   [4096,5120)   Wd [E,D,DE] -> wb_d [D, E*DE]
//   [5120,13312)  LN1 row (b-5120): x -> h_bf
// ---------------------------------------------------------------------------
__global__ __launch_bounds__(256)
void convert_all(const float* __restrict__ in_w, const float* __restrict__ out_w,
                 const float* __restrict__ Wg, const float* __restrict__ Wu,
                 const float* __restrict__ Wd,
                 ushort* __restrict__ wb_in, ushort* __restrict__ wb_out,
                 ushort* __restrict__ wb_gu, ushort* __restrict__ wb_d,
                 const float* __restrict__ x, const float* __restrict__ ln1_g,
                 const float* __restrict__ ln1_b, ushort* __restrict__ h_bf) {
  const int b = blockIdx.x;
  const int tid = threadIdx.x;
  if (b < 1536) {
    const size_t i = ((size_t)b * 256 + tid) * 8;
    *(u8v*)(wb_in + i) = pack8(*(const float4*)(in_w + i),
                               *(const float4*)(in_w + i + 4));
  } else if (b < 2048) {
    const size_t i = ((size_t)(b - 1536) * 256 + tid) * 8;
    *(u8v*)(wb_out + i) = pack8(*(const float4*)(out_w + i),
                                *(const float4*)(out_w + i + 4));
  } else if (b < 4096) {
    const size_t i = ((size_t)(b - 2048) * 256 + tid) * 8;
    const int r = (int)(i >> 10), k = (int)(i & 1023);
    const int j = ((r >> 5) << 4) + (r & 15);
    const float* src = (r & 16) ? Wu : Wg;
    *(u8v*)(wb_gu + i) = pack8(*(const float4*)(src + (size_t)j * Dc + k),
                               *(const float4*)(src + (size_t)j * Dc + k + 4));
  } else if (b < 5120) {
    const size_t i = ((size_t)(b - 4096) * 256 + tid) * 8;
    const int e = (int)(i >> 18);
    const int d = (int)((i >> 8) & 1023);
    const int f = (int)(i & 255);
    *(u8v*)(wb_d + (size_t)d * EDE + e * DEc + f) =
        pack8(*(const float4*)(Wd + i), *(const float4*)(Wd + i + 4));
  } else {  // LN1 for row b-5120
    const int row = b - 5120;
    const float* xr = x + (size_t)row * Dc;
    float4 v = *(const float4*)(xr + tid * 4);
    float s  = v.x + v.y + v.z + v.w;
    float ss = v.x * v.x + v.y * v.y + v.z * v.z + v.w * v.w;
#pragma unroll
    for (int off = 32; off; off >>= 1) {
      s  += __shfl_xor(s, off);
      ss += __shfl_xor(ss, off);
    }
    __shared__ float red[8];
    const int w = tid >> 6;
    if ((tid & 63) == 0) { red[w] = s; red[4 + w] = ss; }
    __syncthreads();
    const float ts  = red[0] + red[1] + red[2] + red[3];
    const float tss = red[4] + red[5] + red[6] + red[7];
    const float mean = ts * (1.0f / Dc);
    const float var  = tss * (1.0f / Dc) - mean * mean;
    const float rstd = rsqrtf(var + 1e-5f);
    float4 gv = *(const float4*)(ln1_g + tid * 4);
    float4 bv = *(const float4*)(ln1_b + tid * 4);
    u4v o;
    o[0] = f2bf((v.x - mean) * rstd * gv.x + bv.x);
    o[1] = f2bf((v.y - mean) * rstd * gv.y + bv.y);
    o[2] = f2bf((v.z - mean) * rstd * gv.z + bv.z);
    o[3] = f2bf((v.w - mean) * rstd * gv.w + bv.w);
    *(u4v*)(h_bf + (size_t)row * Dc + tid * 4) = o;
  }
}

// ---------------------------------------------------------------------------
// LayerNorm (+ optional fused router). One block per token row (D=1024).
// ---------------------------------------------------------------------------
template <int ROUTER>
__global__ __launch_bounds__(256)
void ln_kernel(const float* __restrict__ in, const float* __restrict__ g,
               const float* __restrict__ bt, ushort* __restrict__ out,
               const float* __restrict__ rw, const float* __restrict__ log_temp,
               float* __restrict__ wts) {
  const int row = blockIdx.x;
  const int tid = threadIdx.x;
  const float* xr = in + (size_t)row * Dc;
  float4 v = *(const float4*)(xr + tid * 4);
  float s  = v.x + v.y + v.z + v.w;
  float ss = v.x * v.x + v.y * v.y + v.z * v.z + v.w * v.w;
#pragma unroll
  for (int off = 32; off; off >>= 1) {
    s  += __shfl_xor(s, off);
    ss += __shfl_xor(ss, off);
  }
  __shared__ float red[8];
  const int w = tid >> 6;
  if ((tid & 63) == 0) { red[w] = s; red[4 + w] = ss; }
  __syncthreads();
  const float ts  = red[0] + red[1] + red[2] + red[3];
  const float tss = red[4] + red[5] + red[6] + red[7];
  const float mean = ts * (1.0f / Dc);
  const float var  = tss * (1.0f / Dc) - mean * mean;
  const float rstd = rsqrtf(var + 1e-5f);
  float4 gv = *(const float4*)(g + tid * 4);
  float4 bv = *(const float4*)(bt + tid * 4);
  const float n0 = (v.x - mean) * rstd * gv.x + bv.x;
  const float n1 = (v.y - mean) * rstd * gv.y + bv.y;
  const float n2 = (v.z - mean) * rstd * gv.z + bv.z;
  const float n3 = (v.w - mean) * rstd * gv.w + bv.w;
  u4v o;
  o[0] = f2bf(n0); o[1] = f2bf(n1); o[2] = f2bf(n2); o[3] = f2bf(n3);
  *(u4v*)(out + (size_t)row * Dc + tid * 4) = o;
  if constexpr (ROUTER) {
    float part[Ec];
#pragma unroll
    for (int e = 0; e < Ec; ++e) {
      float4 wv = *(const float4*)(rw + (size_t)e * Dc + tid * 4);
      part[e] = n0 * wv.x + n1 * wv.y + n2 * wv.z + n3 * wv.w;
    }
#pragma unroll
    for (int off = 32; off; off >>= 1) {
#pragma unroll
      for (int e = 0; e < Ec; ++e) part[e] += __shfl_xor(part[e], off);
    }
    __shared__ float red2[4][Ec];
    if ((tid & 63) == 0) {
#pragma unroll
      for (int e = 0; e < Ec; ++e) red2[w][e] = part[e];
    }
    __syncthreads();
    if (tid == 0) {
      const float lt = *log_temp;
      const float temp = log1pf(__expf(lt)) + 0.1f;
      float lg[Ec];
#pragma unroll
      for (int e = 0; e < Ec; ++e)
        lg[e] = (red2[0][e] + red2[1][e] + red2[2][e] + red2[3][e]) / temp;
      float m1 = -1e30f, m2 = -1e30f;
#pragma unroll
      for (int e = 0; e < Ec; ++e) {
        const float vv = lg[e];
        if (vv > m1) { m2 = m1; m1 = vv; }
        else if (vv > m2) { m2 = vv; }
      }
      float sl[Ec];
      float mx = -1e30f;
#pragma unroll
      for (int e = 0; e < Ec; ++e) {
        const float sup = 1.f / (1.f + __expf(-10.f * (lg[e] - m2)));
        sl[e] = lg[e] * sup;
        mx = fmaxf(mx, sl[e]);
      }
      float ssum = 0.f;
#pragma unroll
      for (int e = 0; e < Ec; ++e) {
        const float p = __expf(sl[e] - mx);
        sl[e] = p;
        ssum += p;
      }
      const float inv = 1.f / ssum;
#pragma unroll
      for (int e = 0; e < Ec; ++e) wts[(size_t)row * Ec + e] = sl[e] * inv;
    }
  }
}

// ---------------------------------------------------------------------------
// 256x256 8-phase bf16 GEMM (T3+T4): BK=64, 512 thr = 8 waves (2Mx4N),
// double-buffered 128KiB LDS, raw s_barrier + counted vmcnt.
// EPI: 0 = QKV scatter   4 = fused silu(gate)*up*wts (B row-interleaved)
// ---------------------------------------------------------------------------
template <int EPI>
__global__ __launch_bounds__(512, 2)
void gemm256(const ushort* __restrict__ A, int lda,
             const ushort* __restrict__ B,
             const float* __restrict__ bias,
             void* __restrict__ Cout, int K) {
  __shared__ __align__(16) ushort Asm[2][256 * 64];
  __shared__ __align__(16) ushort Bsm[2][256 * 64];
  const int tid = threadIdx.x;
  const int lane = tid & 63, w = tid >> 6;
  const int g = lane >> 4, c = lane & 15;
  const int wr = w >> 2, wc = w & 3;
  int bid = blockIdx.y * gridDim.x + blockIdx.x;
  const int qq = (gridDim.x * gridDim.y) >> 3;
  bid = (bid & 7) * qq + (bid >> 3);
  const int m0 = (bid / gridDim.x) * 256, n0 = (bid % gridDim.x) * 256;
  f4v acc[8][4];
#pragma unroll
  for (int i = 0; i < 8; ++i)
#pragma unroll
    for (int j = 0; j < 4; ++j) acc[i][j] = f4v{0.f, 0.f, 0.f, 0.f};

  const int srow = tid >> 3;                       // 0..63
  const int koff = 8 * ((tid & 7) ^ (srow & 7));   // pre-swizzled k slot

#define STAGE_A(buf, kt, i)                                                  \
  GLOAD_LDS(A + (size_t)(m0 + (i) * 64 + srow) * lda + (kt) * 64 + koff,     \
            &Asm[buf][((i) * 512 + tid) * 8])
#define STAGE_B(buf, kt, i)                                                  \
  GLOAD_LDS(B + (size_t)(n0 + (i) * 64 + srow) * K + (kt) * 64 + koff,       \
            &Bsm[buf][((i) * 512 + tid) * 8])

#define RD_A(buf, mi, ks)                                                    \
  (*(const s8v*)&Asm[buf][(wr * 128 + (mi) * 16 + c) * 64 +                  \
      8 * (((ks) * 4 + g) ^ ((wr * 128 + (mi) * 16 + c) & 7))])
#define RD_B(buf, ni, ks)                                                    \
  (*(const s8v*)&Bsm[buf][(wc * 64 + (ni) * 16 + c) * 64 +                   \
      8 * (((ks) * 4 + g) ^ ((wc * 64 + (ni) * 16 + c) & 7))])

  const int NT = K >> 6;
  STAGE_B(0, 0, 0); STAGE_B(0, 0, 1); STAGE_B(0, 0, 2); STAGE_B(0, 0, 3);
  STAGE_A(0, 0, 0); STAGE_A(0, 0, 2); STAGE_A(0, 0, 1); STAGE_A(0, 0, 3);
  asm volatile("s_waitcnt vmcnt(0)" ::: "memory");
  __builtin_amdgcn_s_barrier();

  for (int t = 0; t < NT; ++t) {
    const int cur = t & 1, nxt = cur ^ 1;
    const bool st = (t + 1 < NT);
    s8v bf[2][4], af[2][2];
#pragma unroll
    for (int ks = 0; ks < 2; ++ks) {
#pragma unroll
      for (int ni = 0; ni < 4; ++ni) bf[ks][ni] = RD_B(cur, ni, ks);
      af[ks][0] = RD_A(cur, 0, ks); af[ks][1] = RD_A(cur, 1, ks);
    }
    if (st) { STAGE_B(nxt, t + 1, 0); STAGE_B(nxt, t + 1, 1); }
    __builtin_amdgcn_s_barrier();
    __builtin_amdgcn_s_setprio(1);
#pragma unroll
    for (int ks = 0; ks < 2; ++ks)
#pragma unroll
      for (int q = 0; q < 2; ++q)
#pragma unroll
        for (int ni = 0; ni < 4; ++ni)
          acc[q][ni] = __builtin_amdgcn_mfma_f32_16x16x32_bf16(
              af[ks][q], bf[ks][ni], acc[q][ni], 0, 0, 0);
    __builtin_amdgcn_s_setprio(0);
    __builtin_amdgcn_s_barrier();
#pragma unroll
    for (int ks = 0; ks < 2; ++ks) {
      af[ks][0] = RD_A(cur, 2, ks); af[ks][1] = RD_A(cur, 3, ks);
    }
    if (st) { STAGE_B(nxt, t + 1, 2); STAGE_B(nxt, t + 1, 3); }
    __builtin_amdgcn_s_barrier();
    __builtin_amdgcn_s_setprio(1);
#pragma unroll
    for (int ks = 0; ks < 2; ++ks)
#pragma unroll
      for (int q = 0; q < 2; ++q)
#pragma unroll
        for (int ni = 0; ni < 4; ++ni)
          acc[2 + q][ni] = __builtin_amdgcn_mfma_f32_16x16x32_bf16(
              af[ks][q], bf[ks][ni], acc[2 + q][ni], 0, 0, 0);
    __builtin_amdgcn_s_setprio(0);
    if (st) asm volatile("s_waitcnt vmcnt(4)" ::: "memory");
    else    asm volatile("s_waitcnt vmcnt(0)" ::: "memory");
    __builtin_amdgcn_s_barrier();
#pragma unroll
    for (int ks = 0; ks < 2; ++ks) {
      af[ks][0] = RD_A(cur, 4, ks); af[ks][1] = RD_A(cur, 5, ks);
    }
    if (st) { STAGE_A(nxt, t + 1, 0); STAGE_A(nxt, t + 1, 2); }
    __builtin_amdgcn_s_barrier();
    __builtin_amdgcn_s_setprio(1);
#pragma unroll
    for (int ks = 0; ks < 2; ++ks)
#pragma unroll
      for (int q = 0; q < 2; ++q)
#pragma unroll
        for (int ni = 0; ni < 4; ++ni)
          acc[4 + q][ni] = __builtin_amdgcn_mfma_f32_16x16x32_bf16(
              af[ks][q], bf[ks][ni], acc[4 + q][ni], 0, 0, 0);
    __builtin_amdgcn_s_setprio(0);
    __builtin_amdgcn_s_barrier();
#pragma unroll
    for (int ks = 0; ks < 2; ++ks) {
      af[ks][0] = RD_A(cur, 6, ks); af[ks][1] = RD_A(cur, 7, ks);
    }
    if (st) { STAGE_A(nxt, t + 1, 1); STAGE_A(nxt, t + 1, 3); }
    __builtin_amdgcn_s_barrier();
    __builtin_amdgcn_s_setprio(1);
#pragma unroll
    for (int ks = 0; ks < 2; ++ks)
#pragma unroll
      for (int q = 0; q < 2; ++q)
#pragma unroll
        for (int ni = 0; ni < 4; ++ni)
          acc[6 + q][ni] = __builtin_amdgcn_mfma_f32_16x16x32_bf16(
              af[ks][q], bf[ks][ni], acc[6 + q][ni], 0, 0, 0);
    __builtin_amdgcn_s_setprio(0);
    if (st) asm volatile("s_waitcnt vmcnt(2)" ::: "memory");
    __builtin_amdgcn_s_barrier();
  }
#undef STAGE_A
#undef STAGE_B
#undef RD_A
#undef RD_B

#pragma unroll
  for (int mi = 0; mi < 8; ++mi) {
    if constexpr (EPI == 4) {  // fused act: ni pairs (gate, up)
#pragma unroll
      for (int nip = 0; nip < 2; ++nip) {
        const int jbase = ((n0 + wc * 64) >> 1) + nip * 16;
        const int e = jbase >> 8;
#pragma unroll
        for (int j = 0; j < 4; ++j) {
          const int row = m0 + wr * 128 + mi * 16 + g * 4 + j;
          const float wgt = bias[(size_t)row * Ec + e];  // bias = wts
          const float gv = acc[mi][2 * nip][j];
          const float uv = acc[mi][2 * nip + 1][j];
          const float av = (gv / (1.f + __expf(-gv))) * uv * wgt;
          ((ushort*)Cout)[(size_t)row * EDE + jbase + c] = f2bf(av);
        }
      }
    } else {  // EPI == 0: QKV scatter, head-major
#pragma unroll
      for (int ni = 0; ni < 4; ++ni) {
        const int col = n0 + wc * 64 + ni * 16 + c;
        const int which = col >> 10, hh = (col >> 6) & 15, d = col & 63;
        const int row0 = m0 + wr * 128 + mi * 16 + g * 4;
        const int b = row0 >> 11, t0 = row0 & 2047;
        const float bs = bias[col];
        ushort* base = (ushort*)Cout;
        if (which == 2) {  // V transposed: Vt[bh][d][t]
          u4v pk;
#pragma unroll
          for (int j = 0; j < 4; ++j) pk[j] = f2bf(acc[mi][ni][j] + bs);
          *(u4v*)&base[2 * (size_t)NTOK * Dc +
                       (((size_t)(b * Hc + hh)) * 64 + d) * Tc + t0] = pk;
        } else {
          const float qs = (which == 0) ? 0.125f * LOG2E : 1.f;
          const size_t off = (size_t)which * ((size_t)NTOK * Dc);
#pragma unroll
          for (int j = 0; j < 4; ++j)
            base[off + (((size_t)(b * Hc + hh)) * Tc + t0 + j) * 64 + d] =
                f2bf((acc[mi][ni][j] + bs) * qs);
        }
      }
    }
  }
}

// ---------------------------------------------------------------------------
// 128x128 bf16 GEMM, BK=64 2-phase double-buffered (validated round 14).
// EPI: 1 = fp32 +bias+resid   3 = fp32 accumulate
// ---------------------------------------------------------------------------
template <int EPI>
__global__ __launch_bounds__(256)
void gemm_bf16(const ushort* __restrict__ A, int lda,
               const ushort* __restrict__ B,
               const float* __restrict__ bias, const float* __restrict__ resid,
               void* __restrict__ Cout, int ldc, int K) {
  __shared__ __align__(16) ushort As[2][128 * 64];   // 32KB
  __shared__ __align__(16) ushort Bs[2][128 * 64];   // 32KB
  const int tid = threadIdx.x;
  const int lane = tid & 63, w = tid >> 6;
  const int g = lane >> 4, c = lane & 15;
  int bid = blockIdx.y * gridDim.x + blockIdx.x;
  const int qq = (gridDim.x * gridDim.y) >> 3;
  bid = (bid & 7) * qq + (bid >> 3);
  const int m0 = (bid / gridDim.x) * 128, n0 = (bid % gridDim.x) * 128;
  const int wm = (w >> 1) * 64, wn = (w & 1) * 64;
  f4v acc[4][4];
#pragma unroll
  for (int i = 0; i < 4; ++i)
#pragma unroll
    for (int j = 0; j < 4; ++j) acc[i][j] = f4v{0.f, 0.f, 0.f, 0.f};

  const int srow = tid >> 3;                           // 0..31
  const int koff = ((tid & 7) * 8) ^ ((srow & 7) << 3);  // involutive swizzle
  auto stage = [&](int buf, int k0) {
#pragma unroll
    for (int seg = 0; seg < 4; ++seg) {
      const int r = seg * 32 + srow;
      GLOAD_LDS(A + (size_t)(m0 + r) * lda + k0 + koff,
                &As[buf][(seg * 256 + tid) * 8]);
      GLOAD_LDS(B + (size_t)(n0 + r) * K + k0 + koff,
                &Bs[buf][(seg * 256 + tid) * 8]);
    }
  };

  stage(0, 0);   // 8 loads in flight
  int curb = 0;
  for (int k0 = 0; k0 < K; k0 += 64) {
    const bool st = (k0 + 64 < K);
    if (st) {
      stage(curb ^ 1, k0 + 64);   // 16 in flight
      asm volatile("s_waitcnt vmcnt(8)" ::: "memory");  // cur tile landed
    } else {
      asm volatile("s_waitcnt vmcnt(0)" ::: "memory");
    }
    __builtin_amdgcn_s_barrier();
    s8v af[2][4], bf[2][4];
#pragma unroll
    for (int ks = 0; ks < 2; ++ks) {
#pragma unroll
      for (int mi = 0; mi < 4; ++mi) {
        const int R = wm + mi * 16 + c;
        af[ks][mi] = *(const s8v*)&As[curb][R * 64 + 8 * ((ks * 4 + g) ^ (R & 7))];
      }
#pragma unroll
      for (int ni = 0; ni < 4; ++ni) {
        const int R = wn + ni * 16 + c;
        bf[ks][ni] = *(const s8v*)&Bs[curb][R * 64 + 8 * ((ks * 4 + g) ^ (R & 7))];
      }
    }
    __builtin_amdgcn_s_setprio(1);
#pragma unroll
    for (int ks = 0; ks < 2; ++ks)
#pragma unroll
      for (int mi = 0; mi < 4; ++mi)
#pragma unroll
        for (int ni = 0; ni < 4; ++ni)
          acc[mi][ni] = __builtin_amdgcn_mfma_f32_16x16x32_bf16(
              af[ks][mi], bf[ks][ni], acc[mi][ni], 0, 0, 0);
    __builtin_amdgcn_s_setprio(0);
    __builtin_amdgcn_s_barrier();   // all waves done reading curb
    curb ^= 1;
  }

#pragma unroll
  for (int mi = 0; mi < 4; ++mi) {
#pragma unroll
    for (int ni = 0; ni < 4; ++ni) {
#pragma unroll
      for (int j = 0; j < 4; ++j) {
        const int row = m0 + wm + mi * 16 + g * 4 + j;
        const int col = n0 + wn + ni * 16 + c;
        float v = acc[mi][ni][j];
        if constexpr (EPI == 1) {
          v += bias[col] + resid[(size_t)row * ldc + col];
          ((float*)Cout)[(size_t)row * ldc + col] = v;
        } else {
          ((float*)Cout)[(size_t)row * ldc + col] += v;
        }
      }
    }
  }
}

// ---------------------------------------------------------------------------
// MFMA flash attention, 8-wave blocks + 2-chunk-per-barrier-pair unroll:
// 4-buffer LDS rotation (64 KB, still 2 blocks/CU). Per iteration: stage a
// chunk PAIR (4 loads), vmcnt(4) -> current pair landed, 1 barrier, compute
// both chunks back-to-back, 1 barrier. Halves barrier count vs round 13.
// Buffer safety: pair u+1 stages into pair u-1's buffers, whose readers
// finished before the end-of-iteration-(u-1) barrier.
// ---------------------------------------------------------------------------
__global__ __launch_bounds__(512)
void attn_mfma(const ushort* __restrict__ Qb, const ushort* __restrict__ Kb,
               const ushort* __restrict__ Vt, ushort* __restrict__ Ob) {
  __shared__ __align__(16) ushort Ksm[4][64 * 64];
  __shared__ __align__(16) ushort Vtsm[4][64 * 64];
  const int tid = threadIdx.x;
  const int lane = tid & 63, w = tid >> 6;       // w in [0,8)
  const int ql = lane & 31, hi = lane >> 5;
  int bid = blockIdx.x;                           // grid = 512
  bid = (bid & 7) * 64 + (bid >> 3);              // bijective XCD swizzle
  const int qt = bid & 7, bh = bid >> 3;          // 8 q-tiles of 256 per bh
  const ushort* Qh = Qb + (size_t)bh * Tc * 64;
  const ushort* Kh = Kb + (size_t)bh * Tc * 64;
  const ushort* Vth = Vt + (size_t)bh * 64 * Tc;
  const int qrow = qt * 256 + w * 32 + ql;
  s8v qf[4];
#pragma unroll
  for (int ds = 0; ds < 4; ++ds)
    qf[ds] = *(const s8v*)(Qh + (size_t)qrow * 64 + ds * 16 + hi * 8);
  f16v accO0, accO1;
#pragma unroll
  for (int i = 0; i < 16; ++i) { accO0[i] = 0.f; accO1[i] = 0.f; }
  float mold = -1e30f, lsum = 0.f;
  const int srow = tid >> 3;                          // 0..63
  const int soff = ((tid & 7) * 8) ^ ((srow & 7) << 3);
  auto stage = [&](int buf, int j0) {
    GLOAD_LDS(Kh + (size_t)(j0 + srow) * 64 + soff, &Ksm[buf][tid * 8]);
    GLOAD_LDS(Vth + (size_t)srow * Tc + j0 + soff, &Vtsm[buf][tid * 8]);
  };
  // compute one 64-key chunk from buffer buf
  auto chunk = [&](int buf) {
    f16v s0, s1;
#pragma unroll
    for (int i = 0; i < 16; ++i) { s0[i] = 0.f; s1[i] = 0.f; }
    __builtin_amdgcn_s_setprio(1);
#pragma unroll
    for (int ds = 0; ds < 4; ++ds) {
      const int col = (ds * 16 + hi * 8);
      const int r0 = ql;
      s8v kf0 = *(const s8v*)&Ksm[buf][r0 * 64 + (col ^ ((r0 & 7) << 3))];
      s0 = __builtin_amdgcn_mfma_f32_32x32x16_bf16(kf0, qf[ds], s0, 0, 0, 0);
      const int r1 = 32 + ql;
      s8v kf1 = *(const s8v*)&Ksm[buf][r1 * 64 + (col ^ ((r1 & 7) << 3))];
      s1 = __builtin_amdgcn_mfma_f32_32x32x16_bf16(kf1, qf[ds], s1, 0, 0, 0);
    }
    __builtin_amdgcn_s_setprio(0);
    float cc0 = fmaxf(s0[0], s1[0]), cc1 = fmaxf(s0[1], s1[1]);
    float cc2 = fmaxf(s0[2], s1[2]), cc3 = fmaxf(s0[3], s1[3]);
#pragma unroll
    for (int i = 4; i < 16; i += 4) {
      cc0 = max3f(cc0, s0[i + 0], s1[i + 0]);
      cc1 = max3f(cc1, s0[i + 1], s1[i + 1]);
      cc2 = max3f(cc2, s0[i + 2], s1[i + 2]);
      cc3 = max3f(cc3, s0[i + 3], s1[i + 3]);
    }
    float mx = pmax32(fmaxf(max3f(cc0, cc1, cc2), cc3));
    const bool need = mx > mold + 11.5416f;    // 8 * log2(e)
    if (__any((int)need)) {
      const float mnew = fmaxf(mold, mx);
      const float sc = exp2v(mold - mnew);
      lsum *= sc;
#pragma unroll
      for (int i = 0; i < 16; ++i) { accO0[i] *= sc; accO1[i] *= sc; }
      mold = mnew;
    }
    float r0s = 0.f, r1s = 0.f, r2s = 0.f, r3s = 0.f;
#pragma unroll
    for (int i = 0; i < 16; i += 4) {
      s0[i+0] = exp2v(s0[i+0] - mold); r0s += s0[i+0];
      s0[i+1] = exp2v(s0[i+1] - mold); r1s += s0[i+1];
      s0[i+2] = exp2v(s0[i+2] - mold); r2s += s0[i+2];
      s0[i+3] = exp2v(s0[i+3] - mold); r3s += s0[i+3];
      s1[i+0] = exp2v(s1[i+0] - mold); r0s += s1[i+0];
      s1[i+1] = exp2v(s1[i+1] - mold); r1s += s1[i+1];
      s1[i+2] = exp2v(s1[i+2] - mold); r2s += s1[i+2];
      s1[i+3] = exp2v(s1[i+3] - mold); r3s += s1[i+3];
    }
    lsum += psum32((r0s + r1s) + (r2s + r3s));
    s8v pa[4];
#pragma unroll
    for (int s = 0; s < 4; ++s) {
      const f16v st2 = (s < 2) ? s0 : s1;
      const int mA = 2 * (s & 1);
      uint32_t a0 = cvtpk(st2[4 * mA + 0], st2[4 * mA + 1]);
      uint32_t a1 = cvtpk(st2[4 * mA + 2], st2[4 * mA + 3]);
      uint32_t b0 = cvtpk(st2[4 * mA + 4], st2[4 * mA + 5]);
      uint32_t b1 = cvtpk(st2[4 * mA + 6], st2[4 * mA + 7]);
      asm("v_permlane32_swap_b32 %0, %1" : "+v"(b0), "+v"(a0));
      asm("v_permlane32_swap_b32 %0, %1" : "+v"(b1), "+v"(a1));
      union { uint32_t u[4]; s8v v; } pk;
      pk.u[0] = a0; pk.u[1] = a1; pk.u[2] = b0; pk.u[3] = b1;
      pa[s] = pk.v;
    }
    __builtin_amdgcn_s_setprio(1);
#pragma unroll
    for (int s = 0; s < 4; ++s) {
      const int col = (s * 16 + hi * 8);
      const int r0 = ql;
      s8v vf0 = *(const s8v*)&Vtsm[buf][r0 * 64 + (col ^ ((r0 & 7) << 3))];
      accO0 = __builtin_amdgcn_mfma_f32_32x32x16_bf16(vf0, pa[s], accO0, 0, 0, 0);
      const int r1 = 32 + ql;
      s8v vf1 = *(const s8v*)&Vtsm[buf][r1 * 64 + (col ^ ((r1 & 7) << 3))];
      accO1 = __builtin_amdgcn_mfma_f32_32x32x16_bf16(vf1, pa[s], accO1, 0, 0, 0);
    }
    __builtin_amdgcn_s_setprio(0);
  };

  constexpr int NU = Tc / 128;   // 16 chunk pairs
  stage(0, 0);
  stage(1, 64);                  // 4 loads in flight (pair 0)
  for (int u = 0; u < NU; ++u) {
    const bool st = (u + 1 < NU);
    if (st) {
      stage((2 * u + 2) & 3, (2 * u + 2) * 64);
      stage((2 * u + 3) & 3, (2 * u + 3) * 64);   // 8 in flight
      asm volatile("s_waitcnt vmcnt(4)" ::: "memory");  // pair u landed
    } else {
      asm volatile("s_waitcnt vmcnt(0)" ::: "memory");
    }
    __builtin_amdgcn_s_barrier();   // all waves' pair-u loads landed
    chunk((2 * u) & 3);
    chunk((2 * u + 1) & 3);
    __builtin_amdgcn_s_barrier();   // all waves done reading pair u
  }
  const int h = bh & 15, b = bh >> 4;
  const int tok = b * Tc + qt * 256 + w * 32 + ql;
  const float inv = 1.f / lsum;
  ushort* orow = Ob + (size_t)tok * Dc + h * 64;
#pragma unroll
  for (int dt = 0; dt < 2; ++dt) {
    const f16v ac = dt ? accO1 : accO0;
#pragma unroll
    for (int rq = 0; rq < 4; ++rq) {
      u4v pk;
#pragma unroll
      for (int j = 0; j < 4; ++j) pk[j] = f2bf(ac[4 * rq + j] * inv);
      *(u4v*)&orow[dt * 32 + 8 * rq + 4 * hi] = pk;
    }
  }
}

// ---------------------------------------------------------------------------
extern "C" void kernel_launch(void* const* d_in, const int* in_sizes, int n_in,
                              void* d_out, int out_size, void* d_ws, size_t ws_size,
                              hipStream_t stream) {
  (void)in_sizes; (void)n_in; (void)out_size; (void)ws_size;
  const float* x        = (const float*)d_in[0];
  const float* ln1_g    = (const float*)d_in[1];
  const float* ln1_b    = (const float*)d_in[2];
  const float* in_w     = (const float*)d_in[3];
  const float* in_b     = (const float*)d_in[4];
  const float* out_w    = (const float*)d_in[5];
  const float* out_b    = (const float*)d_in[6];
  const float* ln2_g    = (const float*)d_in[7];
  const float* ln2_b    = (const float*)d_in[8];
  const float* rw       = (const float*)d_in[9];
  const float* log_temp = (const float*)d_in[10];
  const float* Wg       = (const float*)d_in[11];
  const float* Wu       = (const float*)d_in[12];
  const float* Wd       = (const float*)d_in[13];
  float* out = (float*)d_out;

  // Workspace (ushorts), total ~138 MiB:
  ushort* h_bf   = (ushort*)d_ws;                       // NTOK*1024   16 MiB
  ushort* Qb     = h_bf   + (size_t)NTOK * Dc;          // 16 MiB
  ushort* Kb     = Qb     + (size_t)NTOK * Dc;          // 16 MiB
  ushort* Vt     = Kb     + (size_t)NTOK * Dc;          // 16 MiB ([bh][d][t])
  ushort* Ob     = Vt     + (size_t)NTOK * Dc;          // 16 MiB
  ushort* act    = Ob     + (size_t)NTOK * Dc;          // NTOK*2048   32 MiB
  ushort* wb_in  = act    + (size_t)NTOK * EDE;         // 3072*1024    6 MiB
  ushort* wb_out = wb_in  + (size_t)3 * Dc * Dc;        // 1024*1024    2 MiB
  ushort* wb_gu  = wb_out + (size_t)Dc * Dc;            // 4096*1024    8 MiB
  ushort* wb_d   = wb_gu  + (size_t)2 * EDE * Dc;       // 1024*2048    4 MiB
  float*  wts    = (float*)(wb_d + (size_t)Dc * EDE);   // NTOK*8     0.25 MiB

  const dim3 blk(256);

  // 0. all weight conversions + LN1 in one launch
  convert_all<<<dim3(5120 + NTOK), blk, 0, stream>>>(
      in_w, out_w, Wg, Wu, Wd, wb_in, wb_out, wb_gu, wb_d,
      x, ln1_g, ln1_b, h_bf);

  // 1. QKV GEMM (256^2 8-phase) -> head-major Q(x0.125*log2e)/K + V^T
  gemm256<0><<<dim3(3 * Dc / 256, NTOK / 256), dim3(512), 0, stream>>>(
      h_bf, Dc, wb_in, in_b, Qb, Dc);
  // 2. MFMA attention (8-wave, 2-chunk unroll) -> Ob bf16
  attn_mfma<<<dim3(Bc * Hc * (Tc / 256)), dim3(512), 0, stream>>>(
      Qb, Kb, Vt, Ob);
  // 3. out proj + bias + residual(x) -> out fp32 (128^2 BK=64 2-phase)
  gemm_bf16<1><<<dim3(Dc / 128, NTOK / 128), blk, 0, stream>>>(
      Ob, Dc, wb_out, out_b, x, out, Dc, Dc);
  // 4. LN2 + fused router: out -> h_bf (h2), wts
  ln_kernel<1><<<dim3(NTOK), blk, 0, stream>>>(out, ln2_g, ln2_b, h_bf,
                                               rw, log_temp, wts);
  // 5. fused gate+up GEMM (256^2 8-phase) + silu*up*wts -> act bf16
  gemm256<4><<<dim3(2 * EDE / 256, NTOK / 256), dim3(512), 0, stream>>>(
      h_bf, Dc, wb_gu, wts, act, Dc);
  // 6. single down GEMM (128^2 BK=64 2-phase, K=2048), += into out
  gemm_bf16<3><<<dim3(Dc / 128, NTOK / 128), blk, 0, stream>>>(
      act, EDE, wb_d, nullptr, nullptr, out, Dc, EDE);
}